// Round 1
// baseline (2768.333 us; speedup 1.0000x reference)
//
#include <hip/hip_runtime.h>
#include <math.h>

#define NN 50000
#define NE 800000
#define EP (NE + NN)        // edges including self loops
#define INC 128
#define HID 64
#define HEADS 4
#define C1 (HEADS * HID)    // 256
#define NEG 0.2f
#define EPSS 1e-16f

// ---------------- float atomic max (int/uint ordering trick) ----------------
__device__ __forceinline__ void atomicMaxF(float* addr, float v) {
    if (v >= 0.f) atomicMax((int*)addr, __float_as_int(v));
    else          atomicMin((unsigned int*)addr, __float_as_uint(v));
}

// ---------------- GEMM1: h1raw[N,256] = x[N,128] @ W1[128,256] ----------------
__global__ __launch_bounds__(256) void gemm1_kernel(const float* __restrict__ x,
                                                    const float* __restrict__ W,
                                                    float* __restrict__ out) {
    __shared__ float xs[32][128];
    __shared__ float ws[128][64];
    const int n0 = blockIdx.x * 32;
    const int c0 = blockIdx.y * 64;
    const int tid = threadIdx.x;

    for (int idx = tid; idx < 32 * 128; idx += 256) {
        int r = idx >> 7, k = idx & 127;
        int n = n0 + r;
        xs[r][k] = (n < NN) ? x[n * INC + k] : 0.f;
    }
    for (int idx = tid; idx < 128 * 64; idx += 256) {
        int k = idx >> 6, c = idx & 63;
        ws[k][c] = W[k * C1 + c0 + c];
    }
    __syncthreads();

    const int c = tid & 63;
    const int rg = tid >> 6;  // 0..3
    float acc[8] = {0.f, 0.f, 0.f, 0.f, 0.f, 0.f, 0.f, 0.f};
    for (int k = 0; k < 128; k += 4) {
        float w0 = ws[k][c], w1 = ws[k + 1][c], w2 = ws[k + 2][c], w3 = ws[k + 3][c];
#pragma unroll
        for (int r = 0; r < 8; ++r) {
            const float4 xv = *reinterpret_cast<const float4*>(&xs[rg * 8 + r][k]);
            acc[r] += xv.x * w0 + xv.y * w1 + xv.z * w2 + xv.w * w3;
        }
    }
#pragma unroll
    for (int r = 0; r < 8; ++r) {
        int n = n0 + rg * 8 + r;
        if (n < NN) out[n * C1 + c0 + c] = acc[r];
    }
}

// ---------------- GEMM2: h2raw[N,64] = h1[N,256] @ W2[256,64] ----------------
__global__ __launch_bounds__(256) void gemm2_kernel(const float* __restrict__ x,
                                                    const float* __restrict__ W,
                                                    float* __restrict__ out) {
    __shared__ float xs[32][128];
    __shared__ float ws[128][64];
    const int n0 = blockIdx.x * 32;
    const int tid = threadIdx.x;
    const int c = tid & 63;
    const int rg = tid >> 6;
    float acc[8] = {0.f, 0.f, 0.f, 0.f, 0.f, 0.f, 0.f, 0.f};

    for (int kc = 0; kc < 256; kc += 128) {
        __syncthreads();
        for (int idx = tid; idx < 32 * 128; idx += 256) {
            int r = idx >> 7, k = idx & 127;
            int n = n0 + r;
            xs[r][k] = (n < NN) ? x[n * C1 + kc + k] : 0.f;
        }
        for (int idx = tid; idx < 128 * 64; idx += 256) {
            int k = idx >> 6, cc = idx & 63;
            ws[k][cc] = W[(kc + k) * HID + cc];
        }
        __syncthreads();
        for (int k = 0; k < 128; k += 4) {
            float w0 = ws[k][c], w1 = ws[k + 1][c], w2 = ws[k + 2][c], w3 = ws[k + 3][c];
#pragma unroll
            for (int r = 0; r < 8; ++r) {
                const float4 xv = *reinterpret_cast<const float4*>(&xs[rg * 8 + r][k]);
                acc[r] += xv.x * w0 + xv.y * w1 + xv.z * w2 + xv.w * w3;
            }
        }
    }
#pragma unroll
    for (int r = 0; r < 8; ++r) {
        int n = n0 + rg * 8 + r;
        if (n < NN) out[n * HID + c] = acc[r];
    }
}

// ---------------- attention logits per node, conv1 (4 heads) ----------------
__global__ void att1_kernel(const float* __restrict__ h, const float* __restrict__ att_s,
                            const float* __restrict__ att_d,
                            float* __restrict__ as_, float* __restrict__ ad_) {
    int idx = blockIdx.x * blockDim.x + threadIdx.x;
    if (idx >= NN * HEADS) return;
    int n = idx >> 2, hd = idx & 3;
    const float* hp = h + n * C1 + hd * HID;
    const float* sp = att_s + hd * HID;
    const float* dp = att_d + hd * HID;
    float s = 0.f, d = 0.f;
    for (int c = 0; c < HID; c += 4) {
        float4 hv = *(const float4*)(hp + c);
        float4 sv = *(const float4*)(sp + c);
        float4 dv = *(const float4*)(dp + c);
        s += hv.x * sv.x + hv.y * sv.y + hv.z * sv.z + hv.w * sv.w;
        d += hv.x * dv.x + hv.y * dv.y + hv.z * dv.z + hv.w * dv.w;
    }
    as_[idx] = s;
    ad_[idx] = d;
}

// ---------------- attention logits per node, conv2 (1 head) ----------------
__global__ void att2_kernel(const float* __restrict__ h, const float* __restrict__ att_s,
                            const float* __restrict__ att_d,
                            float* __restrict__ as_, float* __restrict__ ad_) {
    int n = blockIdx.x * blockDim.x + threadIdx.x;
    if (n >= NN) return;
    const float* hp = h + n * HID;
    float s = 0.f, d = 0.f;
    for (int c = 0; c < HID; c += 4) {
        float4 hv = *(const float4*)(hp + c);
        float4 sv = *(const float4*)(att_s + c);
        float4 dv = *(const float4*)(att_d + c);
        s += hv.x * sv.x + hv.y * sv.y + hv.z * sv.z + hv.w * sv.w;
        d += hv.x * dv.x + hv.y * dv.y + hv.z * dv.z + hv.w * dv.w;
    }
    as_[n] = s;
    ad_[n] = d;
}

// ---------------- init: acc=0, m=-inf, s=0 ----------------
__global__ void init1_kernel(float* __restrict__ acc, float* __restrict__ m, float* __restrict__ s) {
    int i = blockIdx.x * blockDim.x + threadIdx.x;
    if (i < NN * C1) acc[i] = 0.f;
    if (i < NN * HEADS) { m[i] = -INFINITY; s[i] = 0.f; }
}
__global__ void init2_kernel(float* __restrict__ acc, float* __restrict__ m, float* __restrict__ s) {
    int i = blockIdx.x * blockDim.x + threadIdx.x;
    if (i < NN * HID) acc[i] = 0.f;
    if (i < NN) { m[i] = -INFINITY; s[i] = 0.f; }
}

// ---------------- conv1 edge passes ----------------
__global__ void edge_max1(const int* __restrict__ ei, const float* __restrict__ as_,
                          const float* __restrict__ ad_, float* __restrict__ m1) {
    int e = blockIdx.x * blockDim.x + threadIdx.x;
    if (e >= EP) return;
    int s, d;
    if (e < NE) { s = ei[e]; d = ei[NE + e]; } else { s = d = e - NE; }
    float4 av = *(const float4*)(as_ + s * 4);
    float4 bv = *(const float4*)(ad_ + d * 4);
    float t;
    t = av.x + bv.x; t = t > 0.f ? t : NEG * t; atomicMaxF(&m1[d * 4 + 0], t);
    t = av.y + bv.y; t = t > 0.f ? t : NEG * t; atomicMaxF(&m1[d * 4 + 1], t);
    t = av.z + bv.z; t = t > 0.f ? t : NEG * t; atomicMaxF(&m1[d * 4 + 2], t);
    t = av.w + bv.w; t = t > 0.f ? t : NEG * t; atomicMaxF(&m1[d * 4 + 3], t);
}

__global__ void edge_sum1(const int* __restrict__ ei, const float* __restrict__ as_,
                          const float* __restrict__ ad_, const float* __restrict__ m1,
                          float* __restrict__ s1) {
    int e = blockIdx.x * blockDim.x + threadIdx.x;
    if (e >= EP) return;
    int s, d;
    if (e < NE) { s = ei[e]; d = ei[NE + e]; } else { s = d = e - NE; }
    float4 av = *(const float4*)(as_ + s * 4);
    float4 bv = *(const float4*)(ad_ + d * 4);
    float4 mv = *(const float4*)(m1 + d * 4);
    float t;
    t = av.x + bv.x; t = t > 0.f ? t : NEG * t; atomicAdd(&s1[d * 4 + 0], expf(t - mv.x));
    t = av.y + bv.y; t = t > 0.f ? t : NEG * t; atomicAdd(&s1[d * 4 + 1], expf(t - mv.y));
    t = av.z + bv.z; t = t > 0.f ? t : NEG * t; atomicAdd(&s1[d * 4 + 2], expf(t - mv.z));
    t = av.w + bv.w; t = t > 0.f ? t : NEG * t; atomicAdd(&s1[d * 4 + 3], expf(t - mv.w));
}

// wave per edge; lane = channel within head
__global__ __launch_bounds__(256) void edge_scatter1(const int* __restrict__ ei,
                                                     const float* __restrict__ as_,
                                                     const float* __restrict__ ad_,
                                                     const float* __restrict__ m1,
                                                     const float* __restrict__ s1,
                                                     const float* __restrict__ h,
                                                     float* __restrict__ acc) {
    int wid = threadIdx.x >> 6;
    int lane = threadIdx.x & 63;
    int e = blockIdx.x * 4 + wid;
    if (e >= EP) return;
    int s, d;
    if (e < NE) { s = ei[e]; d = ei[NE + e]; } else { s = d = e - NE; }
    float4 av = *(const float4*)(as_ + s * 4);
    float4 bv = *(const float4*)(ad_ + d * 4);
    float4 mv = *(const float4*)(m1 + d * 4);
    float4 sv = *(const float4*)(s1 + d * 4);
    float t;
    t = av.x + bv.x; t = t > 0.f ? t : NEG * t; float al0 = expf(t - mv.x) / (sv.x + EPSS);
    t = av.y + bv.y; t = t > 0.f ? t : NEG * t; float al1 = expf(t - mv.y) / (sv.y + EPSS);
    t = av.z + bv.z; t = t > 0.f ? t : NEG * t; float al2 = expf(t - mv.z) / (sv.z + EPSS);
    t = av.w + bv.w; t = t > 0.f ? t : NEG * t; float al3 = expf(t - mv.w) / (sv.w + EPSS);
    const float* hs = h + s * C1;
    float* ap = acc + d * C1;
    atomicAdd(ap + lane,       al0 * hs[lane]);
    atomicAdd(ap + 64 + lane,  al1 * hs[64 + lane]);
    atomicAdd(ap + 128 + lane, al2 * hs[128 + lane]);
    atomicAdd(ap + 192 + lane, al3 * hs[192 + lane]);
}

__global__ void bias_elu1(float* __restrict__ a, const float* __restrict__ b) {
    int i = blockIdx.x * blockDim.x + threadIdx.x;
    if (i >= NN * C1) return;
    float v = a[i] + b[i & 255];
    a[i] = v > 0.f ? v : (expf(v) - 1.f);
}

// ---------------- conv2 edge passes ----------------
__global__ void edge_max2(const int* __restrict__ ei, const float* __restrict__ as_,
                          const float* __restrict__ ad_, float* __restrict__ m2) {
    int e = blockIdx.x * blockDim.x + threadIdx.x;
    if (e >= EP) return;
    int s, d;
    if (e < NE) { s = ei[e]; d = ei[NE + e]; } else { s = d = e - NE; }
    float t = as_[s] + ad_[d];
    t = t > 0.f ? t : NEG * t;
    atomicMaxF(&m2[d], t);
}

__global__ void edge_sum2(const int* __restrict__ ei, const float* __restrict__ as_,
                          const float* __restrict__ ad_, const float* __restrict__ m2,
                          float* __restrict__ s2) {
    int e = blockIdx.x * blockDim.x + threadIdx.x;
    if (e >= EP) return;
    int s, d;
    if (e < NE) { s = ei[e]; d = ei[NE + e]; } else { s = d = e - NE; }
    float t = as_[s] + ad_[d];
    t = t > 0.f ? t : NEG * t;
    atomicAdd(&s2[d], expf(t - m2[d]));
}

__global__ __launch_bounds__(256) void edge_scatter2(const int* __restrict__ ei,
                                                     const float* __restrict__ as_,
                                                     const float* __restrict__ ad_,
                                                     const float* __restrict__ m2,
                                                     const float* __restrict__ s2,
                                                     const float* __restrict__ h,
                                                     float* __restrict__ acc) {
    int wid = threadIdx.x >> 6;
    int lane = threadIdx.x & 63;
    int e = blockIdx.x * 4 + wid;
    if (e >= EP) return;
    int s, d;
    if (e < NE) { s = ei[e]; d = ei[NE + e]; } else { s = d = e - NE; }
    float t = as_[s] + ad_[d];
    t = t > 0.f ? t : NEG * t;
    float alpha = expf(t - m2[d]) / (s2[d] + EPSS);
    atomicAdd(&acc[d * HID + lane], alpha * h[s * HID + lane]);
}

__global__ void bias2_kernel(float* __restrict__ a, const float* __restrict__ b) {
    int i = blockIdx.x * blockDim.x + threadIdx.x;
    if (i >= NN * HID) return;
    a[i] = a[i] + b[i & 63];
}

// ---------------- edge MLP ----------------
__global__ __launch_bounds__(256) void edge_mlp(const int* __restrict__ ei,
                                                const float* __restrict__ emb,
                                                const float* __restrict__ stats,
                                                const float* __restrict__ mW1,
                                                const float* __restrict__ mb1,
                                                const float* __restrict__ mW2,
                                                const float* __restrict__ mb2,
                                                float* __restrict__ out) {
    __shared__ float w1s[131 * 64];
    __shared__ float b1s[64];
    __shared__ float w2s[128];
    __shared__ float b2s[2];
    const int tid = threadIdx.x;
    for (int idx = tid; idx < 131 * 64; idx += 256) w1s[idx] = mW1[idx];
    if (tid < 64) b1s[tid] = mb1[tid];
    if (tid < 128) w2s[tid] = mW2[tid];
    if (tid < 2) b2s[tid] = mb2[tid];
    __syncthreads();

    const int wid = tid >> 6;
    const int lane = tid & 63;
    const float w0 = w2s[lane * 2];
    const float w1 = w2s[lane * 2 + 1];
    const float bb = b1s[lane];

    for (int e = blockIdx.x * 4 + wid; e < NE; e += gridDim.x * 4) {
        int r = ei[e], c = ei[NE + e];
        float er = emb[r * HID + lane];
        float ec = emb[c * HID + lane];
        float st = (lane < 3) ? stats[e * 3 + lane] : 0.f;
        float acc = bb;
#pragma unroll
        for (int i = 0; i < 64; ++i) acc += __shfl(er, i) * w1s[i * 64 + lane];
#pragma unroll
        for (int i = 0; i < 64; ++i) acc += __shfl(ec, i) * w1s[(64 + i) * 64 + lane];
        acc += __shfl(st, 0) * w1s[128 * 64 + lane];
        acc += __shfl(st, 1) * w1s[129 * 64 + lane];
        acc += __shfl(st, 2) * w1s[130 * 64 + lane];
        acc = fmaxf(acc, 0.f);
        float r0 = acc * w0, r1 = acc * w1;
#pragma unroll
        for (int off = 32; off > 0; off >>= 1) {
            r0 += __shfl_xor(r0, off);
            r1 += __shfl_xor(r1, off);
        }
        if (lane == 0) {
            out[e * 2]     = r0 + b2s[0];
            out[e * 2 + 1] = r1 + b2s[1];
        }
    }
}

// ---------------- launcher ----------------
extern "C" void kernel_launch(void* const* d_in, const int* in_sizes, int n_in,
                              void* d_out, int out_size, void* d_ws, size_t ws_size,
                              hipStream_t stream) {
    const float* x      = (const float*)d_in[0];
    const int*   ei     = (const int*)d_in[1];
    const float* stats  = (const float*)d_in[2];
    const float* W1     = (const float*)d_in[3];
    const float* att_s1 = (const float*)d_in[4];
    const float* att_d1 = (const float*)d_in[5];
    const float* b1     = (const float*)d_in[6];
    const float* W2     = (const float*)d_in[7];
    const float* att_s2 = (const float*)d_in[8];
    const float* att_d2 = (const float*)d_in[9];
    const float* b2     = (const float*)d_in[10];
    const float* mW1    = (const float*)d_in[11];
    const float* mb1    = (const float*)d_in[12];
    const float* mW2    = (const float*)d_in[13];
    const float* mb2    = (const float*)d_in[14];
    float* out = (float*)d_out;
    float* ws  = (float*)d_ws;

    float* h1raw = ws;                              // NN*256
    float* h1    = ws + (size_t)NN * C1;            // NN*256  (acc1 -> h1)
    float* as1   = ws + (size_t)2 * NN * C1;        // NN*4
    float* ad1   = as1 + NN * 4;
    float* m1    = ad1 + NN * 4;
    float* s1    = m1 + NN * 4;
    // phase B reuses the h1raw region (h1raw dead after edge_scatter1)
    float* h2raw = h1raw;                           // NN*64
    float* acc2  = h1raw + (size_t)NN * HID;        // NN*64 (becomes node_emb)
    float* as2   = h1raw + (size_t)2 * NN * HID;    // NN
    float* ad2   = as2 + NN;
    float* m2    = ad2 + NN;
    float* s2    = m2 + NN;

    // ---- conv1 ----
    gemm1_kernel<<<dim3((NN + 31) / 32, 4), 256, 0, stream>>>(x, W1, h1raw);
    att1_kernel<<<(NN * HEADS + 255) / 256, 256, 0, stream>>>(h1raw, att_s1, att_d1, as1, ad1);
    init1_kernel<<<(NN * C1 + 255) / 256, 256, 0, stream>>>(h1, m1, s1);
    edge_max1<<<(EP + 255) / 256, 256, 0, stream>>>(ei, as1, ad1, m1);
    edge_sum1<<<(EP + 255) / 256, 256, 0, stream>>>(ei, as1, ad1, m1, s1);
    edge_scatter1<<<(EP + 3) / 4, 256, 0, stream>>>(ei, as1, ad1, m1, s1, h1raw, h1);
    bias_elu1<<<(NN * C1 + 255) / 256, 256, 0, stream>>>(h1, b1);

    // ---- conv2 ----
    gemm2_kernel<<<(NN + 31) / 32, 256, 0, stream>>>(h1, W2, h2raw);
    att2_kernel<<<(NN + 255) / 256, 256, 0, stream>>>(h2raw, att_s2, att_d2, as2, ad2);
    init2_kernel<<<(NN * HID + 255) / 256, 256, 0, stream>>>(acc2, m2, s2);
    edge_max2<<<(EP + 255) / 256, 256, 0, stream>>>(ei, as2, ad2, m2);
    edge_sum2<<<(EP + 255) / 256, 256, 0, stream>>>(ei, as2, ad2, m2, s2);
    edge_scatter2<<<(EP + 3) / 4, 256, 0, stream>>>(ei, as2, ad2, m2, s2, h2raw, acc2);
    bias2_kernel<<<(NN * HID + 255) / 256, 256, 0, stream>>>(acc2, b2);

    // ---- edge MLP ----
    edge_mlp<<<2048, 256, 0, stream>>>(ei, acc2, stats, mW1, mb1, mW2, mb2, out);
}

// Round 2
// 1784.775 us; speedup vs baseline: 1.5511x; 1.5511x over previous
//
#include <hip/hip_runtime.h>
#include <math.h>

#define NN 50000
#define NE 800000
#define EP (NE + NN)        // edges including self loops
#define INC 128
#define HID 64
#define HEADS 4
#define C1 (HEADS * HID)    // 256
#define NEG 0.2f
#define EPSS 1e-16f

// ---------------- float atomic max (int/uint ordering trick) ----------------
__device__ __forceinline__ void atomicMaxF(float* addr, float v) {
    if (v >= 0.f) atomicMax((int*)addr, __float_as_int(v));
    else          atomicMin((unsigned int*)addr, __float_as_uint(v));
}

// ---------------- GEMM1: h1raw[N,256] = x[N,128] @ W1[128,256] ----------------
__global__ __launch_bounds__(256) void gemm1_kernel(const float* __restrict__ x,
                                                    const float* __restrict__ W,
                                                    float* __restrict__ out) {
    __shared__ float xs[32][128];
    __shared__ float ws[128][64];
    const int n0 = blockIdx.x * 32;
    const int c0 = blockIdx.y * 64;
    const int tid = threadIdx.x;

    for (int idx = tid; idx < 32 * 128; idx += 256) {
        int r = idx >> 7, k = idx & 127;
        int n = n0 + r;
        xs[r][k] = (n < NN) ? x[n * INC + k] : 0.f;
    }
    for (int idx = tid; idx < 128 * 64; idx += 256) {
        int k = idx >> 6, c = idx & 63;
        ws[k][c] = W[k * C1 + c0 + c];
    }
    __syncthreads();

    const int c = tid & 63;
    const int rg = tid >> 6;  // 0..3
    float acc[8] = {0.f, 0.f, 0.f, 0.f, 0.f, 0.f, 0.f, 0.f};
    for (int k = 0; k < 128; k += 4) {
        float w0 = ws[k][c], w1 = ws[k + 1][c], w2 = ws[k + 2][c], w3 = ws[k + 3][c];
#pragma unroll
        for (int r = 0; r < 8; ++r) {
            const float4 xv = *reinterpret_cast<const float4*>(&xs[rg * 8 + r][k]);
            acc[r] += xv.x * w0 + xv.y * w1 + xv.z * w2 + xv.w * w3;
        }
    }
#pragma unroll
    for (int r = 0; r < 8; ++r) {
        int n = n0 + rg * 8 + r;
        if (n < NN) out[n * C1 + c0 + c] = acc[r];
    }
}

// ---------------- GEMM2: h2raw[N,64] = h1[N,256] @ W2[256,64] ----------------
__global__ __launch_bounds__(256) void gemm2_kernel(const float* __restrict__ x,
                                                    const float* __restrict__ W,
                                                    float* __restrict__ out) {
    __shared__ float xs[32][128];
    __shared__ float ws[128][64];
    const int n0 = blockIdx.x * 32;
    const int tid = threadIdx.x;
    const int c = tid & 63;
    const int rg = tid >> 6;
    float acc[8] = {0.f, 0.f, 0.f, 0.f, 0.f, 0.f, 0.f, 0.f};

    for (int kc = 0; kc < 256; kc += 128) {
        __syncthreads();
        for (int idx = tid; idx < 32 * 128; idx += 256) {
            int r = idx >> 7, k = idx & 127;
            int n = n0 + r;
            xs[r][k] = (n < NN) ? x[n * C1 + kc + k] : 0.f;
        }
        for (int idx = tid; idx < 128 * 64; idx += 256) {
            int k = idx >> 6, cc = idx & 63;
            ws[k][cc] = W[(kc + k) * HID + cc];
        }
        __syncthreads();
        for (int k = 0; k < 128; k += 4) {
            float w0 = ws[k][c], w1 = ws[k + 1][c], w2 = ws[k + 2][c], w3 = ws[k + 3][c];
#pragma unroll
            for (int r = 0; r < 8; ++r) {
                const float4 xv = *reinterpret_cast<const float4*>(&xs[rg * 8 + r][k]);
                acc[r] += xv.x * w0 + xv.y * w1 + xv.z * w2 + xv.w * w3;
            }
        }
    }
#pragma unroll
    for (int r = 0; r < 8; ++r) {
        int n = n0 + rg * 8 + r;
        if (n < NN) out[n * HID + c] = acc[r];
    }
}

// ---------------- attention logits per node, conv1 (4 heads) ----------------
__global__ void att1_kernel(const float* __restrict__ h, const float* __restrict__ att_s,
                            const float* __restrict__ att_d,
                            float* __restrict__ as_, float* __restrict__ ad_) {
    int idx = blockIdx.x * blockDim.x + threadIdx.x;
    if (idx >= NN * HEADS) return;
    int n = idx >> 2, hd = idx & 3;
    const float* hp = h + n * C1 + hd * HID;
    const float* sp = att_s + hd * HID;
    const float* dp = att_d + hd * HID;
    float s = 0.f, d = 0.f;
    for (int c = 0; c < HID; c += 4) {
        float4 hv = *(const float4*)(hp + c);
        float4 sv = *(const float4*)(sp + c);
        float4 dv = *(const float4*)(dp + c);
        s += hv.x * sv.x + hv.y * sv.y + hv.z * sv.z + hv.w * sv.w;
        d += hv.x * dv.x + hv.y * dv.y + hv.z * dv.z + hv.w * dv.w;
    }
    as_[idx] = s;
    ad_[idx] = d;
}

// ---------------- attention logits per node, conv2 (1 head) ----------------
__global__ void att2_kernel(const float* __restrict__ h, const float* __restrict__ att_s,
                            const float* __restrict__ att_d,
                            float* __restrict__ as_, float* __restrict__ ad_) {
    int n = blockIdx.x * blockDim.x + threadIdx.x;
    if (n >= NN) return;
    const float* hp = h + n * HID;
    float s = 0.f, d = 0.f;
    for (int c = 0; c < HID; c += 4) {
        float4 hv = *(const float4*)(hp + c);
        float4 sv = *(const float4*)(att_s + c);
        float4 dv = *(const float4*)(att_d + c);
        s += hv.x * sv.x + hv.y * sv.y + hv.z * sv.z + hv.w * sv.w;
        d += hv.x * dv.x + hv.y * dv.y + hv.z * dv.z + hv.w * dv.w;
    }
    as_[n] = s;
    ad_[n] = d;
}

// ---------------- init: acc=0, m=-inf, s=0 ----------------
__global__ void init1_kernel(float* __restrict__ acc, float* __restrict__ m, float* __restrict__ s) {
    int i = blockIdx.x * blockDim.x + threadIdx.x;
    if (i < NN * C1) acc[i] = 0.f;
    if (i < NN * HEADS) { m[i] = -INFINITY; s[i] = 0.f; }
}
__global__ void init2_kernel(float* __restrict__ acc, float* __restrict__ m, float* __restrict__ s) {
    int i = blockIdx.x * blockDim.x + threadIdx.x;
    if (i < NN * HID) acc[i] = 0.f;
    if (i < NN) { m[i] = -INFINITY; s[i] = 0.f; }
}

// ---------------- conv1 edge passes ----------------
__global__ void edge_max1(const int* __restrict__ ei, const float* __restrict__ as_,
                          const float* __restrict__ ad_, float* __restrict__ m1) {
    int e = blockIdx.x * blockDim.x + threadIdx.x;
    if (e >= EP) return;
    int s, d;
    if (e < NE) { s = ei[e]; d = ei[NE + e]; } else { s = d = e - NE; }
    float4 av = *(const float4*)(as_ + s * 4);
    float4 bv = *(const float4*)(ad_ + d * 4);
    float t;
    t = av.x + bv.x; t = t > 0.f ? t : NEG * t; atomicMaxF(&m1[d * 4 + 0], t);
    t = av.y + bv.y; t = t > 0.f ? t : NEG * t; atomicMaxF(&m1[d * 4 + 1], t);
    t = av.z + bv.z; t = t > 0.f ? t : NEG * t; atomicMaxF(&m1[d * 4 + 2], t);
    t = av.w + bv.w; t = t > 0.f ? t : NEG * t; atomicMaxF(&m1[d * 4 + 3], t);
}

__global__ void edge_sum1(const int* __restrict__ ei, const float* __restrict__ as_,
                          const float* __restrict__ ad_, const float* __restrict__ m1,
                          float* __restrict__ s1) {
    int e = blockIdx.x * blockDim.x + threadIdx.x;
    if (e >= EP) return;
    int s, d;
    if (e < NE) { s = ei[e]; d = ei[NE + e]; } else { s = d = e - NE; }
    float4 av = *(const float4*)(as_ + s * 4);
    float4 bv = *(const float4*)(ad_ + d * 4);
    float4 mv = *(const float4*)(m1 + d * 4);
    float t;
    t = av.x + bv.x; t = t > 0.f ? t : NEG * t; atomicAdd(&s1[d * 4 + 0], expf(t - mv.x));
    t = av.y + bv.y; t = t > 0.f ? t : NEG * t; atomicAdd(&s1[d * 4 + 1], expf(t - mv.y));
    t = av.z + bv.z; t = t > 0.f ? t : NEG * t; atomicAdd(&s1[d * 4 + 2], expf(t - mv.z));
    t = av.w + bv.w; t = t > 0.f ? t : NEG * t; atomicAdd(&s1[d * 4 + 3], expf(t - mv.w));
}

// wave per edge; lane = channel within head
__global__ __launch_bounds__(256) void edge_scatter1(const int* __restrict__ ei,
                                                     const float* __restrict__ as_,
                                                     const float* __restrict__ ad_,
                                                     const float* __restrict__ m1,
                                                     const float* __restrict__ s1,
                                                     const float* __restrict__ h,
                                                     float* __restrict__ acc) {
    int wid = threadIdx.x >> 6;
    int lane = threadIdx.x & 63;
    int e = blockIdx.x * 4 + wid;
    if (e >= EP) return;
    int s, d;
    if (e < NE) { s = ei[e]; d = ei[NE + e]; } else { s = d = e - NE; }
    float4 av = *(const float4*)(as_ + s * 4);
    float4 bv = *(const float4*)(ad_ + d * 4);
    float4 mv = *(const float4*)(m1 + d * 4);
    float4 sv = *(const float4*)(s1 + d * 4);
    float t;
    t = av.x + bv.x; t = t > 0.f ? t : NEG * t; float al0 = expf(t - mv.x) / (sv.x + EPSS);
    t = av.y + bv.y; t = t > 0.f ? t : NEG * t; float al1 = expf(t - mv.y) / (sv.y + EPSS);
    t = av.z + bv.z; t = t > 0.f ? t : NEG * t; float al2 = expf(t - mv.z) / (sv.z + EPSS);
    t = av.w + bv.w; t = t > 0.f ? t : NEG * t; float al3 = expf(t - mv.w) / (sv.w + EPSS);
    const float* hs = h + s * C1;
    float* ap = acc + d * C1;
    atomicAdd(ap + lane,       al0 * hs[lane]);
    atomicAdd(ap + 64 + lane,  al1 * hs[64 + lane]);
    atomicAdd(ap + 128 + lane, al2 * hs[128 + lane]);
    atomicAdd(ap + 192 + lane, al3 * hs[192 + lane]);
}

__global__ void bias_elu1(float* __restrict__ a, const float* __restrict__ b) {
    int i = blockIdx.x * blockDim.x + threadIdx.x;
    if (i >= NN * C1) return;
    float v = a[i] + b[i & 255];
    a[i] = v > 0.f ? v : (expf(v) - 1.f);
}

// ---------------- conv2 edge passes ----------------
__global__ void edge_max2(const int* __restrict__ ei, const float* __restrict__ as_,
                          const float* __restrict__ ad_, float* __restrict__ m2) {
    int e = blockIdx.x * blockDim.x + threadIdx.x;
    if (e >= EP) return;
    int s, d;
    if (e < NE) { s = ei[e]; d = ei[NE + e]; } else { s = d = e - NE; }
    float t = as_[s] + ad_[d];
    t = t > 0.f ? t : NEG * t;
    atomicMaxF(&m2[d], t);
}

__global__ void edge_sum2(const int* __restrict__ ei, const float* __restrict__ as_,
                          const float* __restrict__ ad_, const float* __restrict__ m2,
                          float* __restrict__ s2) {
    int e = blockIdx.x * blockDim.x + threadIdx.x;
    if (e >= EP) return;
    int s, d;
    if (e < NE) { s = ei[e]; d = ei[NE + e]; } else { s = d = e - NE; }
    float t = as_[s] + ad_[d];
    t = t > 0.f ? t : NEG * t;
    atomicAdd(&s2[d], expf(t - m2[d]));
}

__global__ __launch_bounds__(256) void edge_scatter2(const int* __restrict__ ei,
                                                     const float* __restrict__ as_,
                                                     const float* __restrict__ ad_,
                                                     const float* __restrict__ m2,
                                                     const float* __restrict__ s2,
                                                     const float* __restrict__ h,
                                                     float* __restrict__ acc) {
    int wid = threadIdx.x >> 6;
    int lane = threadIdx.x & 63;
    int e = blockIdx.x * 4 + wid;
    if (e >= EP) return;
    int s, d;
    if (e < NE) { s = ei[e]; d = ei[NE + e]; } else { s = d = e - NE; }
    float t = as_[s] + ad_[d];
    t = t > 0.f ? t : NEG * t;
    float alpha = expf(t - m2[d]) / (s2[d] + EPSS);
    atomicAdd(&acc[d * HID + lane], alpha * h[s * HID + lane]);
}

__global__ void bias2_kernel(float* __restrict__ a, const float* __restrict__ b) {
    int i = blockIdx.x * blockDim.x + threadIdx.x;
    if (i >= NN * HID) return;
    a[i] = a[i] + b[i & 63];
}

// ---------------- edge MLP: LDS-tiled GEMM, 64 edges/block ----------------
// feat[e] = [emb[r], emb[c], stats[e]] (131), hidden = relu(feat@W1 + b1) (64),
// out = hidden@W2 + b2 (2). Thread tile: 4 edges x 4 cols; 16-lane shfl reduce
// for the 64->2 contraction.
__global__ __launch_bounds__(256) void edge_mlp_tiled(const int* __restrict__ ei,
                                                      const float* __restrict__ emb,
                                                      const float* __restrict__ stats,
                                                      const float* __restrict__ mW1,
                                                      const float* __restrict__ mb1,
                                                      const float* __restrict__ mW2,
                                                      const float* __restrict__ mb2,
                                                      float* __restrict__ out) {
    __shared__ float fS[131][64];   // feat^T  (k-major)
    __shared__ float wS[131][64];   // W1      (k-major, same layout as mW1)
    const int tid = threadIdx.x;
    const int e0 = blockIdx.x * 64;

    // W1 -> LDS (contiguous float4 copy; layouts identical)
    for (int idx = tid; idx < (131 * 64) / 4; idx += 256)
        ((float4*)wS)[idx] = ((const float4*)mW1)[idx];

    // gather feat^T: thread (e = tid&63, q = tid>>6) loads a 32-ch chunk
    {
        const int e = tid & 63;
        const int q = tid >> 6;          // 0,1: src-row chans; 2,3: dst-row chans
        const int ge = e0 + e;
        const int row = (q < 2) ? ei[ge] : ei[NE + ge];
        const int ch0 = (q & 1) * 32;
        const float* src = emb + row * HID + ch0;
        const int kbase = (q < 2 ? 0 : 64) + ch0;
#pragma unroll
        for (int i = 0; i < 8; ++i) {
            float4 v = *(const float4*)(src + i * 4);
            fS[kbase + i * 4 + 0][e] = v.x;
            fS[kbase + i * 4 + 1][e] = v.y;
            fS[kbase + i * 4 + 2][e] = v.z;
            fS[kbase + i * 4 + 3][e] = v.w;
        }
        if (q == 0) {
            fS[128][e] = stats[ge * 3 + 0];
            fS[129][e] = stats[ge * 3 + 1];
            fS[130][e] = stats[ge * 3 + 2];
        }
    }
    __syncthreads();

    const int jc = tid & 15;    // col group (4 cols)
    const int eg = tid >> 4;    // edge group (4 edges)

    float acc[4][4];
#pragma unroll
    for (int r = 0; r < 4; ++r)
#pragma unroll
        for (int j = 0; j < 4; ++j) acc[r][j] = mb1[jc * 4 + j];

#pragma unroll 4
    for (int k = 0; k < 131; ++k) {
        const float4 fv = *(const float4*)&fS[k][eg * 4];
        const float4 wv = *(const float4*)&wS[k][jc * 4];
        acc[0][0] += fv.x * wv.x; acc[0][1] += fv.x * wv.y; acc[0][2] += fv.x * wv.z; acc[0][3] += fv.x * wv.w;
        acc[1][0] += fv.y * wv.x; acc[1][1] += fv.y * wv.y; acc[1][2] += fv.y * wv.z; acc[1][3] += fv.y * wv.w;
        acc[2][0] += fv.z * wv.x; acc[2][1] += fv.z * wv.y; acc[2][2] += fv.z * wv.z; acc[2][3] += fv.z * wv.w;
        acc[3][0] += fv.w * wv.x; acc[3][1] += fv.w * wv.y; acc[3][2] += fv.w * wv.z; acc[3][3] += fv.w * wv.w;
    }

    // second layer: relu then contract 64 -> 2, reduce over the 16 lanes
    float w2a[4], w2b[4];
#pragma unroll
    for (int j = 0; j < 4; ++j) {
        w2a[j] = mW2[(jc * 4 + j) * 2 + 0];
        w2b[j] = mW2[(jc * 4 + j) * 2 + 1];
    }
    const float ob0 = mb2[0], ob1 = mb2[1];
#pragma unroll
    for (int r = 0; r < 4; ++r) {
        float s0 = 0.f, s1 = 0.f;
#pragma unroll
        for (int j = 0; j < 4; ++j) {
            float h = fmaxf(acc[r][j], 0.f);
            s0 += h * w2a[j];
            s1 += h * w2b[j];
        }
#pragma unroll
        for (int off = 8; off > 0; off >>= 1) {
            s0 += __shfl_xor(s0, off);
            s1 += __shfl_xor(s1, off);
        }
        if (jc == 0) {
            const int ge = e0 + eg * 4 + r;
            *(float2*)&out[ge * 2] = make_float2(s0 + ob0, s1 + ob1);
        }
    }
}

// ---------------- launcher ----------------
extern "C" void kernel_launch(void* const* d_in, const int* in_sizes, int n_in,
                              void* d_out, int out_size, void* d_ws, size_t ws_size,
                              hipStream_t stream) {
    const float* x      = (const float*)d_in[0];
    const int*   ei     = (const int*)d_in[1];
    const float* stats  = (const float*)d_in[2];
    const float* W1     = (const float*)d_in[3];
    const float* att_s1 = (const float*)d_in[4];
    const float* att_d1 = (const float*)d_in[5];
    const float* b1     = (const float*)d_in[6];
    const float* W2     = (const float*)d_in[7];
    const float* att_s2 = (const float*)d_in[8];
    const float* att_d2 = (const float*)d_in[9];
    const float* b2     = (const float*)d_in[10];
    const float* mW1    = (const float*)d_in[11];
    const float* mb1    = (const float*)d_in[12];
    const float* mW2    = (const float*)d_in[13];
    const float* mb2    = (const float*)d_in[14];
    float* out = (float*)d_out;
    float* ws  = (float*)d_ws;

    float* h1raw = ws;                              // NN*256
    float* h1    = ws + (size_t)NN * C1;            // NN*256  (acc1 -> h1)
    float* as1   = ws + (size_t)2 * NN * C1;        // NN*4
    float* ad1   = as1 + NN * 4;
    float* m1    = ad1 + NN * 4;
    float* s1    = m1 + NN * 4;
    // phase B reuses the h1raw region (h1raw dead after edge_scatter1)
    float* h2raw = h1raw;                           // NN*64
    float* acc2  = h1raw + (size_t)NN * HID;        // NN*64 (becomes node_emb)
    float* as2   = h1raw + (size_t)2 * NN * HID;    // NN
    float* ad2   = as2 + NN;
    float* m2    = ad2 + NN;
    float* s2    = m2 + NN;

    // ---- conv1 ----
    gemm1_kernel<<<dim3((NN + 31) / 32, 4), 256, 0, stream>>>(x, W1, h1raw);
    att1_kernel<<<(NN * HEADS + 255) / 256, 256, 0, stream>>>(h1raw, att_s1, att_d1, as1, ad1);
    init1_kernel<<<(NN * C1 + 255) / 256, 256, 0, stream>>>(h1, m1, s1);
    edge_max1<<<(EP + 255) / 256, 256, 0, stream>>>(ei, as1, ad1, m1);
    edge_sum1<<<(EP + 255) / 256, 256, 0, stream>>>(ei, as1, ad1, m1, s1);
    edge_scatter1<<<(EP + 3) / 4, 256, 0, stream>>>(ei, as1, ad1, m1, s1, h1raw, h1);
    bias_elu1<<<(NN * C1 + 255) / 256, 256, 0, stream>>>(h1, b1);

    // ---- conv2 ----
    gemm2_kernel<<<(NN + 31) / 32, 256, 0, stream>>>(h1, W2, h2raw);
    att2_kernel<<<(NN + 255) / 256, 256, 0, stream>>>(h2raw, att_s2, att_d2, as2, ad2);
    init2_kernel<<<(NN * HID + 255) / 256, 256, 0, stream>>>(acc2, m2, s2);
    edge_max2<<<(EP + 255) / 256, 256, 0, stream>>>(ei, as2, ad2, m2);
    edge_sum2<<<(EP + 255) / 256, 256, 0, stream>>>(ei, as2, ad2, m2, s2);
    edge_scatter2<<<(EP + 3) / 4, 256, 0, stream>>>(ei, as2, ad2, m2, s2, h2raw, acc2);
    bias2_kernel<<<(NN * HID + 255) / 256, 256, 0, stream>>>(acc2, b2);

    // ---- edge MLP ----
    edge_mlp_tiled<<<NE / 64, 256, 0, stream>>>(ei, acc2, stats, mW1, mb1, mW2, mb2, out);
}

// Round 3
// 818.845 us; speedup vs baseline: 3.3808x; 2.1796x over previous
//
#include <hip/hip_runtime.h>
#include <math.h>

#define NN 50000
#define NE 800000
#define EP (NE + NN)        // edges including self loops
#define INC 128
#define HID 64
#define HEADS 4
#define C1 (HEADS * HID)    // 256
#define NEG 0.2f
#define EPSS 1e-16f

#define SCHUNK 512
#define NSB ((NN + SCHUNK - 1) / SCHUNK)   // 98

// ================= CSR build =================
__global__ void csr_count(const int* __restrict__ ei, int* __restrict__ counts) {
    int e = blockIdx.x * 256 + threadIdx.x;
    if (e >= EP) return;
    int d = (e < NE) ? ei[NE + e] : (e - NE);
    atomicAdd(&counts[d], 1);
}

__global__ __launch_bounds__(SCHUNK) void scan_partial(const int* __restrict__ counts,
                                                       int* __restrict__ bsum) {
    __shared__ int lds[SCHUNK];
    int i = blockIdx.x * SCHUNK + threadIdx.x;
    lds[threadIdx.x] = (i < NN) ? counts[i] : 0;
    __syncthreads();
    for (int off = SCHUNK / 2; off > 0; off >>= 1) {
        if (threadIdx.x < off) lds[threadIdx.x] += lds[threadIdx.x + off];
        __syncthreads();
    }
    if (threadIdx.x == 0) bsum[blockIdx.x] = lds[0];
}

__global__ void scan_top(int* __restrict__ bsum, int* __restrict__ rowptr) {
    __shared__ int lds[NSB];
    int t = threadIdx.x;
    if (t < NSB) lds[t] = bsum[t];
    __syncthreads();
    if (t == 0) {
        int acc = 0;
        for (int i = 0; i < NSB; ++i) { int v = lds[i]; lds[i] = acc; acc += v; }
        rowptr[NN] = acc;   // == EP
    }
    __syncthreads();
    if (t < NSB) bsum[t] = lds[t];
}

__global__ __launch_bounds__(SCHUNK) void scan_final(const int* __restrict__ counts,
                                                     const int* __restrict__ bsum,
                                                     int* __restrict__ rowptr,
                                                     int* __restrict__ cursor) {
    __shared__ int lds[SCHUNK];
    int i = blockIdx.x * SCHUNK + threadIdx.x;
    int v = (i < NN) ? counts[i] : 0;
    lds[threadIdx.x] = v;
    __syncthreads();
    for (int off = 1; off < SCHUNK; off <<= 1) {
        int t = (threadIdx.x >= off) ? lds[threadIdx.x - off] : 0;
        __syncthreads();
        lds[threadIdx.x] += t;
        __syncthreads();
    }
    if (i < NN) {
        int excl = lds[threadIdx.x] - v + bsum[blockIdx.x];
        rowptr[i] = excl;
        cursor[i] = excl;
    }
}

__global__ void csr_fill(const int* __restrict__ ei, int* __restrict__ cursor,
                         int* __restrict__ csr_src) {
    int e = blockIdx.x * 256 + threadIdx.x;
    if (e >= EP) return;
    int s, d;
    if (e < NE) { s = ei[e]; d = ei[NE + e]; } else { s = d = e - NE; }
    int pos = atomicAdd(&cursor[d], 1);
    csr_src[pos] = s;
}

// ================= GEMMs =================
__global__ __launch_bounds__(256) void gemm1_kernel(const float* __restrict__ x,
                                                    const float* __restrict__ W,
                                                    float* __restrict__ out) {
    __shared__ float xs[32][128];
    __shared__ float ws[128][64];
    const int n0 = blockIdx.x * 32;
    const int c0 = blockIdx.y * 64;
    const int tid = threadIdx.x;

    for (int idx = tid; idx < 32 * 128; idx += 256) {
        int r = idx >> 7, k = idx & 127;
        int n = n0 + r;
        xs[r][k] = (n < NN) ? x[n * INC + k] : 0.f;
    }
    for (int idx = tid; idx < 128 * 64; idx += 256) {
        int k = idx >> 6, c = idx & 63;
        ws[k][c] = W[k * C1 + c0 + c];
    }
    __syncthreads();

    const int c = tid & 63;
    const int rg = tid >> 6;
    float acc[8] = {0.f, 0.f, 0.f, 0.f, 0.f, 0.f, 0.f, 0.f};
    for (int k = 0; k < 128; k += 4) {
        float w0 = ws[k][c], w1 = ws[k + 1][c], w2 = ws[k + 2][c], w3 = ws[k + 3][c];
#pragma unroll
        for (int r = 0; r < 8; ++r) {
            const float4 xv = *reinterpret_cast<const float4*>(&xs[rg * 8 + r][k]);
            acc[r] += xv.x * w0 + xv.y * w1 + xv.z * w2 + xv.w * w3;
        }
    }
#pragma unroll
    for (int r = 0; r < 8; ++r) {
        int n = n0 + rg * 8 + r;
        if (n < NN) out[n * C1 + c0 + c] = acc[r];
    }
}

__global__ __launch_bounds__(256) void gemm2_kernel(const float* __restrict__ x,
                                                    const float* __restrict__ W,
                                                    float* __restrict__ out) {
    __shared__ float xs[32][128];
    __shared__ float ws[128][64];
    const int n0 = blockIdx.x * 32;
    const int tid = threadIdx.x;
    const int c = tid & 63;
    const int rg = tid >> 6;
    float acc[8] = {0.f, 0.f, 0.f, 0.f, 0.f, 0.f, 0.f, 0.f};

    for (int kc = 0; kc < 256; kc += 128) {
        __syncthreads();
        for (int idx = tid; idx < 32 * 128; idx += 256) {
            int r = idx >> 7, k = idx & 127;
            int n = n0 + r;
            xs[r][k] = (n < NN) ? x[n * C1 + kc + k] : 0.f;
        }
        for (int idx = tid; idx < 128 * 64; idx += 256) {
            int k = idx >> 6, cc = idx & 63;
            ws[k][cc] = W[(kc + k) * HID + cc];
        }
        __syncthreads();
        for (int k = 0; k < 128; k += 4) {
            float w0 = ws[k][c], w1 = ws[k + 1][c], w2 = ws[k + 2][c], w3 = ws[k + 3][c];
#pragma unroll
            for (int r = 0; r < 8; ++r) {
                const float4 xv = *reinterpret_cast<const float4*>(&xs[rg * 8 + r][k]);
                acc[r] += xv.x * w0 + xv.y * w1 + xv.z * w2 + xv.w * w3;
            }
        }
    }
#pragma unroll
    for (int r = 0; r < 8; ++r) {
        int n = n0 + rg * 8 + r;
        if (n < NN) out[n * HID + c] = acc[r];
    }
}

// ================= attention logits =================
__global__ void att1_kernel(const float* __restrict__ h, const float* __restrict__ att_s,
                            const float* __restrict__ att_d,
                            float* __restrict__ as_, float* __restrict__ ad_) {
    int idx = blockIdx.x * blockDim.x + threadIdx.x;
    if (idx >= NN * HEADS) return;
    int n = idx >> 2, hd = idx & 3;
    const float* hp = h + n * C1 + hd * HID;
    const float* sp = att_s + hd * HID;
    const float* dp = att_d + hd * HID;
    float s = 0.f, d = 0.f;
    for (int c = 0; c < HID; c += 4) {
        float4 hv = *(const float4*)(hp + c);
        float4 sv = *(const float4*)(sp + c);
        float4 dv = *(const float4*)(dp + c);
        s += hv.x * sv.x + hv.y * sv.y + hv.z * sv.z + hv.w * sv.w;
        d += hv.x * dv.x + hv.y * dv.y + hv.z * dv.z + hv.w * dv.w;
    }
    as_[idx] = s;
    ad_[idx] = d;
}

__global__ void att2_kernel(const float* __restrict__ h, const float* __restrict__ att_s,
                            const float* __restrict__ att_d,
                            float* __restrict__ as_, float* __restrict__ ad_) {
    int n = blockIdx.x * blockDim.x + threadIdx.x;
    if (n >= NN) return;
    const float* hp = h + n * HID;
    float s = 0.f, d = 0.f;
    for (int c = 0; c < HID; c += 4) {
        float4 hv = *(const float4*)(hp + c);
        float4 sv = *(const float4*)(att_s + c);
        float4 dv = *(const float4*)(att_d + c);
        s += hv.x * sv.x + hv.y * sv.y + hv.z * sv.z + hv.w * sv.w;
        d += hv.x * dv.x + hv.y * dv.y + hv.z * dv.z + hv.w * dv.w;
    }
    as_[n] = s;
    ad_[n] = d;
}

// ================= conv1 fused aggregate (wave per node) =================
// out[n] = elu( sum_e alpha_e * h[src_e] + b1 )
__global__ __launch_bounds__(256) void conv1_agg(const int* __restrict__ rowptr,
                                                 const int* __restrict__ csr_src,
                                                 const float* __restrict__ as_,
                                                 const float* __restrict__ ad_,
                                                 const float* __restrict__ h,
                                                 const float* __restrict__ b1,
                                                 float* __restrict__ out) {
    const int node = blockIdx.x * 4 + (threadIdx.x >> 6);
    if (node >= NN) return;
    const int lane = threadIdx.x & 63;
    const int beg = rowptr[node], end = rowptr[node + 1];
    const float4 adv = *(const float4*)(ad_ + node * 4);

    // phase 1: per-head max
    float4 mx = make_float4(-INFINITY, -INFINITY, -INFINITY, -INFINITY);
    for (int i = beg + lane; i < end; i += 64) {
        int s = csr_src[i];
        float4 av = *(const float4*)(as_ + s * 4);
        float t;
        t = av.x + adv.x; t = t > 0.f ? t : NEG * t; mx.x = fmaxf(mx.x, t);
        t = av.y + adv.y; t = t > 0.f ? t : NEG * t; mx.y = fmaxf(mx.y, t);
        t = av.z + adv.z; t = t > 0.f ? t : NEG * t; mx.z = fmaxf(mx.z, t);
        t = av.w + adv.w; t = t > 0.f ? t : NEG * t; mx.w = fmaxf(mx.w, t);
    }
#pragma unroll
    for (int off = 32; off > 0; off >>= 1) {
        mx.x = fmaxf(mx.x, __shfl_xor(mx.x, off));
        mx.y = fmaxf(mx.y, __shfl_xor(mx.y, off));
        mx.z = fmaxf(mx.z, __shfl_xor(mx.z, off));
        mx.w = fmaxf(mx.w, __shfl_xor(mx.w, off));
    }

    // phase 2: per-head softmax denom
    float4 sm = make_float4(0.f, 0.f, 0.f, 0.f);
    for (int i = beg + lane; i < end; i += 64) {
        int s = csr_src[i];
        float4 av = *(const float4*)(as_ + s * 4);
        float t;
        t = av.x + adv.x; t = t > 0.f ? t : NEG * t; sm.x += __expf(t - mx.x);
        t = av.y + adv.y; t = t > 0.f ? t : NEG * t; sm.y += __expf(t - mx.y);
        t = av.z + adv.z; t = t > 0.f ? t : NEG * t; sm.z += __expf(t - mx.z);
        t = av.w + adv.w; t = t > 0.f ? t : NEG * t; sm.w += __expf(t - mx.w);
    }
#pragma unroll
    for (int off = 32; off > 0; off >>= 1) {
        sm.x += __shfl_xor(sm.x, off);
        sm.y += __shfl_xor(sm.y, off);
        sm.z += __shfl_xor(sm.z, off);
        sm.w += __shfl_xor(sm.w, off);
    }

    // this lane's head (4 channels lane*4..lane*4+3 all in head lane>>4)
    const int hd = lane >> 4;
    const float mh  = (hd & 2) ? ((hd & 1) ? mx.w : mx.z) : ((hd & 1) ? mx.y : mx.x);
    const float shd = (hd & 2) ? ((hd & 1) ? sm.w : sm.z) : ((hd & 1) ? sm.y : sm.x);
    const float adh = (hd & 2) ? ((hd & 1) ? adv.w : adv.z) : ((hd & 1) ? adv.y : adv.x);
    const float rdenom = 1.f / (shd + EPSS);

    // phase 3: gather-accumulate
    float4 acc = make_float4(0.f, 0.f, 0.f, 0.f);
    for (int i = beg; i < end; ++i) {
        int s = csr_src[i];
        float t = as_[s * 4 + hd] + adh;
        t = t > 0.f ? t : NEG * t;
        float alpha = __expf(t - mh) * rdenom;
        float4 hv = *(const float4*)(h + s * C1 + lane * 4);
        acc.x += alpha * hv.x;
        acc.y += alpha * hv.y;
        acc.z += alpha * hv.z;
        acc.w += alpha * hv.w;
    }

    // epilogue: bias + ELU
    float4 bv = *(const float4*)(b1 + lane * 4);
    float4 o;
    o.x = acc.x + bv.x; o.x = o.x > 0.f ? o.x : (__expf(o.x) - 1.f);
    o.y = acc.y + bv.y; o.y = o.y > 0.f ? o.y : (__expf(o.y) - 1.f);
    o.z = acc.z + bv.z; o.z = o.z > 0.f ? o.z : (__expf(o.z) - 1.f);
    o.w = acc.w + bv.w; o.w = o.w > 0.f ? o.w : (__expf(o.w) - 1.f);
    *(float4*)(out + node * C1 + lane * 4) = o;
}

// ================= conv2 fused aggregate (wave per node, 1 head) =================
__global__ __launch_bounds__(256) void conv2_agg(const int* __restrict__ rowptr,
                                                 const int* __restrict__ csr_src,
                                                 const float* __restrict__ as_,
                                                 const float* __restrict__ ad_,
                                                 const float* __restrict__ h,
                                                 const float* __restrict__ b2,
                                                 float* __restrict__ out) {
    const int node = blockIdx.x * 4 + (threadIdx.x >> 6);
    if (node >= NN) return;
    const int lane = threadIdx.x & 63;
    const int beg = rowptr[node], end = rowptr[node + 1];
    const float ad = ad_[node];

    float mx = -INFINITY;
    for (int i = beg + lane; i < end; i += 64) {
        float t = as_[csr_src[i]] + ad;
        t = t > 0.f ? t : NEG * t;
        mx = fmaxf(mx, t);
    }
#pragma unroll
    for (int off = 32; off > 0; off >>= 1) mx = fmaxf(mx, __shfl_xor(mx, off));

    float sm = 0.f;
    for (int i = beg + lane; i < end; i += 64) {
        float t = as_[csr_src[i]] + ad;
        t = t > 0.f ? t : NEG * t;
        sm += __expf(t - mx);
    }
#pragma unroll
    for (int off = 32; off > 0; off >>= 1) sm += __shfl_xor(sm, off);
    const float rdenom = 1.f / (sm + EPSS);

    float acc = 0.f;
    for (int i = beg; i < end; ++i) {
        int s = csr_src[i];
        float t = as_[s] + ad;
        t = t > 0.f ? t : NEG * t;
        float alpha = __expf(t - mx) * rdenom;
        acc += alpha * h[s * HID + lane];
    }
    out[node * HID + lane] = acc + b2[lane];
}

// ================= edge MLP (unchanged from R2) =================
__global__ __launch_bounds__(256) void edge_mlp_tiled(const int* __restrict__ ei,
                                                      const float* __restrict__ emb,
                                                      const float* __restrict__ stats,
                                                      const float* __restrict__ mW1,
                                                      const float* __restrict__ mb1,
                                                      const float* __restrict__ mW2,
                                                      const float* __restrict__ mb2,
                                                      float* __restrict__ out) {
    __shared__ float fS[131][64];
    __shared__ float wS[131][64];
    const int tid = threadIdx.x;
    const int e0 = blockIdx.x * 64;

    for (int idx = tid; idx < (131 * 64) / 4; idx += 256)
        ((float4*)wS)[idx] = ((const float4*)mW1)[idx];

    {
        const int e = tid & 63;
        const int q = tid >> 6;
        const int ge = e0 + e;
        const int row = (q < 2) ? ei[ge] : ei[NE + ge];
        const int ch0 = (q & 1) * 32;
        const float* src = emb + row * HID + ch0;
        const int kbase = (q < 2 ? 0 : 64) + ch0;
#pragma unroll
        for (int i = 0; i < 8; ++i) {
            float4 v = *(const float4*)(src + i * 4);
            fS[kbase + i * 4 + 0][e] = v.x;
            fS[kbase + i * 4 + 1][e] = v.y;
            fS[kbase + i * 4 + 2][e] = v.z;
            fS[kbase + i * 4 + 3][e] = v.w;
        }
        if (q == 0) {
            fS[128][e] = stats[ge * 3 + 0];
            fS[129][e] = stats[ge * 3 + 1];
            fS[130][e] = stats[ge * 3 + 2];
        }
    }
    __syncthreads();

    const int jc = tid & 15;
    const int eg = tid >> 4;

    float acc[4][4];
#pragma unroll
    for (int r = 0; r < 4; ++r)
#pragma unroll
        for (int j = 0; j < 4; ++j) acc[r][j] = mb1[jc * 4 + j];

#pragma unroll 4
    for (int k = 0; k < 131; ++k) {
        const float4 fv = *(const float4*)&fS[k][eg * 4];
        const float4 wv = *(const float4*)&wS[k][jc * 4];
        acc[0][0] += fv.x * wv.x; acc[0][1] += fv.x * wv.y; acc[0][2] += fv.x * wv.z; acc[0][3] += fv.x * wv.w;
        acc[1][0] += fv.y * wv.x; acc[1][1] += fv.y * wv.y; acc[1][2] += fv.y * wv.z; acc[1][3] += fv.y * wv.w;
        acc[2][0] += fv.z * wv.x; acc[2][1] += fv.z * wv.y; acc[2][2] += fv.z * wv.z; acc[2][3] += fv.z * wv.w;
        acc[3][0] += fv.w * wv.x; acc[3][1] += fv.w * wv.y; acc[3][2] += fv.w * wv.z; acc[3][3] += fv.w * wv.w;
    }

    float w2a[4], w2b[4];
#pragma unroll
    for (int j = 0; j < 4; ++j) {
        w2a[j] = mW2[(jc * 4 + j) * 2 + 0];
        w2b[j] = mW2[(jc * 4 + j) * 2 + 1];
    }
    const float ob0 = mb2[0], ob1 = mb2[1];
#pragma unroll
    for (int r = 0; r < 4; ++r) {
        float s0 = 0.f, s1 = 0.f;
#pragma unroll
        for (int j = 0; j < 4; ++j) {
            float h = fmaxf(acc[r][j], 0.f);
            s0 += h * w2a[j];
            s1 += h * w2b[j];
        }
#pragma unroll
        for (int off = 8; off > 0; off >>= 1) {
            s0 += __shfl_xor(s0, off);
            s1 += __shfl_xor(s1, off);
        }
        if (jc == 0) {
            const int ge = e0 + eg * 4 + r;
            *(float2*)&out[ge * 2] = make_float2(s0 + ob0, s1 + ob1);
        }
    }
}

// ================= launcher =================
extern "C" void kernel_launch(void* const* d_in, const int* in_sizes, int n_in,
                              void* d_out, int out_size, void* d_ws, size_t ws_size,
                              hipStream_t stream) {
    const float* x      = (const float*)d_in[0];
    const int*   ei     = (const int*)d_in[1];
    const float* stats  = (const float*)d_in[2];
    const float* W1     = (const float*)d_in[3];
    const float* att_s1 = (const float*)d_in[4];
    const float* att_d1 = (const float*)d_in[5];
    const float* b1     = (const float*)d_in[6];
    const float* W2     = (const float*)d_in[7];
    const float* att_s2 = (const float*)d_in[8];
    const float* att_d2 = (const float*)d_in[9];
    const float* b2     = (const float*)d_in[10];
    const float* mW1    = (const float*)d_in[11];
    const float* mb1    = (const float*)d_in[12];
    const float* mW2    = (const float*)d_in[13];
    const float* mb2    = (const float*)d_in[14];
    float* out = (float*)d_out;
    float* ws  = (float*)d_ws;

    // word-offset layout (4B units)
    int*   rowptr  = (int*)ws;                             // NN+1
    int*   csr_src = rowptr + NN + 16;                     // EP
    float* as1     = ws + (size_t)(NN + 16) + EP;          // NN*4
    float* ad1     = as1 + (size_t)NN * 4;                 // NN*4
    float* h1raw   = ad1 + (size_t)NN * 4;                 // NN*256
    float* h1      = h1raw + (size_t)NN * C1;              // NN*256
    // transient aliases (dead before their regions are written)
    int*   counts  = (int*)h1raw;                          // NN     (pre-gemm1)
    int*   bsum    = (int*)h1raw + NN + 16;                // NSB    (pre-gemm1)
    int*   cursor  = (int*)h1;                             // NN     (pre-conv1_agg)
    // conv2-phase aliases inside h1raw block (h1raw dead after conv1_agg)
    float* h2raw    = h1raw;                               // NN*64
    float* node_emb = h1raw + (size_t)NN * HID;            // NN*64
    float* as2      = h1raw + (size_t)2 * NN * HID;        // NN
    float* ad2      = as2 + NN;                            // NN

    // ---- CSR build ----
    hipMemsetAsync(counts, 0, NN * sizeof(int), stream);
    csr_count<<<(EP + 255) / 256, 256, 0, stream>>>(ei, counts);
    scan_partial<<<NSB, SCHUNK, 0, stream>>>(counts, bsum);
    scan_top<<<1, 128, 0, stream>>>(bsum, rowptr);
    scan_final<<<NSB, SCHUNK, 0, stream>>>(counts, bsum, rowptr, cursor);
    csr_fill<<<(EP + 255) / 256, 256, 0, stream>>>(ei, cursor, csr_src);

    // ---- conv1 ----
    gemm1_kernel<<<dim3((NN + 31) / 32, 4), 256, 0, stream>>>(x, W1, h1raw);
    att1_kernel<<<(NN * HEADS + 255) / 256, 256, 0, stream>>>(h1raw, att_s1, att_d1, as1, ad1);
    conv1_agg<<<(NN + 3) / 4, 256, 0, stream>>>(rowptr, csr_src, as1, ad1, h1raw, b1, h1);

    // ---- conv2 ----
    gemm2_kernel<<<(NN + 31) / 32, 256, 0, stream>>>(h1, W2, h2raw);
    att2_kernel<<<(NN + 255) / 256, 256, 0, stream>>>(h2raw, att_s2, att_d2, as2, ad2);
    conv2_agg<<<(NN + 3) / 4, 256, 0, stream>>>(rowptr, csr_src, as2, ad2, h2raw, b2, node_emb);

    // ---- edge MLP ----
    edge_mlp_tiled<<<NE / 64, 256, 0, stream>>>(ei, node_emb, stats, mW1, mb1, mW2, mb2, out);
}

// Round 5
// 673.505 us; speedup vs baseline: 4.1103x; 1.2158x over previous
//
#include <hip/hip_runtime.h>
#include <math.h>

#define NN 50000
#define NE 800000
#define EP (NE + NN)        // edges including self loops
#define INC 128
#define HID 64
#define HEADS 4
#define C1 (HEADS * HID)    // 256
#define NEG 0.2f
#define EPSS 1e-16f

#define SCHUNK 512
#define NSB ((NN + SCHUNK - 1) / SCHUNK)   // 98

#define KP 170              // W1^T storage stride (bf16 elems); compute K = 160
typedef __attribute__((ext_vector_type(8))) short bf16x8;
typedef __attribute__((ext_vector_type(4))) float f32x4;

// ---------- bf16 helpers ----------
__device__ __forceinline__ unsigned short f2bf(float f) {
    unsigned u = __float_as_uint(f);
    unsigned r = (u + 0x7FFFu + ((u >> 16) & 1u)) >> 16;
    return (unsigned short)r;
}
__device__ __forceinline__ float bf2f(unsigned short b) {
    return __uint_as_float(((unsigned)b) << 16);
}

// ================= CSR build =================
__global__ void csr_count(const int* __restrict__ ei, int* __restrict__ counts) {
    int e = blockIdx.x * 256 + threadIdx.x;
    if (e >= EP) return;
    int d = (e < NE) ? ei[NE + e] : (e - NE);
    atomicAdd(&counts[d], 1);
}

__global__ __launch_bounds__(SCHUNK) void scan_partial(const int* __restrict__ counts,
                                                       int* __restrict__ bsum) {
    __shared__ int lds[SCHUNK];
    int i = blockIdx.x * SCHUNK + threadIdx.x;
    lds[threadIdx.x] = (i < NN) ? counts[i] : 0;
    __syncthreads();
    for (int off = SCHUNK / 2; off > 0; off >>= 1) {
        if (threadIdx.x < off) lds[threadIdx.x] += lds[threadIdx.x + off];
        __syncthreads();
    }
    if (threadIdx.x == 0) bsum[blockIdx.x] = lds[0];
}

__global__ void scan_top(int* __restrict__ bsum, int* __restrict__ rowptr) {
    __shared__ int lds[NSB];
    int t = threadIdx.x;
    if (t < NSB) lds[t] = bsum[t];
    __syncthreads();
    if (t == 0) {
        int acc = 0;
        for (int i = 0; i < NSB; ++i) { int v = lds[i]; lds[i] = acc; acc += v; }
        rowptr[NN] = acc;   // == EP
    }
    __syncthreads();
    if (t < NSB) bsum[t] = lds[t];
}

__global__ __launch_bounds__(SCHUNK) void scan_final(const int* __restrict__ counts,
                                                     const int* __restrict__ bsum,
                                                     int* __restrict__ rowptr,
                                                     int* __restrict__ cursor) {
    __shared__ int lds[SCHUNK];
    int i = blockIdx.x * SCHUNK + threadIdx.x;
    int v = (i < NN) ? counts[i] : 0;
    lds[threadIdx.x] = v;
    __syncthreads();
    for (int off = 1; off < SCHUNK; off <<= 1) {
        int t = (threadIdx.x >= off) ? lds[threadIdx.x - off] : 0;
        __syncthreads();
        lds[threadIdx.x] += t;
        __syncthreads();
    }
    if (i < NN) {
        int excl = lds[threadIdx.x] - v + bsum[blockIdx.x];
        rowptr[i] = excl;
        cursor[i] = excl;
    }
}

__global__ void csr_fill(const int* __restrict__ ei, int* __restrict__ cursor,
                         int* __restrict__ csr_src) {
    int e = blockIdx.x * 256 + threadIdx.x;
    if (e >= EP) return;
    int s, d;
    if (e < NE) { s = ei[e]; d = ei[NE + e]; } else { s = d = e - NE; }
    int pos = atomicAdd(&cursor[d], 1);
    csr_src[pos] = s;
}

// ================= W1^T hi/lo bf16 prep for edge MLP =================
__global__ void prep_w(const float* __restrict__ mW1,
                       unsigned short* __restrict__ wTh,
                       unsigned short* __restrict__ wTl) {
    int i = blockIdx.x * 256 + threadIdx.x;
    if (i >= 64 * KP) return;
    int c = i / KP, k = i % KP;
    unsigned short h = 0, l = 0;
    if (k < 131) {
        float f = mW1[k * 64 + c];
        h = f2bf(f);
        l = f2bf(f - bf2f(h));
    }
    wTh[i] = h;
    wTl[i] = l;
}

// ================= GEMM1 + att1 fused: h1raw f32, as1/ad1 logits =============
__global__ __launch_bounds__(256) void gemm1_kernel(const float* __restrict__ x,
                                                    const float* __restrict__ W,
                                                    const float* __restrict__ att_s,
                                                    const float* __restrict__ att_d,
                                                    float* __restrict__ h1raw,
                                                    float* __restrict__ as1,
                                                    float* __restrict__ ad1) {
    __shared__ float xs[32][128];
    __shared__ float ws[128][64];
    const int n0 = blockIdx.x * 32;
    const int c0 = blockIdx.y * 64;     // head = blockIdx.y
    const int tid = threadIdx.x;

    for (int idx = tid; idx < 32 * 128; idx += 256) {
        int r = idx >> 7, k = idx & 127;
        int n = n0 + r;
        xs[r][k] = (n < NN) ? x[n * INC + k] : 0.f;
    }
    for (int idx = tid; idx < 128 * 64; idx += 256) {
        int k = idx >> 6, c = idx & 63;
        ws[k][c] = W[k * C1 + c0 + c];
    }
    __syncthreads();

    const int c = tid & 63;
    const int rg = tid >> 6;
    float acc[8] = {0.f, 0.f, 0.f, 0.f, 0.f, 0.f, 0.f, 0.f};
    for (int k = 0; k < 128; k += 4) {
        float w0 = ws[k][c], w1 = ws[k + 1][c], w2 = ws[k + 2][c], w3 = ws[k + 3][c];
#pragma unroll
        for (int r = 0; r < 8; ++r) {
            const float4 xv = *reinterpret_cast<const float4*>(&xs[rg * 8 + r][k]);
            acc[r] += xv.x * w0 + xv.y * w1 + xv.z * w2 + xv.w * w3;
        }
    }

    const float asc = att_s[c0 + c];
    const float adc = att_d[c0 + c];
#pragma unroll
    for (int r = 0; r < 8; ++r) {
        int n = n0 + rg * 8 + r;
        float sa = acc[r] * asc;
        float sd = acc[r] * adc;
#pragma unroll
        for (int off = 32; off > 0; off >>= 1) {
            sa += __shfl_xor(sa, off);
            sd += __shfl_xor(sd, off);
        }
        if (n < NN) {
            h1raw[(size_t)n * C1 + c0 + c] = acc[r];
            if (c == 0) { as1[n * 4 + blockIdx.y] = sa; ad1[n * 4 + blockIdx.y] = sd; }
        }
    }
}

// ================= GEMM2 + att2 fused: h2raw f32, as2/ad2 =====================
__global__ __launch_bounds__(256) void gemm2_kernel(const float* __restrict__ x,
                                                    const float* __restrict__ W,
                                                    const float* __restrict__ att_s,
                                                    const float* __restrict__ att_d,
                                                    float* __restrict__ h2raw,
                                                    float* __restrict__ as2,
                                                    float* __restrict__ ad2) {
    __shared__ float xs[32][128];
    __shared__ float ws[128][64];
    const int n0 = blockIdx.x * 32;
    const int tid = threadIdx.x;
    const int c = tid & 63;
    const int rg = tid >> 6;
    float acc[8] = {0.f, 0.f, 0.f, 0.f, 0.f, 0.f, 0.f, 0.f};

    for (int kc = 0; kc < 256; kc += 128) {
        __syncthreads();
        for (int idx = tid; idx < 32 * 128; idx += 256) {
            int r = idx >> 7, k = idx & 127;
            int n = n0 + r;
            xs[r][k] = (n < NN) ? x[(size_t)n * C1 + kc + k] : 0.f;
        }
        for (int idx = tid; idx < 128 * 64; idx += 256) {
            int k = idx >> 6, cc = idx & 63;
            ws[k][cc] = W[(kc + k) * HID + cc];
        }
        __syncthreads();
        for (int k = 0; k < 128; k += 4) {
            float w0 = ws[k][c], w1 = ws[k + 1][c], w2 = ws[k + 2][c], w3 = ws[k + 3][c];
#pragma unroll
            for (int r = 0; r < 8; ++r) {
                const float4 xv = *reinterpret_cast<const float4*>(&xs[rg * 8 + r][k]);
                acc[r] += xv.x * w0 + xv.y * w1 + xv.z * w2 + xv.w * w3;
            }
        }
    }

    const float asc = att_s[c];
    const float adc = att_d[c];
#pragma unroll
    for (int r = 0; r < 8; ++r) {
        int n = n0 + rg * 8 + r;
        float sa = acc[r] * asc;
        float sd = acc[r] * adc;
#pragma unroll
        for (int off = 32; off > 0; off >>= 1) {
            sa += __shfl_xor(sa, off);
            sd += __shfl_xor(sd, off);
        }
        if (n < NN) {
            h2raw[(size_t)n * HID + c] = acc[r];
            if (c == 0) { as2[n] = sa; ad2[n] = sd; }
        }
    }
}

// ================= conv1 fused aggregate (wave per node, f32) =================
__global__ __launch_bounds__(256) void conv1_agg(const int* __restrict__ rowptr,
                                                 const int* __restrict__ csr_src,
                                                 const float* __restrict__ as_,
                                                 const float* __restrict__ ad_,
                                                 const float* __restrict__ h,
                                                 const float* __restrict__ b1,
                                                 float* __restrict__ out) {
    const int node = blockIdx.x * 4 + (threadIdx.x >> 6);
    if (node >= NN) return;
    const int lane = threadIdx.x & 63;
    const int beg = rowptr[node], end = rowptr[node + 1];
    const float4 adv = *(const float4*)(ad_ + node * 4);

    float4 mx = make_float4(-INFINITY, -INFINITY, -INFINITY, -INFINITY);
    for (int i = beg + lane; i < end; i += 64) {
        int s = csr_src[i];
        float4 av = *(const float4*)(as_ + s * 4);
        float t;
        t = av.x + adv.x; t = t > 0.f ? t : NEG * t; mx.x = fmaxf(mx.x, t);
        t = av.y + adv.y; t = t > 0.f ? t : NEG * t; mx.y = fmaxf(mx.y, t);
        t = av.z + adv.z; t = t > 0.f ? t : NEG * t; mx.z = fmaxf(mx.z, t);
        t = av.w + adv.w; t = t > 0.f ? t : NEG * t; mx.w = fmaxf(mx.w, t);
    }
#pragma unroll
    for (int off = 32; off > 0; off >>= 1) {
        mx.x = fmaxf(mx.x, __shfl_xor(mx.x, off));
        mx.y = fmaxf(mx.y, __shfl_xor(mx.y, off));
        mx.z = fmaxf(mx.z, __shfl_xor(mx.z, off));
        mx.w = fmaxf(mx.w, __shfl_xor(mx.w, off));
    }

    float4 sm = make_float4(0.f, 0.f, 0.f, 0.f);
    for (int i = beg + lane; i < end; i += 64) {
        int s = csr_src[i];
        float4 av = *(const float4*)(as_ + s * 4);
        float t;
        t = av.x + adv.x; t = t > 0.f ? t : NEG * t; sm.x += __expf(t - mx.x);
        t = av.y + adv.y; t = t > 0.f ? t : NEG * t; sm.y += __expf(t - mx.y);
        t = av.z + adv.z; t = t > 0.f ? t : NEG * t; sm.z += __expf(t - mx.z);
        t = av.w + adv.w; t = t > 0.f ? t : NEG * t; sm.w += __expf(t - mx.w);
    }
#pragma unroll
    for (int off = 32; off > 0; off >>= 1) {
        sm.x += __shfl_xor(sm.x, off);
        sm.y += __shfl_xor(sm.y, off);
        sm.z += __shfl_xor(sm.z, off);
        sm.w += __shfl_xor(sm.w, off);
    }

    const int hd = lane >> 4;
    const float mh  = (hd & 2) ? ((hd & 1) ? mx.w : mx.z) : ((hd & 1) ? mx.y : mx.x);
    const float shd = (hd & 2) ? ((hd & 1) ? sm.w : sm.z) : ((hd & 1) ? sm.y : sm.x);
    const float adh = (hd & 2) ? ((hd & 1) ? adv.w : adv.z) : ((hd & 1) ? adv.y : adv.x);
    const float rdenom = 1.f / (shd + EPSS);

    float4 acc = make_float4(0.f, 0.f, 0.f, 0.f);
    for (int i = beg; i < end; ++i) {
        int s = csr_src[i];
        float t = as_[s * 4 + hd] + adh;
        t = t > 0.f ? t : NEG * t;
        float alpha = __expf(t - mh) * rdenom;
        float4 hv = *(const float4*)(h + (size_t)s * C1 + lane * 4);
        acc.x += alpha * hv.x;
        acc.y += alpha * hv.y;
        acc.z += alpha * hv.z;
        acc.w += alpha * hv.w;
    }

    float4 bv = *(const float4*)(b1 + lane * 4);
    float4 o;
    o.x = acc.x + bv.x; o.x = o.x > 0.f ? o.x : (__expf(o.x) - 1.f);
    o.y = acc.y + bv.y; o.y = o.y > 0.f ? o.y : (__expf(o.y) - 1.f);
    o.z = acc.z + bv.z; o.z = o.z > 0.f ? o.z : (__expf(o.z) - 1.f);
    o.w = acc.w + bv.w; o.w = o.w > 0.f ? o.w : (__expf(o.w) - 1.f);
    *(float4*)(out + (size_t)node * C1 + lane * 4) = o;
}

// ================= conv2 fused aggregate (wave per node, 1 head, f32) =========
__global__ __launch_bounds__(256) void conv2_agg(const int* __restrict__ rowptr,
                                                 const int* __restrict__ csr_src,
                                                 const float* __restrict__ as_,
                                                 const float* __restrict__ ad_,
                                                 const float* __restrict__ h,
                                                 const float* __restrict__ b2,
                                                 float* __restrict__ emb) {
    const int node = blockIdx.x * 4 + (threadIdx.x >> 6);
    if (node >= NN) return;
    const int lane = threadIdx.x & 63;
    const int beg = rowptr[node], end = rowptr[node + 1];
    const float ad = ad_[node];

    float mx = -INFINITY;
    for (int i = beg + lane; i < end; i += 64) {
        float t = as_[csr_src[i]] + ad;
        t = t > 0.f ? t : NEG * t;
        mx = fmaxf(mx, t);
    }
#pragma unroll
    for (int off = 32; off > 0; off >>= 1) mx = fmaxf(mx, __shfl_xor(mx, off));

    float sm = 0.f;
    for (int i = beg + lane; i < end; i += 64) {
        float t = as_[csr_src[i]] + ad;
        t = t > 0.f ? t : NEG * t;
        sm += __expf(t - mx);
    }
#pragma unroll
    for (int off = 32; off > 0; off >>= 1) sm += __shfl_xor(sm, off);
    const float rdenom = 1.f / (sm + EPSS);

    float acc = 0.f;
    for (int i = beg; i < end; ++i) {
        int s = csr_src[i];
        float t = as_[s] + ad;
        t = t > 0.f ? t : NEG * t;
        float alpha = __expf(t - mx) * rdenom;
        acc += alpha * h[(size_t)s * HID + lane];
    }
    emb[(size_t)node * HID + lane] = acc + b2[lane];
}

// ================= edge MLP: split-bf16 3-product MFMA =================
// hidden = relu(feat @ W1 + b1), out = hidden @ W2 + b2.
// feat split in registers (fH+fL), W1 hi/lo staged in LDS. Residual ~2^-18.
__global__ __launch_bounds__(256) void edge_mlp_mfma(const int* __restrict__ ei,
                                                     const float* __restrict__ emb,
                                                     const float* __restrict__ stats,
                                                     const unsigned short* __restrict__ wTh,
                                                     const unsigned short* __restrict__ wTl,
                                                     const float* __restrict__ mb1,
                                                     const float* __restrict__ mW2,
                                                     const float* __restrict__ mb2,
                                                     float* __restrict__ out) {
    __shared__ unsigned short wH[64 * KP];
    __shared__ unsigned short wL[64 * KP];
    const int tid = threadIdx.x;
    const int e0 = blockIdx.x * 64;

    for (int idx = tid; idx < (64 * KP) / 8; idx += 256) {
        ((float4*)wH)[idx] = ((const float4*)wTh)[idx];
        ((float4*)wL)[idx] = ((const float4*)wTl)[idx];
    }

    const int w  = tid >> 6;      // wave: A-rows (edges) w*16..w*16+15
    const int l  = tid & 63;
    const int cl = l & 15;        // A row / B col / D col
    const int g  = l >> 4;        // k-group; D row group
    const int g8 = g * 8;
    const int arow = w * 16 + cl;
    const int ge_a = e0 + arow;

    // per-lane feat slices (f32) from global
    const int rn = ei[ge_a];
    const int cn = ei[NE + ge_a];
    const float* rp = emb + (size_t)rn * HID;
    const float* cp = emb + (size_t)cn * HID;
    float4 r0a = *(const float4*)(rp + g8);
    float4 r0b = *(const float4*)(rp + g8 + 4);
    float4 r1a = *(const float4*)(rp + 32 + g8);
    float4 r1b = *(const float4*)(rp + 32 + g8 + 4);
    float4 c0a = *(const float4*)(cp + g8);
    float4 c0b = *(const float4*)(cp + g8 + 4);
    float4 c1a = *(const float4*)(cp + 32 + g8);
    float4 c1b = *(const float4*)(cp + 32 + g8 + 4);
    float s0 = 0.f, s1 = 0.f, s2 = 0.f;
    if (g == 0) {
        s0 = stats[(size_t)ge_a * 3 + 0];
        s1 = stats[(size_t)ge_a * 3 + 1];
        s2 = stats[(size_t)ge_a * 3 + 2];
    }

    // build hi/lo A-fragments for kk=0..4
    bf16x8 aH[5], aL[5];
    float vs[40];
    vs[0]=r0a.x; vs[1]=r0a.y; vs[2]=r0a.z; vs[3]=r0a.w; vs[4]=r0b.x; vs[5]=r0b.y; vs[6]=r0b.z; vs[7]=r0b.w;
    vs[8]=r1a.x; vs[9]=r1a.y; vs[10]=r1a.z; vs[11]=r1a.w; vs[12]=r1b.x; vs[13]=r1b.y; vs[14]=r1b.z; vs[15]=r1b.w;
    vs[16]=c0a.x; vs[17]=c0a.y; vs[18]=c0a.z; vs[19]=c0a.w; vs[20]=c0b.x; vs[21]=c0b.y; vs[22]=c0b.z; vs[23]=c0b.w;
    vs[24]=c1a.x; vs[25]=c1a.y; vs[26]=c1a.z; vs[27]=c1a.w; vs[28]=c1b.x; vs[29]=c1b.y; vs[30]=c1b.z; vs[31]=c1b.w;
    vs[32]=s0; vs[33]=s1; vs[34]=s2; vs[35]=0.f; vs[36]=0.f; vs[37]=0.f; vs[38]=0.f; vs[39]=0.f;
#pragma unroll
    for (int kk = 0; kk < 5; ++kk) {
#pragma unroll
        for (int j = 0; j < 8; ++j) {
            float v = vs[kk * 8 + j];
            unsigned short h = f2bf(v);
            aH[kk][j] = (short)h;
            aL[kk][j] = (short)f2bf(v - bf2f(h));
        }
    }

    // accumulators: 4 col-tiles, bias in C
    f32x4 acc[4];
#pragma unroll
    for (int ct = 0; ct < 4; ++ct) {
        float b = mb1[ct * 16 + cl];
        acc[ct] = (f32x4){b, b, b, b};
    }

    __syncthreads();

#pragma unroll
    for (int kk = 0; kk < 5; ++kk) {
        const int ko = kk * 32 + g8;
#pragma unroll
        for (int ct = 0; ct < 4; ++ct) {
            const bf16x8 bH = *(const bf16x8*)(wH + (ct * 16 + cl) * KP + ko);
            const bf16x8 bL = *(const bf16x8*)(wL + (ct * 16 + cl) * KP + ko);
            acc[ct] = __builtin_amdgcn_mfma_f32_16x16x32_bf16(aH[kk], bH, acc[ct], 0, 0, 0);
            acc[ct] = __builtin_amdgcn_mfma_f32_16x16x32_bf16(aH[kk], bL, acc[ct], 0, 0, 0);
            acc[ct] = __builtin_amdgcn_mfma_f32_16x16x32_bf16(aL[kk], bH, acc[ct], 0, 0, 0);
        }
    }

    // layer 2: relu, contract 64 -> 2, reduce over 16 lanes of the group
    float w2a[4], w2b[4];
#pragma unroll
    for (int ct = 0; ct < 4; ++ct) {
        w2a[ct] = mW2[(ct * 16 + cl) * 2 + 0];
        w2b[ct] = mW2[(ct * 16 + cl) * 2 + 1];
    }
    const float ob0 = mb2[0], ob1 = mb2[1];

#pragma unroll
    for (int reg = 0; reg < 4; ++reg) {
        float p0 = 0.f, p1 = 0.f;
#pragma unroll
        for (int ct = 0; ct < 4; ++ct) {
            float h = fmaxf(acc[ct][reg], 0.f);
            p0 += h * w2a[ct];
            p1 += h * w2b[ct];
        }
#pragma unroll
        for (int off = 8; off > 0; off >>= 1) {
            p0 += __shfl_xor(p0, off);
            p1 += __shfl_xor(p1, off);
        }
        if (cl == 0) {
            const int ge = e0 + w * 16 + g * 4 + reg;
            *(float2*)(out + (size_t)ge * 2) = make_float2(p0 + ob0, p1 + ob1);
        }
    }
}

// ================= launcher =================
extern "C" void kernel_launch(void* const* d_in, const int* in_sizes, int n_in,
                              void* d_out, int out_size, void* d_ws, size_t ws_size,
                              hipStream_t stream) {
    const float* x      = (const float*)d_in[0];
    const int*   ei     = (const int*)d_in[1];
    const float* stats  = (const float*)d_in[2];
    const float* W1     = (const float*)d_in[3];
    const float* att_s1 = (const float*)d_in[4];
    const float* att_d1 = (const float*)d_in[5];
    const float* b1     = (const float*)d_in[6];
    const float* W2     = (const float*)d_in[7];
    const float* att_s2 = (const float*)d_in[8];
    const float* att_d2 = (const float*)d_in[9];
    const float* b2     = (const float*)d_in[10];
    const float* mW1    = (const float*)d_in[11];
    const float* mb1    = (const float*)d_in[12];
    const float* mW2    = (const float*)d_in[13];
    const float* mb2    = (const float*)d_in[14];
    float* out = (float*)d_out;
    float* ws  = (float*)d_ws;

    // float-offset layout
    int*   rowptr  = (int*)ws;                                 // NN+1 (+pad)
    int*   csr_src = rowptr + NN + 16;                         // EP
    float* as1     = ws + (size_t)(NN + 16) + EP;              // 4NN
    float* ad1     = as1 + (size_t)4 * NN;                     // 4NN
    float* h1raw   = ad1 + (size_t)4 * NN;                     // 256NN
    float* h1      = h1raw + (size_t)256 * NN;                 // 256NN
    unsigned short* wTh = (unsigned short*)(h1 + (size_t)256 * NN);  // 64*KP bf16
    unsigned short* wTl = wTh + 64 * KP;                             // 64*KP bf16
    // conv2-phase aliases inside h1raw (h1raw dead after conv1_agg)
    float* h2raw    = h1raw;                                   // 64NN
    float* node_emb = h1raw + (size_t)64 * NN;                 // 64NN
    float* as2      = h1raw + (size_t)128 * NN;                // NN
    float* ad2      = as2 + NN;                                // NN
    // transient ints inside h1 region (dead before conv1_agg writes h1)
    int*   counts  = (int*)h1;                                 // NN
    int*   bsum    = (int*)h1 + NN + 64;                       // NSB
    int*   cursor  = (int*)h1 + NN + 64 + NSB + 64;            // NN

    // ---- CSR build + W prep ----
    hipMemsetAsync(counts, 0, NN * sizeof(int), stream);
    prep_w<<<(64 * KP + 255) / 256, 256, 0, stream>>>(mW1, wTh, wTl);
    csr_count<<<(EP + 255) / 256, 256, 0, stream>>>(ei, counts);
    scan_partial<<<NSB, SCHUNK, 0, stream>>>(counts, bsum);
    scan_top<<<1, 128, 0, stream>>>(bsum, rowptr);
    scan_final<<<NSB, SCHUNK, 0, stream>>>(counts, bsum, rowptr, cursor);
    csr_fill<<<(EP + 255) / 256, 256, 0, stream>>>(ei, cursor, csr_src);

    // ---- conv1 ----
    gemm1_kernel<<<dim3((NN + 31) / 32, 4), 256, 0, stream>>>(x, W1, att_s1, att_d1,
                                                              h1raw, as1, ad1);
    conv1_agg<<<(NN + 3) / 4, 256, 0, stream>>>(rowptr, csr_src, as1, ad1, h1raw, b1, h1);

    // ---- conv2 ----
    gemm2_kernel<<<(NN + 31) / 32, 256, 0, stream>>>(h1, W2, att_s2, att_d2,
                                                     h2raw, as2, ad2);
    conv2_agg<<<(NN + 3) / 4, 256, 0, stream>>>(rowptr, csr_src, as2, ad2, h2raw, b2, node_emb);

    // ---- edge MLP ----
    edge_mlp_mfma<<<NE / 64, 256, 0, stream>>>(ei, node_emb, stats, wTh, wTl,
                                               mb1, mW2, mb2, out);
}

// Round 6
// 522.417 us; speedup vs baseline: 5.2991x; 1.2892x over previous
//
#include <hip/hip_runtime.h>
#include <math.h>

#define NN 50000
#define NE 800000
#define EP (NE + NN)        // edges including self loops
#define INC 128
#define HID 64
#define HEADS 4
#define C1 (HEADS * HID)    // 256
#define NEG 0.2f
#define EPSS 1e-16f

#define SCHUNK 512
#define NSB ((NN + SCHUNK - 1) / SCHUNK)   // 98

#define KP  170             // edge-MLP W1^T storage stride (bf16 elems); K = 160
#define KP1 136             // gemm1 W1^T LDS stride (bf16), 272B: 16B-aligned, 2-way banks
#define KP2 264             // gemm2 W2^T LDS stride (bf16), 528B: 16B-aligned, 2-way banks
typedef __attribute__((ext_vector_type(8))) short bf16x8;
typedef __attribute__((ext_vector_type(4))) float f32x4;

// ---------- bf16 helpers ----------
__device__ __forceinline__ unsigned short f2bf(float f) {
    unsigned u = __float_as_uint(f);
    unsigned r = (u + 0x7FFFu + ((u >> 16) & 1u)) >> 16;
    return (unsigned short)r;
}
__device__ __forceinline__ float bf2f(unsigned short b) {
    return __uint_as_float(((unsigned)b) << 16);
}

// ================= CSR build =================
__global__ void csr_count(const int* __restrict__ ei, int* __restrict__ counts) {
    int e = blockIdx.x * 256 + threadIdx.x;
    if (e >= EP) return;
    int d = (e < NE) ? ei[NE + e] : (e - NE);
    atomicAdd(&counts[d], 1);
}

__global__ __launch_bounds__(SCHUNK) void scan_partial(const int* __restrict__ counts,
                                                       int* __restrict__ bsum) {
    __shared__ int lds[SCHUNK];
    int i = blockIdx.x * SCHUNK + threadIdx.x;
    lds[threadIdx.x] = (i < NN) ? counts[i] : 0;
    __syncthreads();
    for (int off = SCHUNK / 2; off > 0; off >>= 1) {
        if (threadIdx.x < off) lds[threadIdx.x] += lds[threadIdx.x + off];
        __syncthreads();
    }
    if (threadIdx.x == 0) bsum[blockIdx.x] = lds[0];
}

__global__ void scan_top(int* __restrict__ bsum, int* __restrict__ rowptr) {
    __shared__ int lds[NSB];
    int t = threadIdx.x;
    if (t < NSB) lds[t] = bsum[t];
    __syncthreads();
    if (t == 0) {
        int acc = 0;
        for (int i = 0; i < NSB; ++i) { int v = lds[i]; lds[i] = acc; acc += v; }
        rowptr[NN] = acc;   // == EP
    }
    __syncthreads();
    if (t < NSB) bsum[t] = lds[t];
}

__global__ __launch_bounds__(SCHUNK) void scan_final(const int* __restrict__ counts,
                                                     const int* __restrict__ bsum,
                                                     int* __restrict__ rowptr,
                                                     int* __restrict__ cursor) {
    __shared__ int lds[SCHUNK];
    int i = blockIdx.x * SCHUNK + threadIdx.x;
    int v = (i < NN) ? counts[i] : 0;
    lds[threadIdx.x] = v;
    __syncthreads();
    for (int off = 1; off < SCHUNK; off <<= 1) {
        int t = (threadIdx.x >= off) ? lds[threadIdx.x - off] : 0;
        __syncthreads();
        lds[threadIdx.x] += t;
        __syncthreads();
    }
    if (i < NN) {
        int excl = lds[threadIdx.x] - v + bsum[blockIdx.x];
        rowptr[i] = excl;
        cursor[i] = excl;
    }
}

__global__ void csr_fill(const int* __restrict__ ei, int* __restrict__ cursor,
                         int* __restrict__ csr_src) {
    int e = blockIdx.x * 256 + threadIdx.x;
    if (e >= EP) return;
    int s, d;
    if (e < NE) { s = ei[e]; d = ei[NE + e]; } else { s = d = e - NE; }
    int pos = atomicAdd(&cursor[d], 1);
    csr_src[pos] = s;
}

// ================= weight prep (hi/lo bf16 transposes) =================
__global__ void prep_w(const float* __restrict__ mW1,
                       unsigned short* __restrict__ wTh,
                       unsigned short* __restrict__ wTl) {
    int i = blockIdx.x * 256 + threadIdx.x;
    if (i >= 64 * KP) return;
    int c = i / KP, k = i % KP;
    unsigned short h = 0, l = 0;
    if (k < 131) {
        float f = mW1[k * 64 + c];
        h = f2bf(f);
        l = f2bf(f - bf2f(h));
    }
    wTh[i] = h;
    wTl[i] = l;
}

__global__ void prep_w1(const float* __restrict__ W1,
                        unsigned short* __restrict__ w1h,
                        unsigned short* __restrict__ w1l) {
    int i = blockIdx.x * 256 + threadIdx.x;
    if (i >= C1 * INC) return;          // [256 cols][128 k]
    int c = i >> 7, k = i & 127;
    float f = W1[k * C1 + c];
    unsigned short h = f2bf(f);
    w1h[i] = h;
    w1l[i] = f2bf(f - bf2f(h));
}

__global__ void prep_w2(const float* __restrict__ W2,
                        unsigned short* __restrict__ w2h,
                        unsigned short* __restrict__ w2l) {
    int i = blockIdx.x * 256 + threadIdx.x;
    if (i >= HID * C1) return;          // [64 cols][256 k]
    int c = i >> 8, k = i & 255;
    float f = W2[k * HID + c];
    unsigned short h = f2bf(f);
    w2h[i] = h;
    w2l[i] = f2bf(f - bf2f(h));
}

// ================= GEMM1 via split-bf16 MFMA + att1 epilogue =================
// block: 64 nodes x 64 cols (head q = blockIdx.y); K = 128.
__global__ __launch_bounds__(256) void gemm1_mfma(const float* __restrict__ x,
                                                  const unsigned short* __restrict__ w1h,
                                                  const unsigned short* __restrict__ w1l,
                                                  const float* __restrict__ att_s,
                                                  const float* __restrict__ att_d,
                                                  float* __restrict__ h1raw,
                                                  float* __restrict__ as1,
                                                  float* __restrict__ ad1) {
    __shared__ unsigned short wH[64 * KP1];
    __shared__ unsigned short wL[64 * KP1];
    const int tid = threadIdx.x;
    const int n0 = blockIdx.x * 64;
    const int q  = blockIdx.y;

    for (int idx = tid; idx < 64 * 16; idx += 256) {   // 64 cols x 16 chunks x 8 bf16
        int col = idx >> 4, ch = idx & 15;
        *(bf16x8*)(wH + col * KP1 + ch * 8) =
            *(const bf16x8*)(w1h + ((q * 64 + col) << 7) + ch * 8);
        *(bf16x8*)(wL + col * KP1 + ch * 8) =
            *(const bf16x8*)(w1l + ((q * 64 + col) << 7) + ch * 8);
    }

    const int w = tid >> 6, l = tid & 63;
    const int cl = l & 15, g = l >> 4, g8 = g * 8;
    const int na = min(n0 + w * 16 + cl, NN - 1);

    bf16x8 aH[4], aL[4];
#pragma unroll
    for (int kk = 0; kk < 4; ++kk) {
        const float* ap = x + (size_t)na * INC + kk * 32 + g8;
        float4 v0 = *(const float4*)ap;
        float4 v1 = *(const float4*)(ap + 4);
        float vv[8] = {v0.x, v0.y, v0.z, v0.w, v1.x, v1.y, v1.z, v1.w};
#pragma unroll
        for (int j = 0; j < 8; ++j) {
            unsigned short h = f2bf(vv[j]);
            aH[kk][j] = (short)h;
            aL[kk][j] = (short)f2bf(vv[j] - bf2f(h));
        }
    }

    f32x4 acc[4];
#pragma unroll
    for (int ct = 0; ct < 4; ++ct) acc[ct] = (f32x4){0.f, 0.f, 0.f, 0.f};

    __syncthreads();

#pragma unroll
    for (int kk = 0; kk < 4; ++kk) {
        const int ko = kk * 32 + g8;
#pragma unroll
        for (int ct = 0; ct < 4; ++ct) {
            const bf16x8 bH = *(const bf16x8*)(wH + (ct * 16 + cl) * KP1 + ko);
            const bf16x8 bL = *(const bf16x8*)(wL + (ct * 16 + cl) * KP1 + ko);
            acc[ct] = __builtin_amdgcn_mfma_f32_16x16x32_bf16(aH[kk], bH, acc[ct], 0, 0, 0);
            acc[ct] = __builtin_amdgcn_mfma_f32_16x16x32_bf16(aH[kk], bL, acc[ct], 0, 0, 0);
            acc[ct] = __builtin_amdgcn_mfma_f32_16x16x32_bf16(aL[kk], bH, acc[ct], 0, 0, 0);
        }
    }

    float asc[4], adc[4];
#pragma unroll
    for (int ct = 0; ct < 4; ++ct) {
        asc[ct] = att_s[q * 64 + ct * 16 + cl];
        adc[ct] = att_d[q * 64 + ct * 16 + cl];
    }

#pragma unroll
    for (int reg = 0; reg < 4; ++reg) {
        const int nd = n0 + w * 16 + g * 4 + reg;
        float sa = 0.f, sd = 0.f;
#pragma unroll
        for (int ct = 0; ct < 4; ++ct) {
            sa += acc[ct][reg] * asc[ct];
            sd += acc[ct][reg] * adc[ct];
        }
#pragma unroll
        for (int off = 8; off > 0; off >>= 1) {
            sa += __shfl_xor(sa, off);
            sd += __shfl_xor(sd, off);
        }
        if (nd < NN) {
#pragma unroll
            for (int ct = 0; ct < 4; ++ct)
                h1raw[(size_t)nd * C1 + q * 64 + ct * 16 + cl] = acc[ct][reg];
            if (cl == 0) { as1[nd * 4 + q] = sa; ad1[nd * 4 + q] = sd; }
        }
    }
}

// ================= GEMM2 via split-bf16 MFMA + att2 epilogue =================
// block: 64 nodes x 64 cols; K = 256.
__global__ __launch_bounds__(256) void gemm2_mfma(const float* __restrict__ h1,
                                                  const unsigned short* __restrict__ w2h,
                                                  const unsigned short* __restrict__ w2l,
                                                  const float* __restrict__ att_s,
                                                  const float* __restrict__ att_d,
                                                  float* __restrict__ h2raw,
                                                  float* __restrict__ as2,
                                                  float* __restrict__ ad2) {
    __shared__ unsigned short wH[64 * KP2];
    __shared__ unsigned short wL[64 * KP2];
    const int tid = threadIdx.x;
    const int n0 = blockIdx.x * 64;

    for (int idx = tid; idx < 64 * 32; idx += 256) {   // 64 cols x 32 chunks x 8 bf16
        int col = idx >> 5, ch = idx & 31;
        *(bf16x8*)(wH + col * KP2 + ch * 8) =
            *(const bf16x8*)(w2h + ((col) << 8) + ch * 8);
        *(bf16x8*)(wL + col * KP2 + ch * 8) =
            *(const bf16x8*)(w2l + ((col) << 8) + ch * 8);
    }

    const int w = tid >> 6, l = tid & 63;
    const int cl = l & 15, g = l >> 4, g8 = g * 8;
    const int na = min(n0 + w * 16 + cl, NN - 1);

    f32x4 acc[4];
#pragma unroll
    for (int ct = 0; ct < 4; ++ct) acc[ct] = (f32x4){0.f, 0.f, 0.f, 0.f};

    __syncthreads();

#pragma unroll
    for (int kk = 0; kk < 8; ++kk) {
        const float* ap = h1 + (size_t)na * C1 + kk * 32 + g8;
        float4 v0 = *(const float4*)ap;
        float4 v1 = *(const float4*)(ap + 4);
        float vv[8] = {v0.x, v0.y, v0.z, v0.w, v1.x, v1.y, v1.z, v1.w};
        bf16x8 aH, aL;
#pragma unroll
        for (int j = 0; j < 8; ++j) {
            unsigned short h = f2bf(vv[j]);
            aH[j] = (short)h;
            aL[j] = (short)f2bf(vv[j] - bf2f(h));
        }
        const int ko = kk * 32 + g8;
#pragma unroll
        for (int ct = 0; ct < 4; ++ct) {
            const bf16x8 bH = *(const bf16x8*)(wH + (ct * 16 + cl) * KP2 + ko);
            const bf16x8 bL = *(const bf16x8*)(wL + (ct * 16 + cl) * KP2 + ko);
            acc[ct] = __builtin_amdgcn_mfma_f32_16x16x32_bf16(aH, bH, acc[ct], 0, 0, 0);
            acc[ct] = __builtin_amdgcn_mfma_f32_16x16x32_bf16(aH, bL, acc[ct], 0, 0, 0);
            acc[ct] = __builtin_amdgcn_mfma_f32_16x16x32_bf16(aL, bH, acc[ct], 0, 0, 0);
        }
    }

    float asc[4], adc[4];
#pragma unroll
    for (int ct = 0; ct < 4; ++ct) {
        asc[ct] = att_s[ct * 16 + cl];
        adc[ct] = att_d[ct * 16 + cl];
    }

#pragma unroll
    for (int reg = 0; reg < 4; ++reg) {
        const int nd = n0 + w * 16 + g * 4 + reg;
        float sa = 0.f, sd = 0.f;
#pragma unroll
        for (int ct = 0; ct < 4; ++ct) {
            sa += acc[ct][reg] * asc[ct];
            sd += acc[ct][reg] * adc[ct];
        }
#pragma unroll
        for (int off = 8; off > 0; off >>= 1) {
            sa += __shfl_xor(sa, off);
            sd += __shfl_xor(sd, off);
        }
        if (nd < NN) {
#pragma unroll
            for (int ct = 0; ct < 4; ++ct)
                h2raw[(size_t)nd * HID + ct * 16 + cl] = acc[ct][reg];
            if (cl == 0) { as2[nd] = sa; ad2[nd] = sd; }
        }
    }
}

// ================= conv1 fused aggregate (wave per node, f32) =================
__global__ __launch_bounds__(256) void conv1_agg(const int* __restrict__ rowptr,
                                                 const int* __restrict__ csr_src,
                                                 const float* __restrict__ as_,
                                                 const float* __restrict__ ad_,
                                                 const float* __restrict__ h,
                                                 const float* __restrict__ b1,
                                                 float* __restrict__ out) {
    const int node = blockIdx.x * 4 + (threadIdx.x >> 6);
    if (node >= NN) return;
    const int lane = threadIdx.x & 63;
    const int beg = rowptr[node], end = rowptr[node + 1];
    const float4 adv = *(const float4*)(ad_ + node * 4);

    float4 mx = make_float4(-INFINITY, -INFINITY, -INFINITY, -INFINITY);
    for (int i = beg + lane; i < end; i += 64) {
        int s = csr_src[i];
        float4 av = *(const float4*)(as_ + s * 4);
        float t;
        t = av.x + adv.x; t = t > 0.f ? t : NEG * t; mx.x = fmaxf(mx.x, t);
        t = av.y + adv.y; t = t > 0.f ? t : NEG * t; mx.y = fmaxf(mx.y, t);
        t = av.z + adv.z; t = t > 0.f ? t : NEG * t; mx.z = fmaxf(mx.z, t);
        t = av.w + adv.w; t = t > 0.f ? t : NEG * t; mx.w = fmaxf(mx.w, t);
    }
#pragma unroll
    for (int off = 32; off > 0; off >>= 1) {
        mx.x = fmaxf(mx.x, __shfl_xor(mx.x, off));
        mx.y = fmaxf(mx.y, __shfl_xor(mx.y, off));
        mx.z = fmaxf(mx.z, __shfl_xor(mx.z, off));
        mx.w = fmaxf(mx.w, __shfl_xor(mx.w, off));
    }

    float4 sm = make_float4(0.f, 0.f, 0.f, 0.f);
    for (int i = beg + lane; i < end; i += 64) {
        int s = csr_src[i];
        float4 av = *(const float4*)(as_ + s * 4);
        float t;
        t = av.x + adv.x; t = t > 0.f ? t : NEG * t; sm.x += __expf(t - mx.x);
        t = av.y + adv.y; t = t > 0.f ? t : NEG * t; sm.y += __expf(t - mx.y);
        t = av.z + adv.z; t = t > 0.f ? t : NEG * t; sm.z += __expf(t - mx.z);
        t = av.w + adv.w; t = t > 0.f ? t : NEG * t; sm.w += __expf(t - mx.w);
    }
#pragma unroll
    for (int off = 32; off > 0; off >>= 1) {
        sm.x += __shfl_xor(sm.x, off);
        sm.y += __shfl_xor(sm.y, off);
        sm.z += __shfl_xor(sm.z, off);
        sm.w += __shfl_xor(sm.w, off);
    }

    const int hd = lane >> 4;
    const float mh  = (hd & 2) ? ((hd & 1) ? mx.w : mx.z) : ((hd & 1) ? mx.y : mx.x);
    const float shd = (hd & 2) ? ((hd & 1) ? sm.w : sm.z) : ((hd & 1) ? sm.y : sm.x);
    const float adh = (hd & 2) ? ((hd & 1) ? adv.w : adv.z) : ((hd & 1) ? adv.y : adv.x);
    const float rdenom = 1.f / (shd + EPSS);

    float4 acc = make_float4(0.f, 0.f, 0.f, 0.f);
    for (int i = beg; i < end; ++i) {
        int s = csr_src[i];
        float t = as_[s * 4 + hd] + adh;
        t = t > 0.f ? t : NEG * t;
        float alpha = __expf(t - mh) * rdenom;
        float4 hv = *(const float4*)(h + (size_t)s * C1 + lane * 4);
        acc.x += alpha * hv.x;
        acc.y += alpha * hv.y;
        acc.z += alpha * hv.z;
        acc.w += alpha * hv.w;
    }

    float4 bv = *(const float4*)(b1 + lane * 4);
    float4 o;
    o.x = acc.x + bv.x; o.x = o.x > 0.f ? o.x : (__expf(o.x) - 1.f);
    o.y = acc.y + bv.y; o.y = o.y > 0.f ? o.y : (__expf(o.y) - 1.f);
    o.z = acc.z + bv.z; o.z = o.z > 0.f ? o.z : (__expf(o.z) - 1.f);
    o.w = acc.w + bv.w; o.w = o.w > 0.f ? o.w : (__expf(o.w) - 1.f);
    *(float4*)(out + (size_t)node * C1 + lane * 4) = o;
}

// ================= conv2 fused aggregate (wave per node, 1 head, f32) =========
__global__ __launch_bounds__(256) void conv2_agg(const int* __restrict__ rowptr,
                                                 const int* __restrict__ csr_src,
                                                 const float* __restrict__ as_,
                                                 const float* __restrict__ ad_,
                                                 const float* __restrict__ h,
                                                 const float* __restrict__ b2,
                                                 float* __restrict__ emb) {
    const int node = blockIdx.x * 4 + (threadIdx.x >> 6);
    if (node >= NN) return;
    const int lane = threadIdx.x & 63;
    const int beg = rowptr[node], end = rowptr[node + 1];
    const float ad = ad_[node];

    float mx = -INFINITY;
    for (int i = beg + lane; i < end; i += 64) {
        float t = as_[csr_src[i]] + ad;
        t = t > 0.f ? t : NEG * t;
        mx = fmaxf(mx, t);
    }
#pragma unroll
    for (int off = 32; off > 0; off >>= 1) mx = fmaxf(mx, __shfl_xor(mx, off));

    float sm = 0.f;
    for (int i = beg + lane; i < end; i += 64) {
        float t = as_[csr_src[i]] + ad;
        t = t > 0.f ? t : NEG * t;
        sm += __expf(t - mx);
    }
#pragma unroll
    for (int off = 32; off > 0; off >>= 1) sm += __shfl_xor(sm, off);
    const float rdenom = 1.f / (sm + EPSS);

    float acc = 0.f;
    for (int i = beg; i < end; ++i) {
        int s = csr_src[i];
        float t = as_[s] + ad;
        t = t > 0.f ? t : NEG * t;
        float alpha = __expf(t - mx) * rdenom;
        acc += alpha * h[(size_t)s * HID + lane];
    }
    emb[(size_t)node * HID + lane] = acc + b2[lane];
}

// ================= edge MLP: split-bf16 3-product MFMA =================
__global__ __launch_bounds__(256) void edge_mlp_mfma(const int* __restrict__ ei,
                                                     const float* __restrict__ emb,
                                                     const float* __restrict__ stats,
                                                     const unsigned short* __restrict__ wTh,
                                                     const unsigned short* __restrict__ wTl,
                                                     const float* __restrict__ mb1,
                                                     const float* __restrict__ mW2,
                                                     const float* __restrict__ mb2,
                                                     float* __restrict__ out) {
    __shared__ unsigned short wH[64 * KP];
    __shared__ unsigned short wL[64 * KP];
    const int tid = threadIdx.x;
    const int e0 = blockIdx.x * 64;

    for (int idx = tid; idx < (64 * KP) / 8; idx += 256) {
        ((float4*)wH)[idx] = ((const float4*)wTh)[idx];
        ((float4*)wL)[idx] = ((const float4*)wTl)[idx];
    }

    const int w  = tid >> 6;
    const int l  = tid & 63;
    const int cl = l & 15;
    const int g  = l >> 4;
    const int g8 = g * 8;
    const int arow = w * 16 + cl;
    const int ge_a = e0 + arow;

    const int rn = ei[ge_a];
    const int cn = ei[NE + ge_a];
    const float* rp = emb + (size_t)rn * HID;
    const float* cp = emb + (size_t)cn * HID;
    float4 r0a = *(const float4*)(rp + g8);
    float4 r0b = *(const float4*)(rp + g8 + 4);
    float4 r1a = *(const float4*)(rp + 32 + g8);
    float4 r1b = *(const float4*)(rp + 32 + g8 + 4);
    float4 c0a = *(const float4*)(cp + g8);
    float4 c0b = *(const float4*)(cp + g8 + 4);
    float4 c1a = *(const float4*)(cp + 32 + g8);
    float4 c1b = *(const float4*)(cp + 32 + g8 + 4);
    float s0 = 0.f, s1 = 0.f, s2 = 0.f;
    if (g == 0) {
        s0 = stats[(size_t)ge_a * 3 + 0];
        s1 = stats[(size_t)ge_a * 3 + 1];
        s2 = stats[(size_t)ge_a * 3 + 2];
    }

    bf16x8 aH[5], aL[5];
    float vs[40];
    vs[0]=r0a.x; vs[1]=r0a.y; vs[2]=r0a.z; vs[3]=r0a.w; vs[4]=r0b.x; vs[5]=r0b.y; vs[6]=r0b.z; vs[7]=r0b.w;
    vs[8]=r1a.x; vs[9]=r1a.y; vs[10]=r1a.z; vs[11]=r1a.w; vs[12]=r1b.x; vs[13]=r1b.y; vs[14]=r1b.z; vs[15]=r1b.w;
    vs[16]=c0a.x; vs[17]=c0a.y; vs[18]=c0a.z; vs[19]=c0a.w; vs[20]=c0b.x; vs[21]=c0b.y; vs[22]=c0b.z; vs[23]=c0b.w;
    vs[24]=c1a.x; vs[25]=c1a.y; vs[26]=c1a.z; vs[27]=c1a.w; vs[28]=c1b.x; vs[29]=c1b.y; vs[30]=c1b.z; vs[31]=c1b.w;
    vs[32]=s0; vs[33]=s1; vs[34]=s2; vs[35]=0.f; vs[36]=0.f; vs[37]=0.f; vs[38]=0.f; vs[39]=0.f;
#pragma unroll
    for (int kk = 0; kk < 5; ++kk) {
#pragma unroll
        for (int j = 0; j < 8; ++j) {
            float v = vs[kk * 8 + j];
            unsigned short h = f2bf(v);
            aH[kk][j] = (short)h;
            aL[kk][j] = (short)f2bf(v - bf2f(h));
        }
    }

    f32x4 acc[4];
#pragma unroll
    for (int ct = 0; ct < 4; ++ct) {
        float b = mb1[ct * 16 + cl];
        acc[ct] = (f32x4){b, b, b, b};
    }

    __syncthreads();

#pragma unroll
    for (int kk = 0; kk < 5; ++kk) {
        const int ko = kk * 32 + g8;
#pragma unroll
        for (int ct = 0; ct < 4; ++ct) {
            const bf16x8 bH = *(const bf16x8*)(wH + (ct * 16 + cl) * KP + ko);
            const bf16x8 bL = *(const bf16x8*)(wL + (ct * 16 + cl) * KP + ko);
            acc[ct] = __builtin_amdgcn_mfma_f32_16x16x32_bf16(aH[kk], bH, acc[ct], 0, 0, 0);
            acc[ct] = __builtin_amdgcn_mfma_f32_16x16x32_bf16(aH[kk], bL, acc[ct], 0, 0, 0);
            acc[ct] = __builtin_amdgcn_mfma_f32_16x16x32_bf16(aL[kk], bH, acc[ct], 0, 0, 0);
        }
    }

    float w2a[4], w2b[4];
#pragma unroll
    for (int ct = 0; ct < 4; ++ct) {
        w2a[ct] = mW2[(ct * 16 + cl) * 2 + 0];
        w2b[ct] = mW2[(ct * 16 + cl) * 2 + 1];
    }
    const float ob0 = mb2[0], ob1 = mb2[1];

#pragma unroll
    for (int reg = 0; reg < 4; ++reg) {
        float p0 = 0.f, p1 = 0.f;
#pragma unroll
        for (int ct = 0; ct < 4; ++ct) {
            float h = fmaxf(acc[ct][reg], 0.f);
            p0 += h * w2a[ct];
            p1 += h * w2b[ct];
        }
#pragma unroll
        for (int off = 8; off > 0; off >>= 1) {
            p0 += __shfl_xor(p0, off);
            p1 += __shfl_xor(p1, off);
        }
        if (cl == 0) {
            const int ge = e0 + w * 16 + g * 4 + reg;
            *(float2*)(out + (size_t)ge * 2) = make_float2(p0 + ob0, p1 + ob1);
        }
    }
}

// ================= launcher =================
extern "C" void kernel_launch(void* const* d_in, const int* in_sizes, int n_in,
                              void* d_out, int out_size, void* d_ws, size_t ws_size,
                              hipStream_t stream) {
    const float* x      = (const float*)d_in[0];
    const int*   ei     = (const int*)d_in[1];
    const float* stats  = (const float*)d_in[2];
    const float* W1     = (const float*)d_in[3];
    const float* att_s1 = (const float*)d_in[4];
    const float* att_d1 = (const float*)d_in[5];
    const float* b1     = (const float*)d_in[6];
    const float* W2     = (const float*)d_in[7];
    const float* att_s2 = (const float*)d_in[8];
    const float* att_d2 = (const float*)d_in[9];
    const float* b2     = (const float*)d_in[10];
    const float* mW1    = (const float*)d_in[11];
    const float* mb1    = (const float*)d_in[12];
    const float* mW2    = (const float*)d_in[13];
    const float* mb2    = (const float*)d_in[14];
    float* out = (float*)d_out;
    float* ws  = (float*)d_ws;

    // float-offset layout
    int*   rowptr  = (int*)ws;                                 // NN+1 (+pad)
    int*   csr_src = rowptr + NN + 16;                         // EP
    float* as1     = ws + (size_t)(NN + 16) + EP;              // 4NN
    float* ad1     = as1 + (size_t)4 * NN;                     // 4NN
    float* h1raw   = ad1 + (size_t)4 * NN;                     // 256NN
    float* h1      = h1raw + (size_t)256 * NN;                 // 256NN
    unsigned short* wTh = (unsigned short*)(h1 + (size_t)256 * NN);  // 64*KP bf16
    unsigned short* wTl = wTh + 64 * KP;                             // 64*KP bf16
    unsigned short* w1h = wTl + 64 * KP;                             // 256*128
    unsigned short* w1l = w1h + C1 * INC;                            // 256*128
    unsigned short* w2h = w1l + C1 * INC;                            // 64*256
    unsigned short* w2l = w2h + HID * C1;                            // 64*256
    // conv2-phase aliases inside h1raw (h1raw dead after conv1_agg)
    float* h2raw    = h1raw;                                   // 64NN
    float* node_emb = h1raw + (size_t)64 * NN;                 // 64NN
    float* as2      = h1raw + (size_t)128 * NN;                // NN
    float* ad2      = as2 + NN;                                // NN
    // transient ints inside h1 region (dead before conv1_agg writes h1)
    int*   counts  = (int*)h1;                                 // NN
    int*   bsum    = (int*)h1 + NN + 64;                       // NSB
    int*   cursor  = (int*)h1 + NN + 64 + NSB + 64;            // NN

    // ---- CSR build + weight prep ----
    hipMemsetAsync(counts, 0, NN * sizeof(int), stream);
    prep_w<<<(64 * KP + 255) / 256, 256, 0, stream>>>(mW1, wTh, wTl);
    prep_w1<<<(C1 * INC + 255) / 256, 256, 0, stream>>>(W1, w1h, w1l);
    prep_w2<<<(HID * C1 + 255) / 256, 256, 0, stream>>>(W2, w2h, w2l);
    csr_count<<<(EP + 255) / 256, 256, 0, stream>>>(ei, counts);
    scan_partial<<<NSB, SCHUNK, 0, stream>>>(counts, bsum);
    scan_top<<<1, 128, 0, stream>>>(bsum, rowptr);
    scan_final<<<NSB, SCHUNK, 0, stream>>>(counts, bsum, rowptr, cursor);
    csr_fill<<<(EP + 255) / 256, 256, 0, stream>>>(ei, cursor, csr_src);

    // ---- conv1 ----
    gemm1_mfma<<<dim3((NN + 63) / 64, 4), 256, 0, stream>>>(x, w1h, w1l, att_s1, att_d1,
                                                            h1raw, as1, ad1);
    conv1_agg<<<(NN + 3) / 4, 256, 0, stream>>>(rowptr, csr_src, as1, ad1, h1raw, b1, h1);

    // ---- conv2 ----
    gemm2_mfma<<<(NN + 63) / 64, 256, 0, stream>>>(h1, w2h, w2l, att_s2, att_d2,
                                                   h2raw, as2, ad2);
    conv2_agg<<<(NN + 3) / 4, 256, 0, stream>>>(rowptr, csr_src, as2, ad2, h2raw, b2, node_emb);

    // ---- edge MLP ----
    edge_mlp_mfma<<<NE / 64, 256, 0, stream>>>(ei, node_emb, stats, wTh, wTl,
                                               mb1, mW2, mb2, out);
}

// Round 7
// 477.915 us; speedup vs baseline: 5.7925x; 1.0931x over previous
//
#include <hip/hip_runtime.h>
#include <math.h>

#define NN 50000
#define NE 800000
#define EP (NE + NN)        // edges including self loops
#define INC 128
#define HID 64
#define HEADS 4
#define C1 (HEADS * HID)    // 256
#define NEG 0.2f
#define EPSS 1e-16f

#define SCHUNK 512
#define NSB ((NN + SCHUNK - 1) / SCHUNK)   // 98

#define KP  170             // edge-MLP W1^T storage stride (bf16 elems); K = 160
#define KP1 136             // gemm1 W1^T LDS stride
#define KP2 264             // gemm2 W2^T LDS stride
typedef __attribute__((ext_vector_type(8))) short bf16x8;
typedef __attribute__((ext_vector_type(4))) float f32x4;

// ---------- bf16 helpers ----------
__device__ __forceinline__ unsigned short f2bf(float f) {
    unsigned u = __float_as_uint(f);
    unsigned r = (u + 0x7FFFu + ((u >> 16) & 1u)) >> 16;
    return (unsigned short)r;
}
__device__ __forceinline__ float bf2f(unsigned short b) {
    return __uint_as_float(((unsigned)b) << 16);
}

// ================= CSR build =================
__global__ void csr_count(const int* __restrict__ ei, int* __restrict__ counts) {
    int e = blockIdx.x * 256 + threadIdx.x;
    if (e >= EP) return;
    int d = (e < NE) ? ei[NE + e] : (e - NE);
    atomicAdd(&counts[d], 1);
}

__global__ __launch_bounds__(SCHUNK) void scan_partial(const int* __restrict__ counts,
                                                       int* __restrict__ bsum) {
    __shared__ int lds[SCHUNK];
    int i = blockIdx.x * SCHUNK + threadIdx.x;
    lds[threadIdx.x] = (i < NN) ? counts[i] : 0;
    __syncthreads();
    for (int off = SCHUNK / 2; off > 0; off >>= 1) {
        if (threadIdx.x < off) lds[threadIdx.x] += lds[threadIdx.x + off];
        __syncthreads();
    }
    if (threadIdx.x == 0) bsum[blockIdx.x] = lds[0];
}

__global__ void scan_top(int* __restrict__ bsum, int* __restrict__ rowptr) {
    __shared__ int lds[NSB];
    int t = threadIdx.x;
    if (t < NSB) lds[t] = bsum[t];
    __syncthreads();
    if (t == 0) {
        int acc = 0;
        for (int i = 0; i < NSB; ++i) { int v = lds[i]; lds[i] = acc; acc += v; }
        rowptr[NN] = acc;   // == EP
    }
    __syncthreads();
    if (t < NSB) bsum[t] = lds[t];
}

__global__ __launch_bounds__(SCHUNK) void scan_final(const int* __restrict__ counts,
                                                     const int* __restrict__ bsum,
                                                     int* __restrict__ rowptr,
                                                     int* __restrict__ cursor) {
    __shared__ int lds[SCHUNK];
    int i = blockIdx.x * SCHUNK + threadIdx.x;
    int v = (i < NN) ? counts[i] : 0;
    lds[threadIdx.x] = v;
    __syncthreads();
    for (int off = 1; off < SCHUNK; off <<= 1) {
        int t = (threadIdx.x >= off) ? lds[threadIdx.x - off] : 0;
        __syncthreads();
        lds[threadIdx.x] += t;
        __syncthreads();
    }
    if (i < NN) {
        int excl = lds[threadIdx.x] - v + bsum[blockIdx.x];
        rowptr[i] = excl;
        cursor[i] = excl;
    }
}

__global__ void csr_fill(const int* __restrict__ ei, int* __restrict__ cursor,
                         int* __restrict__ csr_src) {
    int e = blockIdx.x * 256 + threadIdx.x;
    if (e >= EP) return;
    int s, d;
    if (e < NE) { s = ei[e]; d = ei[NE + e]; } else { s = d = e - NE; }
    int pos = atomicAdd(&cursor[d], 1);
    csr_src[pos] = s;
}

// ================= weight prep (hi/lo bf16 transposes) =================
__global__ void prep_w(const float* __restrict__ mW1,
                       unsigned short* __restrict__ wTh,
                       unsigned short* __restrict__ wTl) {
    int i = blockIdx.x * 256 + threadIdx.x;
    if (i >= 64 * KP) return;
    int c = i / KP, k = i % KP;
    unsigned short h = 0, l = 0;
    if (k < 131) {
        float f = mW1[k * 64 + c];
        h = f2bf(f);
        l = f2bf(f - bf2f(h));
    }
    wTh[i] = h;
    wTl[i] = l;
}

__global__ void prep_w1(const float* __restrict__ W1,
                        unsigned short* __restrict__ w1h,
                        unsigned short* __restrict__ w1l) {
    int i = blockIdx.x * 256 + threadIdx.x;
    if (i >= C1 * INC) return;          // [256 cols][128 k]
    int c = i >> 7, k = i & 127;
    float f = W1[k * C1 + c];
    unsigned short h = f2bf(f);
    w1h[i] = h;
    w1l[i] = f2bf(f - bf2f(h));
}

__global__ void prep_w2(const float* __restrict__ W2,
                        unsigned short* __restrict__ w2h,
                        unsigned short* __restrict__ w2l) {
    int i = blockIdx.x * 256 + threadIdx.x;
    if (i >= HID * C1) return;          // [64 cols][256 k]
    int c = i >> 8, k = i & 255;
    float f = W2[k * HID + c];
    unsigned short h = f2bf(f);
    w2h[i] = h;
    w2l[i] = f2bf(f - bf2f(h));
}

// ================= GEMM1 via split-bf16 MFMA + att1 epilogue =================
// block: 64 nodes x 64 cols (head q = blockIdx.y); K = 128. h1 stored bf16.
__global__ __launch_bounds__(256) void gemm1_mfma(const float* __restrict__ x,
                                                  const unsigned short* __restrict__ w1h,
                                                  const unsigned short* __restrict__ w1l,
                                                  const float* __restrict__ att_s,
                                                  const float* __restrict__ att_d,
                                                  unsigned short* __restrict__ h1b,
                                                  float* __restrict__ as1,
                                                  float* __restrict__ ad1) {
    __shared__ unsigned short wH[64 * KP1];
    __shared__ unsigned short wL[64 * KP1];
    const int tid = threadIdx.x;
    const int n0 = blockIdx.x * 64;
    const int q  = blockIdx.y;

    for (int idx = tid; idx < 64 * 16; idx += 256) {
        int col = idx >> 4, ch = idx & 15;
        *(bf16x8*)(wH + col * KP1 + ch * 8) =
            *(const bf16x8*)(w1h + ((q * 64 + col) << 7) + ch * 8);
        *(bf16x8*)(wL + col * KP1 + ch * 8) =
            *(const bf16x8*)(w1l + ((q * 64 + col) << 7) + ch * 8);
    }

    const int w = tid >> 6, l = tid & 63;
    const int cl = l & 15, g = l >> 4, g8 = g * 8;
    const int na = min(n0 + w * 16 + cl, NN - 1);

    bf16x8 aH[4], aL[4];
#pragma unroll
    for (int kk = 0; kk < 4; ++kk) {
        const float* ap = x + (size_t)na * INC + kk * 32 + g8;
        float4 v0 = *(const float4*)ap;
        float4 v1 = *(const float4*)(ap + 4);
        float vv[8] = {v0.x, v0.y, v0.z, v0.w, v1.x, v1.y, v1.z, v1.w};
#pragma unroll
        for (int j = 0; j < 8; ++j) {
            unsigned short h = f2bf(vv[j]);
            aH[kk][j] = (short)h;
            aL[kk][j] = (short)f2bf(vv[j] - bf2f(h));
        }
    }

    f32x4 acc[4];
#pragma unroll
    for (int ct = 0; ct < 4; ++ct) acc[ct] = (f32x4){0.f, 0.f, 0.f, 0.f};

    __syncthreads();

#pragma unroll
    for (int kk = 0; kk < 4; ++kk) {
        const int ko = kk * 32 + g8;
#pragma unroll
        for (int ct = 0; ct < 4; ++ct) {
            const bf16x8 bH = *(const bf16x8*)(wH + (ct * 16 + cl) * KP1 + ko);
            const bf16x8 bL = *(const bf16x8*)(wL + (ct * 16 + cl) * KP1 + ko);
            acc[ct] = __builtin_amdgcn_mfma_f32_16x16x32_bf16(aH[kk], bH, acc[ct], 0, 0, 0);
            acc[ct] = __builtin_amdgcn_mfma_f32_16x16x32_bf16(aH[kk], bL, acc[ct], 0, 0, 0);
            acc[ct] = __builtin_amdgcn_mfma_f32_16x16x32_bf16(aL[kk], bH, acc[ct], 0, 0, 0);
        }
    }

    float asc[4], adc[4];
#pragma unroll
    for (int ct = 0; ct < 4; ++ct) {
        asc[ct] = att_s[q * 64 + ct * 16 + cl];
        adc[ct] = att_d[q * 64 + ct * 16 + cl];
    }

#pragma unroll
    for (int reg = 0; reg < 4; ++reg) {
        const int nd = n0 + w * 16 + g * 4 + reg;
        float sa = 0.f, sd = 0.f;
#pragma unroll
        for (int ct = 0; ct < 4; ++ct) {
            sa += acc[ct][reg] * asc[ct];
            sd += acc[ct][reg] * adc[ct];
        }
#pragma unroll
        for (int off = 8; off > 0; off >>= 1) {
            sa += __shfl_xor(sa, off);
            sd += __shfl_xor(sd, off);
        }
        if (nd < NN) {
#pragma unroll
            for (int ct = 0; ct < 4; ++ct)
                h1b[(size_t)nd * C1 + q * 64 + ct * 16 + cl] = f2bf(acc[ct][reg]);
            if (cl == 0) { as1[nd * 4 + q] = sa; ad1[nd * 4 + q] = sd; }
        }
    }
}

// ================= GEMM2 via split-bf16 MFMA + att2 epilogue =================
// block: 64 nodes x 64 cols; K = 256 (A = h1 f32). h2 stored bf16.
__global__ __launch_bounds__(256) void gemm2_mfma(const float* __restrict__ h1,
                                                  const unsigned short* __restrict__ w2h,
                                                  const unsigned short* __restrict__ w2l,
                                                  const float* __restrict__ att_s,
                                                  const float* __restrict__ att_d,
                                                  unsigned short* __restrict__ h2b,
                                                  float* __restrict__ as2,
                                                  float* __restrict__ ad2) {
    __shared__ unsigned short wH[64 * KP2];
    __shared__ unsigned short wL[64 * KP2];
    const int tid = threadIdx.x;
    const int n0 = blockIdx.x * 64;

    for (int idx = tid; idx < 64 * 32; idx += 256) {
        int col = idx >> 5, ch = idx & 31;
        *(bf16x8*)(wH + col * KP2 + ch * 8) =
            *(const bf16x8*)(w2h + ((col) << 8) + ch * 8);
        *(bf16x8*)(wL + col * KP2 + ch * 8) =
            *(const bf16x8*)(w2l + ((col) << 8) + ch * 8);
    }

    const int w = tid >> 6, l = tid & 63;
    const int cl = l & 15, g = l >> 4, g8 = g * 8;
    const int na = min(n0 + w * 16 + cl, NN - 1);

    f32x4 acc[4];
#pragma unroll
    for (int ct = 0; ct < 4; ++ct) acc[ct] = (f32x4){0.f, 0.f, 0.f, 0.f};

    __syncthreads();

#pragma unroll
    for (int kk = 0; kk < 8; ++kk) {
        const float* ap = h1 + (size_t)na * C1 + kk * 32 + g8;
        float4 v0 = *(const float4*)ap;
        float4 v1 = *(const float4*)(ap + 4);
        float vv[8] = {v0.x, v0.y, v0.z, v0.w, v1.x, v1.y, v1.z, v1.w};
        bf16x8 aH, aL;
#pragma unroll
        for (int j = 0; j < 8; ++j) {
            unsigned short h = f2bf(vv[j]);
            aH[j] = (short)h;
            aL[j] = (short)f2bf(vv[j] - bf2f(h));
        }
        const int ko = kk * 32 + g8;
#pragma unroll
        for (int ct = 0; ct < 4; ++ct) {
            const bf16x8 bH = *(const bf16x8*)(wH + (ct * 16 + cl) * KP2 + ko);
            const bf16x8 bL = *(const bf16x8*)(wL + (ct * 16 + cl) * KP2 + ko);
            acc[ct] = __builtin_amdgcn_mfma_f32_16x16x32_bf16(aH, bH, acc[ct], 0, 0, 0);
            acc[ct] = __builtin_amdgcn_mfma_f32_16x16x32_bf16(aH, bL, acc[ct], 0, 0, 0);
            acc[ct] = __builtin_amdgcn_mfma_f32_16x16x32_bf16(aL, bH, acc[ct], 0, 0, 0);
        }
    }

    float asc[4], adc[4];
#pragma unroll
    for (int ct = 0; ct < 4; ++ct) {
        asc[ct] = att_s[ct * 16 + cl];
        adc[ct] = att_d[ct * 16 + cl];
    }

#pragma unroll
    for (int reg = 0; reg < 4; ++reg) {
        const int nd = n0 + w * 16 + g * 4 + reg;
        float sa = 0.f, sd = 0.f;
#pragma unroll
        for (int ct = 0; ct < 4; ++ct) {
            sa += acc[ct][reg] * asc[ct];
            sd += acc[ct][reg] * adc[ct];
        }
#pragma unroll
        for (int off = 8; off > 0; off >>= 1) {
            sa += __shfl_xor(sa, off);
            sd += __shfl_xor(sd, off);
        }
        if (nd < NN) {
#pragma unroll
            for (int ct = 0; ct < 4; ++ct)
                h2b[(size_t)nd * HID + ct * 16 + cl] = f2bf(acc[ct][reg]);
            if (cl == 0) { as2[nd] = sa; ad2[nd] = sd; }
        }
    }
}

// ================= conv1 fused aggregate (wave per node, bf16 gather) =========
__global__ __launch_bounds__(256) void conv1_agg(const int* __restrict__ rowptr,
                                                 const int* __restrict__ csr_src,
                                                 const float* __restrict__ as_,
                                                 const float* __restrict__ ad_,
                                                 const unsigned short* __restrict__ h1b,
                                                 const float* __restrict__ b1,
                                                 float* __restrict__ out) {
    const int node = blockIdx.x * 4 + (threadIdx.x >> 6);
    if (node >= NN) return;
    const int lane = threadIdx.x & 63;
    const int beg = rowptr[node], end = rowptr[node + 1];
    const float4 adv = *(const float4*)(ad_ + node * 4);

    float4 mx = make_float4(-INFINITY, -INFINITY, -INFINITY, -INFINITY);
    for (int i = beg + lane; i < end; i += 64) {
        int s = csr_src[i];
        float4 av = *(const float4*)(as_ + s * 4);
        float t;
        t = av.x + adv.x; t = t > 0.f ? t : NEG * t; mx.x = fmaxf(mx.x, t);
        t = av.y + adv.y; t = t > 0.f ? t : NEG * t; mx.y = fmaxf(mx.y, t);
        t = av.z + adv.z; t = t > 0.f ? t : NEG * t; mx.z = fmaxf(mx.z, t);
        t = av.w + adv.w; t = t > 0.f ? t : NEG * t; mx.w = fmaxf(mx.w, t);
    }
#pragma unroll
    for (int off = 32; off > 0; off >>= 1) {
        mx.x = fmaxf(mx.x, __shfl_xor(mx.x, off));
        mx.y = fmaxf(mx.y, __shfl_xor(mx.y, off));
        mx.z = fmaxf(mx.z, __shfl_xor(mx.z, off));
        mx.w = fmaxf(mx.w, __shfl_xor(mx.w, off));
    }

    float4 sm = make_float4(0.f, 0.f, 0.f, 0.f);
    for (int i = beg + lane; i < end; i += 64) {
        int s = csr_src[i];
        float4 av = *(const float4*)(as_ + s * 4);
        float t;
        t = av.x + adv.x; t = t > 0.f ? t : NEG * t; sm.x += __expf(t - mx.x);
        t = av.y + adv.y; t = t > 0.f ? t : NEG * t; sm.y += __expf(t - mx.y);
        t = av.z + adv.z; t = t > 0.f ? t : NEG * t; sm.z += __expf(t - mx.z);
        t = av.w + adv.w; t = t > 0.f ? t : NEG * t; sm.w += __expf(t - mx.w);
    }
#pragma unroll
    for (int off = 32; off > 0; off >>= 1) {
        sm.x += __shfl_xor(sm.x, off);
        sm.y += __shfl_xor(sm.y, off);
        sm.z += __shfl_xor(sm.z, off);
        sm.w += __shfl_xor(sm.w, off);
    }

    const int hd = lane >> 4;
    const float mh  = (hd & 2) ? ((hd & 1) ? mx.w : mx.z) : ((hd & 1) ? mx.y : mx.x);
    const float shd = (hd & 2) ? ((hd & 1) ? sm.w : sm.z) : ((hd & 1) ? sm.y : sm.x);
    const float adh = (hd & 2) ? ((hd & 1) ? adv.w : adv.z) : ((hd & 1) ? adv.y : adv.x);
    const float rdenom = 1.f / (shd + EPSS);

    float4 acc = make_float4(0.f, 0.f, 0.f, 0.f);
    for (int i = beg; i < end; ++i) {
        int s = csr_src[i];
        float t = as_[s * 4 + hd] + adh;
        t = t > 0.f ? t : NEG * t;
        float alpha = __expf(t - mh) * rdenom;
        ushort4 hv = *(const ushort4*)(h1b + (size_t)s * C1 + lane * 4);
        acc.x += alpha * bf2f(hv.x);
        acc.y += alpha * bf2f(hv.y);
        acc.z += alpha * bf2f(hv.z);
        acc.w += alpha * bf2f(hv.w);
    }

    float4 bv = *(const float4*)(b1 + lane * 4);
    float4 o;
    o.x = acc.x + bv.x; o.x = o.x > 0.f ? o.x : (__expf(o.x) - 1.f);
    o.y = acc.y + bv.y; o.y = o.y > 0.f ? o.y : (__expf(o.y) - 1.f);
    o.z = acc.z + bv.z; o.z = o.z > 0.f ? o.z : (__expf(o.z) - 1.f);
    o.w = acc.w + bv.w; o.w = o.w > 0.f ? o.w : (__expf(o.w) - 1.f);
    *(float4*)(out + (size_t)node * C1 + lane * 4) = o;
}

// ================= conv2 fused aggregate (wave per node, bf16 gather) =========
__global__ __launch_bounds__(256) void conv2_agg(const int* __restrict__ rowptr,
                                                 const int* __restrict__ csr_src,
                                                 const float* __restrict__ as_,
                                                 const float* __restrict__ ad_,
                                                 const unsigned short* __restrict__ h2b,
                                                 const float* __restrict__ b2,
                                                 unsigned short* __restrict__ embb) {
    const int node = blockIdx.x * 4 + (threadIdx.x >> 6);
    if (node >= NN) return;
    const int lane = threadIdx.x & 63;
    const int beg = rowptr[node], end = rowptr[node + 1];
    const float ad = ad_[node];

    float mx = -INFINITY;
    for (int i = beg + lane; i < end; i += 64) {
        float t = as_[csr_src[i]] + ad;
        t = t > 0.f ? t : NEG * t;
        mx = fmaxf(mx, t);
    }
#pragma unroll
    for (int off = 32; off > 0; off >>= 1) mx = fmaxf(mx, __shfl_xor(mx, off));

    float sm = 0.f;
    for (int i = beg + lane; i < end; i += 64) {
        float t = as_[csr_src[i]] + ad;
        t = t > 0.f ? t : NEG * t;
        sm += __expf(t - mx);
    }
#pragma unroll
    for (int off = 32; off > 0; off >>= 1) sm += __shfl_xor(sm, off);
    const float rdenom = 1.f / (sm + EPSS);

    float acc = 0.f;
    for (int i = beg; i < end; ++i) {
        int s = csr_src[i];
        float t = as_[s] + ad;
        t = t > 0.f ? t : NEG * t;
        float alpha = __expf(t - mx) * rdenom;
        acc += alpha * bf2f(h2b[(size_t)s * HID + lane]);
    }
    embb[(size_t)node * HID + lane] = f2bf(acc + b2[lane]);
}

// ================= edge MLP: bf16-A x split-bf16-W MFMA =================
// A (feat) is already bf16 (embb) -> exact load, no lo-part needed (2 MFMA/tile).
__global__ __launch_bounds__(256) void edge_mlp_mfma(const int* __restrict__ ei,
                                                     const unsigned short* __restrict__ embb,
                                                     const float* __restrict__ stats,
                                                     const unsigned short* __restrict__ wTh,
                                                     const unsigned short* __restrict__ wTl,
                                                     const float* __restrict__ mb1,
                                                     const float* __restrict__ mW2,
                                                     const float* __restrict__ mb2,
                                                     float* __restrict__ out) {
    __shared__ unsigned short wH[64 * KP];
    __shared__ unsigned short wL[64 * KP];
    const int tid = threadIdx.x;
    const int e0 = blockIdx.x * 64;

    for (int idx = tid; idx < (64 * KP) / 8; idx += 256) {
        ((float4*)wH)[idx] = ((const float4*)wTh)[idx];
        ((float4*)wL)[idx] = ((const float4*)wTl)[idx];
    }

    const int w  = tid >> 6;
    const int l  = tid & 63;
    const int cl = l & 15;
    const int g  = l >> 4;
    const int g8 = g * 8;
    const int arow = w * 16 + cl;
    const int ge_a = e0 + arow;

    const int rn = ei[ge_a];
    const int cn = ei[NE + ge_a];
    const unsigned short* rp = embb + (size_t)rn * HID;
    const unsigned short* cp = embb + (size_t)cn * HID;

    bf16x8 aH[5];
    aH[0] = *(const bf16x8*)(rp + g8);
    aH[1] = *(const bf16x8*)(rp + 32 + g8);
    aH[2] = *(const bf16x8*)(cp + g8);
    aH[3] = *(const bf16x8*)(cp + 32 + g8);
    {
        bf16x8 z = {0, 0, 0, 0, 0, 0, 0, 0};
        if (g == 0) {
            z[0] = (short)f2bf(stats[(size_t)ge_a * 3 + 0]);
            z[1] = (short)f2bf(stats[(size_t)ge_a * 3 + 1]);
            z[2] = (short)f2bf(stats[(size_t)ge_a * 3 + 2]);
        }
        aH[4] = z;
    }

    f32x4 acc[4];
#pragma unroll
    for (int ct = 0; ct < 4; ++ct) {
        float b = mb1[ct * 16 + cl];
        acc[ct] = (f32x4){b, b, b, b};
    }

    __syncthreads();

#pragma unroll
    for (int kk = 0; kk < 5; ++kk) {
        const int ko = kk * 32 + g8;
#pragma unroll
        for (int ct = 0; ct < 4; ++ct) {
            const bf16x8 bH = *(const bf16x8*)(wH + (ct * 16 + cl) * KP + ko);
            const bf16x8 bL = *(const bf16x8*)(wL + (ct * 16 + cl) * KP + ko);
            acc[ct] = __builtin_amdgcn_mfma_f32_16x16x32_bf16(aH[kk], bH, acc[ct], 0, 0, 0);
            acc[ct] = __builtin_amdgcn_mfma_f32_16x16x32_bf16(aH[kk], bL, acc[ct], 0, 0, 0);
        }
    }

    float w2a[4], w2b[4];
#pragma unroll
    for (int ct = 0; ct < 4; ++ct) {
        w2a[ct] = mW2[(ct * 16 + cl) * 2 + 0];
        w2b[ct] = mW2[(ct * 16 + cl) * 2 + 1];
    }
    const float ob0 = mb2[0], ob1 = mb2[1];

#pragma unroll
    for (int reg = 0; reg < 4; ++reg) {
        float p0 = 0.f, p1 = 0.f;
#pragma unroll
        for (int ct = 0; ct < 4; ++ct) {
            float h = fmaxf(acc[ct][reg], 0.f);
            p0 += h * w2a[ct];
            p1 += h * w2b[ct];
        }
#pragma unroll
        for (int off = 8; off > 0; off >>= 1) {
            p0 += __shfl_xor(p0, off);
            p1 += __shfl_xor(p1, off);
        }
        if (cl == 0) {
            const int ge = e0 + w * 16 + g * 4 + reg;
            *(float2*)(out + (size_t)ge * 2) = make_float2(p0 + ob0, p1 + ob1);
        }
    }
}

// ================= launcher =================
extern "C" void kernel_launch(void* const* d_in, const int* in_sizes, int n_in,
                              void* d_out, int out_size, void* d_ws, size_t ws_size,
                              hipStream_t stream) {
    const float* x      = (const float*)d_in[0];
    const int*   ei     = (const int*)d_in[1];
    const float* stats  = (const float*)d_in[2];
    const float* W1     = (const float*)d_in[3];
    const float* att_s1 = (const float*)d_in[4];
    const float* att_d1 = (const float*)d_in[5];
    const float* b1     = (const float*)d_in[6];
    const float* W2     = (const float*)d_in[7];
    const float* att_s2 = (const float*)d_in[8];
    const float* att_d2 = (const float*)d_in[9];
    const float* b2     = (const float*)d_in[10];
    const float* mW1    = (const float*)d_in[11];
    const float* mb1    = (const float*)d_in[12];
    const float* mW2    = (const float*)d_in[13];
    const float* mb2    = (const float*)d_in[14];
    float* out = (float*)d_out;
    float* ws  = (float*)d_ws;

    // f32-word-offset layout
    int*   rowptr  = (int*)ws;                                 // NN+16
    int*   csr_src = rowptr + NN + 16;                         // EP
    float* as1     = ws + (size_t)(NN + 16) + EP;              // 4NN
    float* ad1     = as1 + (size_t)4 * NN;                     // 4NN
    unsigned short* h1b = (unsigned short*)(ad1 + (size_t)4 * NN);   // NN*256 bf16 = 128NN w
    float* h1      = ad1 + (size_t)4 * NN + (size_t)128 * NN;  // 256NN (f32)
    unsigned short* h2b = (unsigned short*)(h1 + (size_t)256 * NN);  // NN*64 bf16 = 32NN w
    float* as2     = h1 + (size_t)256 * NN + (size_t)32 * NN;  // NN
    float* ad2     = as2 + NN;                                 // NN
    unsigned short* embb = (unsigned short*)(ad2 + NN);        // NN*64 bf16 = 32NN w
    unsigned short* wTh = (unsigned short*)(ad2 + NN + (size_t)32 * NN);  // 64*KP
    unsigned short* wTl = wTh + 64 * KP;
    unsigned short* w1h = wTl + 64 * KP;                       // 256*128
    unsigned short* w1l = w1h + C1 * INC;
    unsigned short* w2h = w1l + C1 * INC;                      // 64*256
    unsigned short* w2l = w2h + HID * C1;
    // transient ints inside h1 region (h1 written later, by conv1_agg)
    int*   counts  = (int*)h1;                                 // NN
    int*   bsum    = (int*)h1 + NN + 64;                       // NSB
    int*   cursor  = (int*)h1 + NN + 64 + NSB + 64;            // NN

    // ---- CSR build + weight prep ----
    hipMemsetAsync(counts, 0, NN * sizeof(int), stream);
    prep_w<<<(64 * KP + 255) / 256, 256, 0, stream>>>(mW1, wTh, wTl);
    prep_w1<<<(C1 * INC + 255) / 256, 256, 0, stream>>>(W1, w1h, w1l);
    prep_w2<<<(HID * C1 + 255) / 256, 256, 0, stream>>>(W2, w2h, w2l);
    csr_count<<<(EP + 255) / 256, 256, 0, stream>>>(ei, counts);
    scan_partial<<<NSB, SCHUNK, 0, stream>>>(counts, bsum);
    scan_top<<<1, 128, 0, stream>>>(bsum, rowptr);
    scan_final<<<NSB, SCHUNK, 0, stream>>>(counts, bsum, rowptr, cursor);
    csr_fill<<<(EP + 255) / 256, 256, 0, stream>>>(ei, cursor, csr_src);

    // ---- conv1 ----
    gemm1_mfma<<<dim3((NN + 63) / 64, 4), 256, 0, stream>>>(x, w1h, w1l, att_s1, att_d1,
                                                            h1b, as1, ad1);
    conv1_agg<<<(NN + 3) / 4, 256, 0, stream>>>(rowptr, csr_src, as1, ad1, h1b, b1, h1);

    // ---- conv2 ----
    gemm2_mfma<<<(NN + 63) / 64, 256, 0, stream>>>(h1, w2h, w2l, att_s2, att_d2,
                                                   h2b, as2, ad2);
    conv2_agg<<<(NN + 3) / 4, 256, 0, stream>>>(rowptr, csr_src, as2, ad2, h2b, b2, embb);

    // ---- edge MLP ----
    edge_mlp_mfma<<<NE / 64, 256, 0, stream>>>(ei, embb, stats, wTh, wTl,
                                               mb1, mW2, mb2, out);
}

// Round 8
// 382.958 us; speedup vs baseline: 7.2288x; 1.2480x over previous
//
#include <hip/hip_runtime.h>
#include <math.h>

#define NN 50000
#define NE 800000
#define EP (NE + NN)        // edges including self loops
#define INC 128
#define HID 64
#define HEADS 4
#define C1 (HEADS * HID)    // 256
#define NEG 0.2f
#define EPSS 1e-16f

#define SCHUNK 512
#define NSB ((NN + SCHUNK - 1) / SCHUNK)   // 98

#define KP  170             // edge-MLP W1^T storage stride (bf16 elems); K = 160
#define KP1 136             // gemm1 W1^T LDS stride
#define KP2 264             // gemm2 W2^T LDS stride
typedef __attribute__((ext_vector_type(8))) short bf16x8;
typedef __attribute__((ext_vector_type(4))) float f32x4;

// ---------- bf16 helpers ----------
__device__ __forceinline__ unsigned short f2bf(float f) {
    unsigned u = __float_as_uint(f);
    unsigned r = (u + 0x7FFFu + ((u >> 16) & 1u)) >> 16;
    return (unsigned short)r;
}
__device__ __forceinline__ float bf2f(unsigned short b) {
    return __uint_as_float(((unsigned)b) << 16);
}

// ================= CSR build =================
__global__ void csr_count(const int* __restrict__ ei, int* __restrict__ counts) {
    int e = blockIdx.x * 256 + threadIdx.x;
    if (e >= EP) return;
    int d = (e < NE) ? ei[NE + e] : (e - NE);
    atomicAdd(&counts[d], 1);
}

__global__ __launch_bounds__(SCHUNK) void scan_partial(const int* __restrict__ counts,
                                                       int* __restrict__ bsum) {
    __shared__ int lds[SCHUNK];
    int i = blockIdx.x * SCHUNK + threadIdx.x;
    lds[threadIdx.x] = (i < NN) ? counts[i] : 0;
    __syncthreads();
    for (int off = SCHUNK / 2; off > 0; off >>= 1) {
        if (threadIdx.x < off) lds[threadIdx.x] += lds[threadIdx.x + off];
        __syncthreads();
    }
    if (threadIdx.x == 0) bsum[blockIdx.x] = lds[0];
}

__global__ void scan_top(int* __restrict__ bsum, int* __restrict__ rowptr) {
    __shared__ int lds[NSB];
    int t = threadIdx.x;
    if (t < NSB) lds[t] = bsum[t];
    __syncthreads();
    if (t == 0) {
        int acc = 0;
        for (int i = 0; i < NSB; ++i) { int v = lds[i]; lds[i] = acc; acc += v; }
        rowptr[NN] = acc;   // == EP
    }
    __syncthreads();
    if (t < NSB) bsum[t] = lds[t];
}

__global__ __launch_bounds__(SCHUNK) void scan_final(const int* __restrict__ counts,
                                                     const int* __restrict__ bsum,
                                                     int* __restrict__ rowptr,
                                                     int* __restrict__ cursor) {
    __shared__ int lds[SCHUNK];
    int i = blockIdx.x * SCHUNK + threadIdx.x;
    int v = (i < NN) ? counts[i] : 0;
    lds[threadIdx.x] = v;
    __syncthreads();
    for (int off = 1; off < SCHUNK; off <<= 1) {
        int t = (threadIdx.x >= off) ? lds[threadIdx.x - off] : 0;
        __syncthreads();
        lds[threadIdx.x] += t;
        __syncthreads();
    }
    if (i < NN) {
        int excl = lds[threadIdx.x] - v + bsum[blockIdx.x];
        rowptr[i] = excl;
        cursor[i] = excl;
    }
}

__global__ void csr_fill(const int* __restrict__ ei, int* __restrict__ cursor,
                         int* __restrict__ csr_src) {
    int e = blockIdx.x * 256 + threadIdx.x;
    if (e >= EP) return;
    int s, d;
    if (e < NE) { s = ei[e]; d = ei[NE + e]; } else { s = d = e - NE; }
    int pos = atomicAdd(&cursor[d], 1);
    csr_src[pos] = s;
}

// ================= merged weight prep (hi/lo bf16 transposes) =================
// region 0: mW1^T -> wTh/wTl   [64][KP]
// region 1: W1^T  -> w1h/w1l   [256][128]
// region 2: W2^T  -> w2h/w2l   [64][256]
#define PREP_N0 (64 * KP)
#define PREP_N1 (C1 * INC)
#define PREP_N2 (HID * C1)
__global__ void prep_all(const float* __restrict__ mW1, const float* __restrict__ W1,
                         const float* __restrict__ W2,
                         unsigned short* __restrict__ wTh, unsigned short* __restrict__ wTl,
                         unsigned short* __restrict__ w1h, unsigned short* __restrict__ w1l,
                         unsigned short* __restrict__ w2h, unsigned short* __restrict__ w2l) {
    int i = blockIdx.x * 256 + threadIdx.x;
    if (i < PREP_N0) {
        int c = i / KP, k = i % KP;
        unsigned short h = 0, l = 0;
        if (k < 131) {
            float f = mW1[k * 64 + c];
            h = f2bf(f);
            l = f2bf(f - bf2f(h));
        }
        wTh[i] = h; wTl[i] = l;
        return;
    }
    i -= PREP_N0;
    if (i < PREP_N1) {
        int c = i >> 7, k = i & 127;
        float f = W1[k * C1 + c];
        unsigned short h = f2bf(f);
        w1h[i] = h; w1l[i] = f2bf(f - bf2f(h));
        return;
    }
    i -= PREP_N1;
    if (i < PREP_N2) {
        int c = i >> 8, k = i & 255;
        float f = W2[k * HID + c];
        unsigned short h = f2bf(f);
        w2h[i] = h; w2l[i] = f2bf(f - bf2f(h));
    }
}

// ================= GEMM1 via split-bf16 MFMA + att1 epilogue =================
// block: 64 nodes x 64 cols (head q = blockIdx.y); K = 128. h1 stored bf16.
__global__ __launch_bounds__(256) void gemm1_mfma(const float* __restrict__ x,
                                                  const unsigned short* __restrict__ w1h,
                                                  const unsigned short* __restrict__ w1l,
                                                  const float* __restrict__ att_s,
                                                  const float* __restrict__ att_d,
                                                  unsigned short* __restrict__ h1b,
                                                  float* __restrict__ as1,
                                                  float* __restrict__ ad1) {
    __shared__ unsigned short wH[64 * KP1];
    __shared__ unsigned short wL[64 * KP1];
    const int tid = threadIdx.x;
    const int n0 = blockIdx.x * 64;
    const int q  = blockIdx.y;

    for (int idx = tid; idx < 64 * 16; idx += 256) {
        int col = idx >> 4, ch = idx & 15;
        *(bf16x8*)(wH + col * KP1 + ch * 8) =
            *(const bf16x8*)(w1h + ((q * 64 + col) << 7) + ch * 8);
        *(bf16x8*)(wL + col * KP1 + ch * 8) =
            *(const bf16x8*)(w1l + ((q * 64 + col) << 7) + ch * 8);
    }

    const int w = tid >> 6, l = tid & 63;
    const int cl = l & 15, g = l >> 4, g8 = g * 8;
    const int na = min(n0 + w * 16 + cl, NN - 1);

    bf16x8 aH[4], aL[4];
#pragma unroll
    for (int kk = 0; kk < 4; ++kk) {
        const float* ap = x + (size_t)na * INC + kk * 32 + g8;
        float4 v0 = *(const float4*)ap;
        float4 v1 = *(const float4*)(ap + 4);
        float vv[8] = {v0.x, v0.y, v0.z, v0.w, v1.x, v1.y, v1.z, v1.w};
#pragma unroll
        for (int j = 0; j < 8; ++j) {
            unsigned short h = f2bf(vv[j]);
            aH[kk][j] = (short)h;
            aL[kk][j] = (short)f2bf(vv[j] - bf2f(h));
        }
    }

    f32x4 acc[4];
#pragma unroll
    for (int ct = 0; ct < 4; ++ct) acc[ct] = (f32x4){0.f, 0.f, 0.f, 0.f};

    __syncthreads();

#pragma unroll
    for (int kk = 0; kk < 4; ++kk) {
        const int ko = kk * 32 + g8;
#pragma unroll
        for (int ct = 0; ct < 4; ++ct) {
            const bf16x8 bH = *(const bf16x8*)(wH + (ct * 16 + cl) * KP1 + ko);
            const bf16x8 bL = *(const bf16x8*)(wL + (ct * 16 + cl) * KP1 + ko);
            acc[ct] = __builtin_amdgcn_mfma_f32_16x16x32_bf16(aH[kk], bH, acc[ct], 0, 0, 0);
            acc[ct] = __builtin_amdgcn_mfma_f32_16x16x32_bf16(aH[kk], bL, acc[ct], 0, 0, 0);
            acc[ct] = __builtin_amdgcn_mfma_f32_16x16x32_bf16(aL[kk], bH, acc[ct], 0, 0, 0);
        }
    }

    float asc[4], adc[4];
#pragma unroll
    for (int ct = 0; ct < 4; ++ct) {
        asc[ct] = att_s[q * 64 + ct * 16 + cl];
        adc[ct] = att_d[q * 64 + ct * 16 + cl];
    }

#pragma unroll
    for (int reg = 0; reg < 4; ++reg) {
        const int nd = n0 + w * 16 + g * 4 + reg;
        float sa = 0.f, sd = 0.f;
#pragma unroll
        for (int ct = 0; ct < 4; ++ct) {
            sa += acc[ct][reg] * asc[ct];
            sd += acc[ct][reg] * adc[ct];
        }
#pragma unroll
        for (int off = 8; off > 0; off >>= 1) {
            sa += __shfl_xor(sa, off);
            sd += __shfl_xor(sd, off);
        }
        if (nd < NN) {
#pragma unroll
            for (int ct = 0; ct < 4; ++ct)
                h1b[(size_t)nd * C1 + q * 64 + ct * 16 + cl] = f2bf(acc[ct][reg]);
            if (cl == 0) { as1[nd * 4 + q] = sa; ad1[nd * 4 + q] = sd; }
        }
    }
}

// ================= GEMM2: bf16-A x split-bf16-W MFMA + att2 epilogue =========
// A = h1c (bf16, exact) -> 2 MFMAs/tile. block: 64 nodes x 64 cols; K = 256.
__global__ __launch_bounds__(256) void gemm2_mfma(const unsigned short* __restrict__ h1c,
                                                  const unsigned short* __restrict__ w2h,
                                                  const unsigned short* __restrict__ w2l,
                                                  const float* __restrict__ att_s,
                                                  const float* __restrict__ att_d,
                                                  unsigned short* __restrict__ h2b,
                                                  float* __restrict__ as2,
                                                  float* __restrict__ ad2) {
    __shared__ unsigned short wH[64 * KP2];
    __shared__ unsigned short wL[64 * KP2];
    const int tid = threadIdx.x;
    const int n0 = blockIdx.x * 64;

    for (int idx = tid; idx < 64 * 32; idx += 256) {
        int col = idx >> 5, ch = idx & 31;
        *(bf16x8*)(wH + col * KP2 + ch * 8) =
            *(const bf16x8*)(w2h + ((col) << 8) + ch * 8);
        *(bf16x8*)(wL + col * KP2 + ch * 8) =
            *(const bf16x8*)(w2l + ((col) << 8) + ch * 8);
    }

    const int w = tid >> 6, l = tid & 63;
    const int cl = l & 15, g = l >> 4, g8 = g * 8;
    const int na = min(n0 + w * 16 + cl, NN - 1);

    f32x4 acc[4];
#pragma unroll
    for (int ct = 0; ct < 4; ++ct) acc[ct] = (f32x4){0.f, 0.f, 0.f, 0.f};

    __syncthreads();

#pragma unroll
    for (int kk = 0; kk < 8; ++kk) {
        const bf16x8 aH = *(const bf16x8*)(h1c + (size_t)na * C1 + kk * 32 + g8);
        const int ko = kk * 32 + g8;
#pragma unroll
        for (int ct = 0; ct < 4; ++ct) {
            const bf16x8 bH = *(const bf16x8*)(wH + (ct * 16 + cl) * KP2 + ko);
            const bf16x8 bL = *(const bf16x8*)(wL + (ct * 16 + cl) * KP2 + ko);
            acc[ct] = __builtin_amdgcn_mfma_f32_16x16x32_bf16(aH, bH, acc[ct], 0, 0, 0);
            acc[ct] = __builtin_amdgcn_mfma_f32_16x16x32_bf16(aH, bL, acc[ct], 0, 0, 0);
        }
    }

    float asc[4], adc[4];
#pragma unroll
    for (int ct = 0; ct < 4; ++ct) {
        asc[ct] = att_s[ct * 16 + cl];
        adc[ct] = att_d[ct * 16 + cl];
    }

#pragma unroll
    for (int reg = 0; reg < 4; ++reg) {
        const int nd = n0 + w * 16 + g * 4 + reg;
        float sa = 0.f, sd = 0.f;
#pragma unroll
        for (int ct = 0; ct < 4; ++ct) {
            sa += acc[ct][reg] * asc[ct];
            sd += acc[ct][reg] * adc[ct];
        }
#pragma unroll
        for (int off = 8; off > 0; off >>= 1) {
            sa += __shfl_xor(sa, off);
            sd += __shfl_xor(sd, off);
        }
        if (nd < NN) {
#pragma unroll
            for (int ct = 0; ct < 4; ++ct)
                h2b[(size_t)nd * HID + ct * 16 + cl] = f2bf(acc[ct][reg]);
            if (cl == 0) { as2[nd] = sa; ad2[nd] = sd; }
        }
    }
}

// ================= conv1 aggregate: SINGLE pass (m=0 softmax, factored denom) ==
// out = (sum_e exp(t_e) * h[src_e]) / (sum_e exp(t_e) + eps), then bias+ELU.
// Each lane owns 4 channels of head (lane>>4); sees every edge -> no reduces.
__global__ __launch_bounds__(256) void conv1_agg(const int* __restrict__ rowptr,
                                                 const int* __restrict__ csr_src,
                                                 const float* __restrict__ as_,
                                                 const float* __restrict__ ad_,
                                                 const unsigned short* __restrict__ h1b,
                                                 const float* __restrict__ b1,
                                                 unsigned short* __restrict__ h1c) {
    const int node = blockIdx.x * 4 + (threadIdx.x >> 6);
    if (node >= NN) return;
    const int lane = threadIdx.x & 63;
    const int hd = lane >> 4;
    const int beg = rowptr[node], end = rowptr[node + 1];
    const float adh = ad_[node * 4 + hd];

    float4 acc = make_float4(0.f, 0.f, 0.f, 0.f);
    float sm = 0.f;
#pragma unroll 2
    for (int i = beg; i < end; ++i) {
        int s = csr_src[i];
        float t = as_[s * 4 + hd] + adh;
        t = t > 0.f ? t : NEG * t;
        float e = __expf(t);
        ushort4 hv = *(const ushort4*)(h1b + (size_t)s * C1 + lane * 4);
        acc.x += e * bf2f(hv.x);
        acc.y += e * bf2f(hv.y);
        acc.z += e * bf2f(hv.z);
        acc.w += e * bf2f(hv.w);
        sm += e;
    }
    const float rden = 1.f / (sm + EPSS);

    float4 bv = *(const float4*)(b1 + lane * 4);
    float4 o;
    o.x = acc.x * rden + bv.x; o.x = o.x > 0.f ? o.x : (__expf(o.x) - 1.f);
    o.y = acc.y * rden + bv.y; o.y = o.y > 0.f ? o.y : (__expf(o.y) - 1.f);
    o.z = acc.z * rden + bv.z; o.z = o.z > 0.f ? o.z : (__expf(o.z) - 1.f);
    o.w = acc.w * rden + bv.w; o.w = o.w > 0.f ? o.w : (__expf(o.w) - 1.f);
    ushort4 ob;
    ob.x = f2bf(o.x); ob.y = f2bf(o.y); ob.z = f2bf(o.z); ob.w = f2bf(o.w);
    *(ushort4*)(h1c + (size_t)node * C1 + lane * 4) = ob;
}

// ================= conv2 aggregate: SINGLE pass, 1 head ======================
__global__ __launch_bounds__(256) void conv2_agg(const int* __restrict__ rowptr,
                                                 const int* __restrict__ csr_src,
                                                 const float* __restrict__ as_,
                                                 const float* __restrict__ ad_,
                                                 const unsigned short* __restrict__ h2b,
                                                 const float* __restrict__ b2,
                                                 unsigned short* __restrict__ embb) {
    const int node = blockIdx.x * 4 + (threadIdx.x >> 6);
    if (node >= NN) return;
    const int lane = threadIdx.x & 63;
    const int beg = rowptr[node], end = rowptr[node + 1];
    const float ad = ad_[node];

    float acc = 0.f, sm = 0.f;
#pragma unroll 2
    for (int i = beg; i < end; ++i) {
        int s = csr_src[i];
        float t = as_[s] + ad;
        t = t > 0.f ? t : NEG * t;
        float e = __expf(t);
        acc += e * bf2f(h2b[(size_t)s * HID + lane]);
        sm += e;
    }
    embb[(size_t)node * HID + lane] = f2bf(acc / (sm + EPSS) + b2[lane]);
}

// ================= edge MLP: bf16-A x split-bf16-W MFMA =================
__global__ __launch_bounds__(256) void edge_mlp_mfma(const int* __restrict__ ei,
                                                     const unsigned short* __restrict__ embb,
                                                     const float* __restrict__ stats,
                                                     const unsigned short* __restrict__ wTh,
                                                     const unsigned short* __restrict__ wTl,
                                                     const float* __restrict__ mb1,
                                                     const float* __restrict__ mW2,
                                                     const float* __restrict__ mb2,
                                                     float* __restrict__ out) {
    __shared__ unsigned short wH[64 * KP];
    __shared__ unsigned short wL[64 * KP];
    const int tid = threadIdx.x;
    const int e0 = blockIdx.x * 64;

    for (int idx = tid; idx < (64 * KP) / 8; idx += 256) {
        ((float4*)wH)[idx] = ((const float4*)wTh)[idx];
        ((float4*)wL)[idx] = ((const float4*)wTl)[idx];
    }

    const int w  = tid >> 6;
    const int l  = tid & 63;
    const int cl = l & 15;
    const int g  = l >> 4;
    const int g8 = g * 8;
    const int arow = w * 16 + cl;
    const int ge_a = e0 + arow;

    const int rn = ei[ge_a];
    const int cn = ei[NE + ge_a];
    const unsigned short* rp = embb + (size_t)rn * HID;
    const unsigned short* cp = embb + (size_t)cn * HID;

    bf16x8 aH[5];
    aH[0] = *(const bf16x8*)(rp + g8);
    aH[1] = *(const bf16x8*)(rp + 32 + g8);
    aH[2] = *(const bf16x8*)(cp + g8);
    aH[3] = *(const bf16x8*)(cp + 32 + g8);
    {
        bf16x8 z = {0, 0, 0, 0, 0, 0, 0, 0};
        if (g == 0) {
            z[0] = (short)f2bf(stats[(size_t)ge_a * 3 + 0]);
            z[1] = (short)f2bf(stats[(size_t)ge_a * 3 + 1]);
            z[2] = (short)f2bf(stats[(size_t)ge_a * 3 + 2]);
        }
        aH[4] = z;
    }

    f32x4 acc[4];
#pragma unroll
    for (int ct = 0; ct < 4; ++ct) {
        float b = mb1[ct * 16 + cl];
        acc[ct] = (f32x4){b, b, b, b};
    }

    __syncthreads();

#pragma unroll
    for (int kk = 0; kk < 5; ++kk) {
        const int ko = kk * 32 + g8;
#pragma unroll
        for (int ct = 0; ct < 4; ++ct) {
            const bf16x8 bH = *(const bf16x8*)(wH + (ct * 16 + cl) * KP + ko);
            const bf16x8 bL = *(const bf16x8*)(wL + (ct * 16 + cl) * KP + ko);
            acc[ct] = __builtin_amdgcn_mfma_f32_16x16x32_bf16(aH[kk], bH, acc[ct], 0, 0, 0);
            acc[ct] = __builtin_amdgcn_mfma_f32_16x16x32_bf16(aH[kk], bL, acc[ct], 0, 0, 0);
        }
    }

    float w2a[4], w2b[4];
#pragma unroll
    for (int ct = 0; ct < 4; ++ct) {
        w2a[ct] = mW2[(ct * 16 + cl) * 2 + 0];
        w2b[ct] = mW2[(ct * 16 + cl) * 2 + 1];
    }
    const float ob0 = mb2[0], ob1 = mb2[1];

#pragma unroll
    for (int reg = 0; reg < 4; ++reg) {
        float p0 = 0.f, p1 = 0.f;
#pragma unroll
        for (int ct = 0; ct < 4; ++ct) {
            float h = fmaxf(acc[ct][reg], 0.f);
            p0 += h * w2a[ct];
            p1 += h * w2b[ct];
        }
#pragma unroll
        for (int off = 8; off > 0; off >>= 1) {
            p0 += __shfl_xor(p0, off);
            p1 += __shfl_xor(p1, off);
        }
        if (cl == 0) {
            const int ge = e0 + w * 16 + g * 4 + reg;
            *(float2*)(out + (size_t)ge * 2) = make_float2(p0 + ob0, p1 + ob1);
        }
    }
}

// ================= launcher =================
extern "C" void kernel_launch(void* const* d_in, const int* in_sizes, int n_in,
                              void* d_out, int out_size, void* d_ws, size_t ws_size,
                              hipStream_t stream) {
    const float* x      = (const float*)d_in[0];
    const int*   ei     = (const int*)d_in[1];
    const float* stats  = (const float*)d_in[2];
    const float* W1     = (const float*)d_in[3];
    const float* att_s1 = (const float*)d_in[4];
    const float* att_d1 = (const float*)d_in[5];
    const float* b1     = (const float*)d_in[6];
    const float* W2     = (const float*)d_in[7];
    const float* att_s2 = (const float*)d_in[8];
    const float* att_d2 = (const float*)d_in[9];
    const float* b2     = (const float*)d_in[10];
    const float* mW1    = (const float*)d_in[11];
    const float* mb1    = (const float*)d_in[12];
    const float* mW2    = (const float*)d_in[13];
    const float* mb2    = (const float*)d_in[14];
    float* out = (float*)d_out;
    float* ws  = (float*)d_ws;

    // f32-word-offset layout (no aliasing)
    int*   rowptr  = (int*)ws;                                 // NN+16
    int*   csr_src = rowptr + NN + 16;                         // EP
    float* as1     = ws + (size_t)(NN + 16) + EP;              // 4NN
    float* ad1     = as1 + (size_t)4 * NN;                     // 4NN
    unsigned short* h1b = (unsigned short*)(ad1 + (size_t)4 * NN);   // NN*256 bf16 = 128NN w
    unsigned short* h1c = h1b + (size_t)256 * NN;              // NN*256 bf16 = 128NN w
    unsigned short* h2b = h1c + (size_t)256 * NN;              // NN*64 bf16 = 32NN w
    unsigned short* embb = h2b + (size_t)64 * NN;              // NN*64 bf16
    float* as2     = (float*)(embb + (size_t)64 * NN);         // NN
    float* ad2     = as2 + NN;                                 // NN
    unsigned short* wTh = (unsigned short*)(ad2 + NN);         // 64*KP
    unsigned short* wTl = wTh + 64 * KP;
    unsigned short* w1h = wTl + 64 * KP;                       // 256*128
    unsigned short* w1l = w1h + C1 * INC;
    unsigned short* w2h = w1l + C1 * INC;                      // 64*256
    unsigned short* w2l = w2h + HID * C1;
    int*   counts  = (int*)(w2l + HID * C1 + 64);              // NN
    int*   bsum    = counts + NN + 64;                         // NSB
    int*   cursor  = bsum + NSB + 64;                          // NN

    // ---- CSR build + weight prep ----
    hipMemsetAsync(counts, 0, NN * sizeof(int), stream);
    prep_all<<<(PREP_N0 + PREP_N1 + PREP_N2 + 255) / 256, 256, 0, stream>>>(
        mW1, W1, W2, wTh, wTl, w1h, w1l, w2h, w2l);
    csr_count<<<(EP + 255) / 256, 256, 0, stream>>>(ei, counts);
    scan_partial<<<NSB, SCHUNK, 0, stream>>>(counts, bsum);
    scan_top<<<1, 128, 0, stream>>>(bsum, rowptr);
    scan_final<<<NSB, SCHUNK, 0, stream>>>(counts, bsum, rowptr, cursor);
    csr_fill<<<(EP + 255) / 256, 256, 0, stream>>>(ei, cursor, csr_src);

    // ---- conv1 ----
    gemm1_mfma<<<dim3((NN + 63) / 64, 4), 256, 0, stream>>>(x, w1h, w1l, att_s1, att_d1,
                                                            h1b, as1, ad1);
    conv1_agg<<<(NN + 3) / 4, 256, 0, stream>>>(rowptr, csr_src, as1, ad1, h1b, b1, h1c);

    // ---- conv2 ----
    gemm2_mfma<<<(NN + 63) / 64, 256, 0, stream>>>(h1c, w2h, w2l, att_s2, att_d2,
                                                   h2b, as2, ad2);
    conv2_agg<<<(NN + 3) / 4, 256, 0, stream>>>(rowptr, csr_src, as2, ad2, h2b, b2, embb);

    // ---- edge MLP ----
    edge_mlp_mfma<<<NE / 64, 256, 0, stream>>>(ei, embb, stats, wTh, wTl,
                                               mb1, mW2, mb2, out);
}

// Round 9
// 346.820 us; speedup vs baseline: 7.9821x; 1.1042x over previous
//
#include <hip/hip_runtime.h>
#include <math.h>

#define NN 50000
#define NE 800000
#define EP (NE + NN)        // edges including self loops
#define INC 128
#define HID 64
#define HEADS 4
#define C1 (HEADS * HID)    // 256
#define NEG 0.2f
#define EPSS 1e-16f

#define SCHUNK 512
#define NSB ((NN + SCHUNK - 1) / SCHUNK)   // 98

#define KP  170             // edge-MLP W1^T storage stride (bf16 elems); K = 160
#define KP1 136             // gemm1 W1^T LDS stride
#define KP2 264             // gemm2 W2^T LDS stride
typedef __attribute__((ext_vector_type(8))) short bf16x8;
typedef __attribute__((ext_vector_type(4))) float f32x4;

// ---------- bf16 helpers ----------
__device__ __forceinline__ unsigned short f2bf(float f) {
    unsigned u = __float_as_uint(f);
    unsigned r = (u + 0x7FFFu + ((u >> 16) & 1u)) >> 16;
    return (unsigned short)r;
}
__device__ __forceinline__ float bf2f(unsigned short b) {
    return __uint_as_float(((unsigned)b) << 16);
}

// ================= CSR build =================
__global__ void csr_count(const int* __restrict__ ei, int* __restrict__ counts) {
    int e = blockIdx.x * 256 + threadIdx.x;
    if (e >= EP) return;
    int d = (e < NE) ? ei[NE + e] : (e - NE);
    atomicAdd(&counts[d], 1);
}

__global__ __launch_bounds__(SCHUNK) void scan_partial(const int* __restrict__ counts,
                                                       int* __restrict__ bsum) {
    __shared__ int lds[SCHUNK];
    int i = blockIdx.x * SCHUNK + threadIdx.x;
    lds[threadIdx.x] = (i < NN) ? counts[i] : 0;
    __syncthreads();
    for (int off = SCHUNK / 2; off > 0; off >>= 1) {
        if (threadIdx.x < off) lds[threadIdx.x] += lds[threadIdx.x + off];
        __syncthreads();
    }
    if (threadIdx.x == 0) bsum[blockIdx.x] = lds[0];
}

__global__ void scan_top(int* __restrict__ bsum, int* __restrict__ rowptr) {
    __shared__ int lds[NSB];
    int t = threadIdx.x;
    if (t < NSB) lds[t] = bsum[t];
    __syncthreads();
    if (t == 0) {
        int acc = 0;
        for (int i = 0; i < NSB; ++i) { int v = lds[i]; lds[i] = acc; acc += v; }
        rowptr[NN] = acc;   // == EP
    }
    __syncthreads();
    if (t < NSB) bsum[t] = lds[t];
}

__global__ __launch_bounds__(SCHUNK) void scan_final(const int* __restrict__ counts,
                                                     const int* __restrict__ bsum,
                                                     int* __restrict__ rowptr,
                                                     int* __restrict__ cursor) {
    __shared__ int lds[SCHUNK];
    int i = blockIdx.x * SCHUNK + threadIdx.x;
    int v = (i < NN) ? counts[i] : 0;
    lds[threadIdx.x] = v;
    __syncthreads();
    for (int off = 1; off < SCHUNK; off <<= 1) {
        int t = (threadIdx.x >= off) ? lds[threadIdx.x - off] : 0;
        __syncthreads();
        lds[threadIdx.x] += t;
        __syncthreads();
    }
    if (i < NN) {
        int excl = lds[threadIdx.x] - v + bsum[blockIdx.x];
        rowptr[i] = excl;
        cursor[i] = excl;
    }
}

__global__ void csr_fill(const int* __restrict__ ei, int* __restrict__ cursor,
                         int* __restrict__ csr_src) {
    int e = blockIdx.x * 256 + threadIdx.x;
    if (e >= EP) return;
    int s, d;
    if (e < NE) { s = ei[e]; d = ei[NE + e]; } else { s = d = e - NE; }
    int pos = atomicAdd(&cursor[d], 1);
    csr_src[pos] = s;
}

// ================= merged weight prep (hi/lo bf16 transposes) =================
#define PREP_N0 (64 * KP)
#define PREP_N1 (C1 * INC)
#define PREP_N2 (HID * C1)
__global__ void prep_all(const float* __restrict__ mW1, const float* __restrict__ W1,
                         const float* __restrict__ W2,
                         unsigned short* __restrict__ wTh, unsigned short* __restrict__ wTl,
                         unsigned short* __restrict__ w1h, unsigned short* __restrict__ w1l,
                         unsigned short* __restrict__ w2h, unsigned short* __restrict__ w2l) {
    int i = blockIdx.x * 256 + threadIdx.x;
    if (i < PREP_N0) {
        int c = i / KP, k = i % KP;
        unsigned short h = 0, l = 0;
        if (k < 131) {
            float f = mW1[k * 64 + c];
            h = f2bf(f);
            l = f2bf(f - bf2f(h));
        }
        wTh[i] = h; wTl[i] = l;
        return;
    }
    i -= PREP_N0;
    if (i < PREP_N1) {
        int c = i >> 7, k = i & 127;
        float f = W1[k * C1 + c];
        unsigned short h = f2bf(f);
        w1h[i] = h; w1l[i] = f2bf(f - bf2f(h));
        return;
    }
    i -= PREP_N1;
    if (i < PREP_N2) {
        int c = i >> 8, k = i & 255;
        float f = W2[k * HID + c];
        unsigned short h = f2bf(f);
        w2h[i] = h; w2l[i] = f2bf(f - bf2f(h));
    }
}

// ================= GEMM1 via split-bf16 MFMA + att1 epilogue =================
__global__ __launch_bounds__(256) void gemm1_mfma(const float* __restrict__ x,
                                                  const unsigned short* __restrict__ w1h,
                                                  const unsigned short* __restrict__ w1l,
                                                  const float* __restrict__ att_s,
                                                  const float* __restrict__ att_d,
                                                  unsigned short* __restrict__ h1b,
                                                  float* __restrict__ as1,
                                                  float* __restrict__ ad1) {
    __shared__ unsigned short wH[64 * KP1];
    __shared__ unsigned short wL[64 * KP1];
    const int tid = threadIdx.x;
    const int n0 = blockIdx.x * 64;
    const int q  = blockIdx.y;

    for (int idx = tid; idx < 64 * 16; idx += 256) {
        int col = idx >> 4, ch = idx & 15;
        *(bf16x8*)(wH + col * KP1 + ch * 8) =
            *(const bf16x8*)(w1h + ((q * 64 + col) << 7) + ch * 8);
        *(bf16x8*)(wL + col * KP1 + ch * 8) =
            *(const bf16x8*)(w1l + ((q * 64 + col) << 7) + ch * 8);
    }

    const int w = tid >> 6, l = tid & 63;
    const int cl = l & 15, g = l >> 4, g8 = g * 8;
    const int na = min(n0 + w * 16 + cl, NN - 1);

    bf16x8 aH[4], aL[4];
#pragma unroll
    for (int kk = 0; kk < 4; ++kk) {
        const float* ap = x + (size_t)na * INC + kk * 32 + g8;
        float4 v0 = *(const float4*)ap;
        float4 v1 = *(const float4*)(ap + 4);
        float vv[8] = {v0.x, v0.y, v0.z, v0.w, v1.x, v1.y, v1.z, v1.w};
#pragma unroll
        for (int j = 0; j < 8; ++j) {
            unsigned short h = f2bf(vv[j]);
            aH[kk][j] = (short)h;
            aL[kk][j] = (short)f2bf(vv[j] - bf2f(h));
        }
    }

    f32x4 acc[4];
#pragma unroll
    for (int ct = 0; ct < 4; ++ct) acc[ct] = (f32x4){0.f, 0.f, 0.f, 0.f};

    __syncthreads();

#pragma unroll
    for (int kk = 0; kk < 4; ++kk) {
        const int ko = kk * 32 + g8;
#pragma unroll
        for (int ct = 0; ct < 4; ++ct) {
            const bf16x8 bH = *(const bf16x8*)(wH + (ct * 16 + cl) * KP1 + ko);
            const bf16x8 bL = *(const bf16x8*)(wL + (ct * 16 + cl) * KP1 + ko);
            acc[ct] = __builtin_amdgcn_mfma_f32_16x16x32_bf16(aH[kk], bH, acc[ct], 0, 0, 0);
            acc[ct] = __builtin_amdgcn_mfma_f32_16x16x32_bf16(aH[kk], bL, acc[ct], 0, 0, 0);
            acc[ct] = __builtin_amdgcn_mfma_f32_16x16x32_bf16(aL[kk], bH, acc[ct], 0, 0, 0);
        }
    }

    float asc[4], adc[4];
#pragma unroll
    for (int ct = 0; ct < 4; ++ct) {
        asc[ct] = att_s[q * 64 + ct * 16 + cl];
        adc[ct] = att_d[q * 64 + ct * 16 + cl];
    }

#pragma unroll
    for (int reg = 0; reg < 4; ++reg) {
        const int nd = n0 + w * 16 + g * 4 + reg;
        float sa = 0.f, sd = 0.f;
#pragma unroll
        for (int ct = 0; ct < 4; ++ct) {
            sa += acc[ct][reg] * asc[ct];
            sd += acc[ct][reg] * adc[ct];
        }
#pragma unroll
        for (int off = 8; off > 0; off >>= 1) {
            sa += __shfl_xor(sa, off);
            sd += __shfl_xor(sd, off);
        }
        if (nd < NN) {
#pragma unroll
            for (int ct = 0; ct < 4; ++ct)
                h1b[(size_t)nd * C1 + q * 64 + ct * 16 + cl] = f2bf(acc[ct][reg]);
            if (cl == 0) { as1[nd * 4 + q] = sa; ad1[nd * 4 + q] = sd; }
        }
    }
}

// ================= GEMM2: bf16-A x split-bf16-W MFMA + att2 epilogue =========
__global__ __launch_bounds__(256) void gemm2_mfma(const unsigned short* __restrict__ h1c,
                                                  const unsigned short* __restrict__ w2h,
                                                  const unsigned short* __restrict__ w2l,
                                                  const float* __restrict__ att_s,
                                                  const float* __restrict__ att_d,
                                                  unsigned short* __restrict__ h2b,
                                                  float* __restrict__ as2,
                                                  float* __restrict__ ad2) {
    __shared__ unsigned short wH[64 * KP2];
    __shared__ unsigned short wL[64 * KP2];
    const int tid = threadIdx.x;
    const int n0 = blockIdx.x * 64;

    for (int idx = tid; idx < 64 * 32; idx += 256) {
        int col = idx >> 5, ch = idx & 31;
        *(bf16x8*)(wH + col * KP2 + ch * 8) =
            *(const bf16x8*)(w2h + ((col) << 8) + ch * 8);
        *(bf16x8*)(wL + col * KP2 + ch * 8) =
            *(const bf16x8*)(w2l + ((col) << 8) + ch * 8);
    }

    const int w = tid >> 6, l = tid & 63;
    const int cl = l & 15, g = l >> 4, g8 = g * 8;
    const int na = min(n0 + w * 16 + cl, NN - 1);

    f32x4 acc[4];
#pragma unroll
    for (int ct = 0; ct < 4; ++ct) acc[ct] = (f32x4){0.f, 0.f, 0.f, 0.f};

    __syncthreads();

#pragma unroll
    for (int kk = 0; kk < 8; ++kk) {
        const bf16x8 aH = *(const bf16x8*)(h1c + (size_t)na * C1 + kk * 32 + g8);
        const int ko = kk * 32 + g8;
#pragma unroll
        for (int ct = 0; ct < 4; ++ct) {
            const bf16x8 bH = *(const bf16x8*)(wH + (ct * 16 + cl) * KP2 + ko);
            const bf16x8 bL = *(const bf16x8*)(wL + (ct * 16 + cl) * KP2 + ko);
            acc[ct] = __builtin_amdgcn_mfma_f32_16x16x32_bf16(aH, bH, acc[ct], 0, 0, 0);
            acc[ct] = __builtin_amdgcn_mfma_f32_16x16x32_bf16(aH, bL, acc[ct], 0, 0, 0);
        }
    }

    float asc[4], adc[4];
#pragma unroll
    for (int ct = 0; ct < 4; ++ct) {
        asc[ct] = att_s[ct * 16 + cl];
        adc[ct] = att_d[ct * 16 + cl];
    }

#pragma unroll
    for (int reg = 0; reg < 4; ++reg) {
        const int nd = n0 + w * 16 + g * 4 + reg;
        float sa = 0.f, sd = 0.f;
#pragma unroll
        for (int ct = 0; ct < 4; ++ct) {
            sa += acc[ct][reg] * asc[ct];
            sd += acc[ct][reg] * adc[ct];
        }
#pragma unroll
        for (int off = 8; off > 0; off >>= 1) {
            sa += __shfl_xor(sa, off);
            sd += __shfl_xor(sd, off);
        }
        if (nd < NN) {
#pragma unroll
            for (int ct = 0; ct < 4; ++ct)
                h2b[(size_t)nd * HID + ct * 16 + cl] = f2bf(acc[ct][reg]);
            if (cl == 0) { as2[nd] = sa; ad2[nd] = sd; }
        }
    }
}

// ================= conv1 aggregate: SINGLE pass (m=0 softmax, factored denom) ==
__global__ __launch_bounds__(256) void conv1_agg(const int* __restrict__ rowptr,
                                                 const int* __restrict__ csr_src,
                                                 const float* __restrict__ as_,
                                                 const float* __restrict__ ad_,
                                                 const unsigned short* __restrict__ h1b,
                                                 const float* __restrict__ b1,
                                                 unsigned short* __restrict__ h1c) {
    const int node = blockIdx.x * 4 + (threadIdx.x >> 6);
    if (node >= NN) return;
    const int lane = threadIdx.x & 63;
    const int hd = lane >> 4;
    const int beg = rowptr[node], end = rowptr[node + 1];
    const float adh = ad_[node * 4 + hd];

    float4 acc = make_float4(0.f, 0.f, 0.f, 0.f);
    float sm = 0.f;
#pragma unroll 2
    for (int i = beg; i < end; ++i) {
        int s = csr_src[i];
        float t = as_[s * 4 + hd] + adh;
        t = t > 0.f ? t : NEG * t;
        float e = __expf(t);
        ushort4 hv = *(const ushort4*)(h1b + (size_t)s * C1 + lane * 4);
        acc.x += e * bf2f(hv.x);
        acc.y += e * bf2f(hv.y);
        acc.z += e * bf2f(hv.z);
        acc.w += e * bf2f(hv.w);
        sm += e;
    }
    const float rden = 1.f / (sm + EPSS);

    float4 bv = *(const float4*)(b1 + lane * 4);
    float4 o;
    o.x = acc.x * rden + bv.x; o.x = o.x > 0.f ? o.x : (__expf(o.x) - 1.f);
    o.y = acc.y * rden + bv.y; o.y = o.y > 0.f ? o.y : (__expf(o.y) - 1.f);
    o.z = acc.z * rden + bv.z; o.z = o.z > 0.f ? o.z : (__expf(o.z) - 1.f);
    o.w = acc.w * rden + bv.w; o.w = o.w > 0.f ? o.w : (__expf(o.w) - 1.f);
    ushort4 ob;
    ob.x = f2bf(o.x); ob.y = f2bf(o.y); ob.z = f2bf(o.z); ob.w = f2bf(o.w);
    *(ushort4*)(h1c + (size_t)node * C1 + lane * 4) = ob;
}

// ================= conv2 aggregate: SINGLE pass, 1 head ======================
__global__ __launch_bounds__(256) void conv2_agg(const int* __restrict__ rowptr,
                                                 const int* __restrict__ csr_src,
                                                 const float* __restrict__ as_,
                                                 const float* __restrict__ ad_,
                                                 const unsigned short* __restrict__ h2b,
                                                 const float* __restrict__ b2,
                                                 unsigned short* __restrict__ embb) {
    const int node = blockIdx.x * 4 + (threadIdx.x >> 6);
    if (node >= NN) return;
    const int lane = threadIdx.x & 63;
    const int beg = rowptr[node], end = rowptr[node + 1];
    const float ad = ad_[node];

    float acc = 0.f, sm = 0.f;
#pragma unroll 2
    for (int i = beg; i < end; ++i) {
        int s = csr_src[i];
        float t = as_[s] + ad;
        t = t > 0.f ? t : NEG * t;
        float e = __expf(t);
        acc += e * bf2f(h2b[(size_t)s * HID + lane]);
        sm += e;
    }
    embb[(size_t)node * HID + lane] = f2bf(acc / (sm + EPSS) + b2[lane]);
}

// ================= edge MLP: persistent waves, W in registers, NO LDS =========
// Each wave owns 16 edges/tile; B fragments (W1 hi/lo) live in 160 VGPRs,
// loaded once from global (L2-broadcast). Grid-stride over NE/16 tiles.
__global__ __launch_bounds__(256) void edge_mlp_mfma(const int* __restrict__ ei,
                                                     const unsigned short* __restrict__ embb,
                                                     const float* __restrict__ stats,
                                                     const unsigned short* __restrict__ wTh,
                                                     const unsigned short* __restrict__ wTl,
                                                     const float* __restrict__ mb1,
                                                     const float* __restrict__ mW2,
                                                     const float* __restrict__ mb2,
                                                     float* __restrict__ out) {
    const int l  = threadIdx.x & 63;
    const int cl = l & 15;
    const int g  = l >> 4;
    const int g8 = g * 8;

    // B fragments -> registers (block-invariant, lane-determined)
    bf16x8 bH[5][4], bL[5][4];
#pragma unroll
    for (int kk = 0; kk < 5; ++kk)
#pragma unroll
        for (int ct = 0; ct < 4; ++ct) {
            bH[kk][ct] = *(const bf16x8*)(wTh + (ct * 16 + cl) * KP + kk * 32 + g8);
            bL[kk][ct] = *(const bf16x8*)(wTl + (ct * 16 + cl) * KP + kk * 32 + g8);
        }

    float bia[4], w2a[4], w2b[4];
#pragma unroll
    for (int ct = 0; ct < 4; ++ct) {
        bia[ct] = mb1[ct * 16 + cl];
        w2a[ct] = mW2[(ct * 16 + cl) * 2 + 0];
        w2b[ct] = mW2[(ct * 16 + cl) * 2 + 1];
    }
    const float ob0 = mb2[0], ob1 = mb2[1];

    const int wave0  = blockIdx.x * 4 + (threadIdx.x >> 6);
    const int nwaves = gridDim.x * 4;

    for (int t = wave0; t < NE / 16; t += nwaves) {
        const int ge_a = t * 16 + cl;
        const int rn = ei[ge_a];
        const int cn = ei[NE + ge_a];
        const unsigned short* rp = embb + (size_t)rn * HID;
        const unsigned short* cp = embb + (size_t)cn * HID;

        bf16x8 aH[5];
        aH[0] = *(const bf16x8*)(rp + g8);
        aH[1] = *(const bf16x8*)(rp + 32 + g8);
        aH[2] = *(const bf16x8*)(cp + g8);
        aH[3] = *(const bf16x8*)(cp + 32 + g8);
        {
            bf16x8 z = {0, 0, 0, 0, 0, 0, 0, 0};
            if (g == 0) {
                z[0] = (short)f2bf(stats[(size_t)ge_a * 3 + 0]);
                z[1] = (short)f2bf(stats[(size_t)ge_a * 3 + 1]);
                z[2] = (short)f2bf(stats[(size_t)ge_a * 3 + 2]);
            }
            aH[4] = z;
        }

        f32x4 acc[4];
#pragma unroll
        for (int ct = 0; ct < 4; ++ct)
            acc[ct] = (f32x4){bia[ct], bia[ct], bia[ct], bia[ct]};

#pragma unroll
        for (int kk = 0; kk < 5; ++kk) {
#pragma unroll
            for (int ct = 0; ct < 4; ++ct) {
                acc[ct] = __builtin_amdgcn_mfma_f32_16x16x32_bf16(aH[kk], bH[kk][ct], acc[ct], 0, 0, 0);
                acc[ct] = __builtin_amdgcn_mfma_f32_16x16x32_bf16(aH[kk], bL[kk][ct], acc[ct], 0, 0, 0);
            }
        }

#pragma unroll
        for (int reg = 0; reg < 4; ++reg) {
            float p0 = 0.f, p1 = 0.f;
#pragma unroll
            for (int ct = 0; ct < 4; ++ct) {
                float h = fmaxf(acc[ct][reg], 0.f);
                p0 += h * w2a[ct];
                p1 += h * w2b[ct];
            }
#pragma unroll
            for (int off = 8; off > 0; off >>= 1) {
                p0 += __shfl_xor(p0, off);
                p1 += __shfl_xor(p1, off);
            }
            if (cl == 0) {
                const int ge = t * 16 + g * 4 + reg;
                *(float2*)(out + (size_t)ge * 2) = make_float2(p0 + ob0, p1 + ob1);
            }
        }
    }
}

// ================= launcher =================
extern "C" void kernel_launch(void* const* d_in, const int* in_sizes, int n_in,
                              void* d_out, int out_size, void* d_ws, size_t ws_size,
                              hipStream_t stream) {
    const float* x      = (const float*)d_in[0];
    const int*   ei     = (const int*)d_in[1];
    const float* stats  = (const float*)d_in[2];
    const float* W1     = (const float*)d_in[3];
    const float* att_s1 = (const float*)d_in[4];
    const float* att_d1 = (const float*)d_in[5];
    const float* b1     = (const float*)d_in[6];
    const float* W2     = (const float*)d_in[7];
    const float* att_s2 = (const float*)d_in[8];
    const float* att_d2 = (const float*)d_in[9];
    const float* b2     = (const float*)d_in[10];
    const float* mW1    = (const float*)d_in[11];
    const float* mb1    = (const float*)d_in[12];
    const float* mW2    = (const float*)d_in[13];
    const float* mb2    = (const float*)d_in[14];
    float* out = (float*)d_out;
    float* ws  = (float*)d_ws;

    // f32-word-offset layout (no aliasing)
    int*   rowptr  = (int*)ws;                                 // NN+16
    int*   csr_src = rowptr + NN + 16;                         // EP
    float* as1     = ws + (size_t)(NN + 16) + EP;              // 4NN
    float* ad1     = as1 + (size_t)4 * NN;                     // 4NN
    unsigned short* h1b = (unsigned short*)(ad1 + (size_t)4 * NN);   // NN*256 bf16 = 128NN w
    unsigned short* h1c = h1b + (size_t)256 * NN;              // NN*256 bf16 = 128NN w
    unsigned short* h2b = h1c + (size_t)256 * NN;              // NN*64 bf16 = 32NN w
    unsigned short* embb = h2b + (size_t)64 * NN;              // NN*64 bf16
    float* as2     = (float*)(embb + (size_t)64 * NN);         // NN
    float* ad2     = as2 + NN;                                 // NN
    unsigned short* wTh = (unsigned short*)(ad2 + NN);         // 64*KP
    unsigned short* wTl = wTh + 64 * KP;
    unsigned short* w1h = wTl + 64 * KP;                       // 256*128
    unsigned short* w1l = w1h + C1 * INC;
    unsigned short* w2h = w1l + C1 * INC;                      // 64*256
    unsigned short* w2l = w2h + HID * C1;
    int*   counts  = (int*)(w2l + HID * C1 + 64);              // NN
    int*   bsum    = counts + NN + 64;                         // NSB
    int*   cursor  = bsum + NSB + 64;                          // NN

    // ---- CSR build + weight prep ----
    hipMemsetAsync(counts, 0, NN * sizeof(int), stream);
    prep_all<<<(PREP_N0 + PREP_N1 + PREP_N2 + 255) / 256, 256, 0, stream>>>(
        mW1, W1, W2, wTh, wTl, w1h, w1l, w2h, w2l);
    csr_count<<<(EP + 255) / 256, 256, 0, stream>>>(ei, counts);
    scan_partial<<<NSB, SCHUNK, 0, stream>>>(counts, bsum);
    scan_top<<<1, 128, 0, stream>>>(bsum, rowptr);
    scan_final<<<NSB, SCHUNK, 0, stream>>>(counts, bsum, rowptr, cursor);
    csr_fill<<<(EP + 255) / 256, 256, 0, stream>>>(ei, cursor, csr_src);

    // ---- conv1 ----
    gemm1_mfma<<<dim3((NN + 63) / 64, 4), 256, 0, stream>>>(x, w1h, w1l, att_s1, att_d1,
                                                            h1b, as1, ad1);
    conv1_agg<<<(NN + 3) / 4, 256, 0, stream>>>(rowptr, csr_src, as1, ad1, h1b, b1, h1c);

    // ---- conv2 ----
    gemm2_mfma<<<(NN + 63) / 64, 256, 0, stream>>>(h1c, w2h, w2l, att_s2, att_d2,
                                                   h2b, as2, ad2);
    conv2_agg<<<(NN + 3) / 4, 256, 0, stream>>>(rowptr, csr_src, as2, ad2, h2b, b2, embb);

    // ---- edge MLP: persistent, reg-resident W ----
    edge_mlp_mfma<<<512, 256, 0, stream>>>(ei, embb, stats, wTh, wTl,
                                           mb1, mW2, mb2, out);
}

// Round 10
// 319.311 us; speedup vs baseline: 8.6697x; 1.0861x over previous
//
#include <hip/hip_runtime.h>
#include <math.h>

#define NN 50000
#define NE 800000
#define EP (NE + NN)        // edges including self loops
#define INC 128
#define HID 64
#define HEADS 4
#define C1 (HEADS * HID)    // 256
#define NEG 0.2f
#define EPSS 1e-16f

#define SCHUNK 512
#define NSB ((NN + SCHUNK - 1) / SCHUNK)   // 98

#define KP  170             // edge-MLP W1^T storage stride (bf16 elems); K = 160
#define KP1 136             // gemm1 W1^T LDS stride
#define KP2 264             // gemm2 W2^T LDS stride
typedef __attribute__((ext_vector_type(8))) short bf16x8;
typedef __attribute__((ext_vector_type(4))) float f32x4;

// ---------- bf16 helpers ----------
__device__ __forceinline__ unsigned short f2bf(float f) {
    unsigned u = __float_as_uint(f);
    unsigned r = (u + 0x7FFFu + ((u >> 16) & 1u)) >> 16;
    return (unsigned short)r;
}
__device__ __forceinline__ float bf2f(unsigned short b) {
    return __uint_as_float(((unsigned)b) << 16);
}

// ================= CSR build (count merged into prep_all) =================
__global__ __launch_bounds__(SCHUNK) void scan_partial(const int* __restrict__ counts,
                                                       int* __restrict__ bsum) {
    __shared__ int lds[SCHUNK];
    int i = blockIdx.x * SCHUNK + threadIdx.x;
    lds[threadIdx.x] = (i < NN) ? counts[i] : 0;
    __syncthreads();
    for (int off = SCHUNK / 2; off > 0; off >>= 1) {
        if (threadIdx.x < off) lds[threadIdx.x] += lds[threadIdx.x + off];
        __syncthreads();
    }
    if (threadIdx.x == 0) bsum[blockIdx.x] = lds[0];
}

__global__ void scan_top(int* __restrict__ bsum, int* __restrict__ rowptr) {
    __shared__ int lds[NSB];
    int t = threadIdx.x;
    if (t < NSB) lds[t] = bsum[t];
    __syncthreads();
    if (t == 0) {
        int acc = 0;
        for (int i = 0; i < NSB; ++i) { int v = lds[i]; lds[i] = acc; acc += v; }
        rowptr[NN] = acc;   // == EP
    }
    __syncthreads();
    if (t < NSB) bsum[t] = lds[t];
}

__global__ __launch_bounds__(SCHUNK) void scan_final(const int* __restrict__ counts,
                                                     const int* __restrict__ bsum,
                                                     int* __restrict__ rowptr,
                                                     int* __restrict__ cursor) {
    __shared__ int lds[SCHUNK];
    int i = blockIdx.x * SCHUNK + threadIdx.x;
    int v = (i < NN) ? counts[i] : 0;
    lds[threadIdx.x] = v;
    __syncthreads();
    for (int off = 1; off < SCHUNK; off <<= 1) {
        int t = (threadIdx.x >= off) ? lds[threadIdx.x - off] : 0;
        __syncthreads();
        lds[threadIdx.x] += t;
        __syncthreads();
    }
    if (i < NN) {
        int excl = lds[threadIdx.x] - v + bsum[blockIdx.x];
        rowptr[i] = excl;
        cursor[i] = excl;
    }
}

__global__ void csr_fill(const int* __restrict__ ei, int* __restrict__ cursor,
                         int* __restrict__ csr_src, int* __restrict__ csr_dst) {
    int e = blockIdx.x * 256 + threadIdx.x;
    if (e >= EP) return;
    int s, d;
    if (e < NE) { s = ei[e]; d = ei[NE + e]; } else { s = d = e - NE; }
    int pos = atomicAdd(&cursor[d], 1);
    csr_src[pos] = s;
    csr_dst[pos] = d;
}

// ================= merged weight prep + edge count =================
#define PREP_N0 (64 * KP)
#define PREP_N1 (C1 * INC)
#define PREP_N2 (HID * C1)
#define PREP_TOT (PREP_N0 + PREP_N1 + PREP_N2)
__global__ void prep_all(const float* __restrict__ mW1, const float* __restrict__ W1,
                         const float* __restrict__ W2, const int* __restrict__ ei,
                         unsigned short* __restrict__ wTh, unsigned short* __restrict__ wTl,
                         unsigned short* __restrict__ w1h, unsigned short* __restrict__ w1l,
                         unsigned short* __restrict__ w2h, unsigned short* __restrict__ w2l,
                         int* __restrict__ counts) {
    int i = blockIdx.x * 256 + threadIdx.x;
    if (i < PREP_N0) {
        int c = i / KP, k = i % KP;
        unsigned short h = 0, l = 0;
        if (k < 131) {
            float f = mW1[k * 64 + c];
            h = f2bf(f);
            l = f2bf(f - bf2f(h));
        }
        wTh[i] = h; wTl[i] = l;
        return;
    }
    i -= PREP_N0;
    if (i < PREP_N1) {
        int c = i >> 7, k = i & 127;
        float f = W1[k * C1 + c];
        unsigned short h = f2bf(f);
        w1h[i] = h; w1l[i] = f2bf(f - bf2f(h));
        return;
    }
    i -= PREP_N1;
    if (i < PREP_N2) {
        int c = i >> 8, k = i & 255;
        float f = W2[k * HID + c];
        unsigned short h = f2bf(f);
        w2h[i] = h; w2l[i] = f2bf(f - bf2f(h));
        return;
    }
    i -= PREP_N2;
    if (i < EP) {
        int d = (i < NE) ? ei[NE + i] : (i - NE);
        atomicAdd(&counts[d], 1);
    }
}

// ================= edge softmax weights (precomputed once per edge) ==========
__global__ void edge_w1k(const int* __restrict__ csr_src, const int* __restrict__ csr_dst,
                         const float* __restrict__ as1, const float* __restrict__ ad1,
                         float* __restrict__ w1e) {
    int i = blockIdx.x * 256 + threadIdx.x;
    if (i >= EP) return;
    int s = csr_src[i], d = csr_dst[i];
    float4 a = *(const float4*)(as1 + s * 4);
    float4 b = *(const float4*)(ad1 + d * 4);
    float4 o;
    float t;
    t = a.x + b.x; t = t > 0.f ? t : NEG * t; o.x = __expf(t);
    t = a.y + b.y; t = t > 0.f ? t : NEG * t; o.y = __expf(t);
    t = a.z + b.z; t = t > 0.f ? t : NEG * t; o.z = __expf(t);
    t = a.w + b.w; t = t > 0.f ? t : NEG * t; o.w = __expf(t);
    *(float4*)(w1e + (size_t)i * 4) = o;
}

__global__ void edge_w2k(const int* __restrict__ csr_src, const int* __restrict__ csr_dst,
                         const float* __restrict__ as2, const float* __restrict__ ad2,
                         float* __restrict__ w2e) {
    int i = blockIdx.x * 256 + threadIdx.x;
    if (i >= EP) return;
    float t = as2[csr_src[i]] + ad2[csr_dst[i]];
    t = t > 0.f ? t : NEG * t;
    w2e[i] = __expf(t);
}

// ================= GEMM1 via split-bf16 MFMA + att1 epilogue =================
__global__ __launch_bounds__(256) void gemm1_mfma(const float* __restrict__ x,
                                                  const unsigned short* __restrict__ w1h,
                                                  const unsigned short* __restrict__ w1l,
                                                  const float* __restrict__ att_s,
                                                  const float* __restrict__ att_d,
                                                  unsigned short* __restrict__ h1b,
                                                  float* __restrict__ as1,
                                                  float* __restrict__ ad1) {
    __shared__ unsigned short wH[64 * KP1];
    __shared__ unsigned short wL[64 * KP1];
    const int tid = threadIdx.x;
    const int n0 = blockIdx.x * 64;
    const int q  = blockIdx.y;

    for (int idx = tid; idx < 64 * 16; idx += 256) {
        int col = idx >> 4, ch = idx & 15;
        *(bf16x8*)(wH + col * KP1 + ch * 8) =
            *(const bf16x8*)(w1h + ((q * 64 + col) << 7) + ch * 8);
        *(bf16x8*)(wL + col * KP1 + ch * 8) =
            *(const bf16x8*)(w1l + ((q * 64 + col) << 7) + ch * 8);
    }

    const int w = tid >> 6, l = tid & 63;
    const int cl = l & 15, g = l >> 4, g8 = g * 8;
    const int na = min(n0 + w * 16 + cl, NN - 1);

    bf16x8 aH[4], aL[4];
#pragma unroll
    for (int kk = 0; kk < 4; ++kk) {
        const float* ap = x + (size_t)na * INC + kk * 32 + g8;
        float4 v0 = *(const float4*)ap;
        float4 v1 = *(const float4*)(ap + 4);
        float vv[8] = {v0.x, v0.y, v0.z, v0.w, v1.x, v1.y, v1.z, v1.w};
#pragma unroll
        for (int j = 0; j < 8; ++j) {
            unsigned short h = f2bf(vv[j]);
            aH[kk][j] = (short)h;
            aL[kk][j] = (short)f2bf(vv[j] - bf2f(h));
        }
    }

    f32x4 acc[4];
#pragma unroll
    for (int ct = 0; ct < 4; ++ct) acc[ct] = (f32x4){0.f, 0.f, 0.f, 0.f};

    __syncthreads();

#pragma unroll
    for (int kk = 0; kk < 4; ++kk) {
        const int ko = kk * 32 + g8;
#pragma unroll
        for (int ct = 0; ct < 4; ++ct) {
            const bf16x8 bH = *(const bf16x8*)(wH + (ct * 16 + cl) * KP1 + ko);
            const bf16x8 bL = *(const bf16x8*)(wL + (ct * 16 + cl) * KP1 + ko);
            acc[ct] = __builtin_amdgcn_mfma_f32_16x16x32_bf16(aH[kk], bH, acc[ct], 0, 0, 0);
            acc[ct] = __builtin_amdgcn_mfma_f32_16x16x32_bf16(aH[kk], bL, acc[ct], 0, 0, 0);
            acc[ct] = __builtin_amdgcn_mfma_f32_16x16x32_bf16(aL[kk], bH, acc[ct], 0, 0, 0);
        }
    }

    float asc[4], adc[4];
#pragma unroll
    for (int ct = 0; ct < 4; ++ct) {
        asc[ct] = att_s[q * 64 + ct * 16 + cl];
        adc[ct] = att_d[q * 64 + ct * 16 + cl];
    }

#pragma unroll
    for (int reg = 0; reg < 4; ++reg) {
        const int nd = n0 + w * 16 + g * 4 + reg;
        float sa = 0.f, sd = 0.f;
#pragma unroll
        for (int ct = 0; ct < 4; ++ct) {
            sa += acc[ct][reg] * asc[ct];
            sd += acc[ct][reg] * adc[ct];
        }
#pragma unroll
        for (int off = 8; off > 0; off >>= 1) {
            sa += __shfl_xor(sa, off);
            sd += __shfl_xor(sd, off);
        }
        if (nd < NN) {
#pragma unroll
            for (int ct = 0; ct < 4; ++ct)
                h1b[(size_t)nd * C1 + q * 64 + ct * 16 + cl] = f2bf(acc[ct][reg]);
            if (cl == 0) { as1[nd * 4 + q] = sa; ad1[nd * 4 + q] = sd; }
        }
    }
}

// ================= GEMM2: bf16-A x split-bf16-W MFMA + att2 epilogue =========
__global__ __launch_bounds__(256) void gemm2_mfma(const unsigned short* __restrict__ h1c,
                                                  const unsigned short* __restrict__ w2h,
                                                  const unsigned short* __restrict__ w2l,
                                                  const float* __restrict__ att_s,
                                                  const float* __restrict__ att_d,
                                                  unsigned short* __restrict__ h2b,
                                                  float* __restrict__ as2,
                                                  float* __restrict__ ad2) {
    __shared__ unsigned short wH[64 * KP2];
    __shared__ unsigned short wL[64 * KP2];
    const int tid = threadIdx.x;
    const int n0 = blockIdx.x * 64;

    for (int idx = tid; idx < 64 * 32; idx += 256) {
        int col = idx >> 5, ch = idx & 31;
        *(bf16x8*)(wH + col * KP2 + ch * 8) =
            *(const bf16x8*)(w2h + ((col) << 8) + ch * 8);
        *(bf16x8*)(wL + col * KP2 + ch * 8) =
            *(const bf16x8*)(w2l + ((col) << 8) + ch * 8);
    }

    const int w = tid >> 6, l = tid & 63;
    const int cl = l & 15, g = l >> 4, g8 = g * 8;
    const int na = min(n0 + w * 16 + cl, NN - 1);

    f32x4 acc[4];
#pragma unroll
    for (int ct = 0; ct < 4; ++ct) acc[ct] = (f32x4){0.f, 0.f, 0.f, 0.f};

    __syncthreads();

#pragma unroll
    for (int kk = 0; kk < 8; ++kk) {
        const bf16x8 aH = *(const bf16x8*)(h1c + (size_t)na * C1 + kk * 32 + g8);
        const int ko = kk * 32 + g8;
#pragma unroll
        for (int ct = 0; ct < 4; ++ct) {
            const bf16x8 bH = *(const bf16x8*)(wH + (ct * 16 + cl) * KP2 + ko);
            const bf16x8 bL = *(const bf16x8*)(wL + (ct * 16 + cl) * KP2 + ko);
            acc[ct] = __builtin_amdgcn_mfma_f32_16x16x32_bf16(aH, bH, acc[ct], 0, 0, 0);
            acc[ct] = __builtin_amdgcn_mfma_f32_16x16x32_bf16(aH, bL, acc[ct], 0, 0, 0);
        }
    }

    float asc[4], adc[4];
#pragma unroll
    for (int ct = 0; ct < 4; ++ct) {
        asc[ct] = att_s[ct * 16 + cl];
        adc[ct] = att_d[ct * 16 + cl];
    }

#pragma unroll
    for (int reg = 0; reg < 4; ++reg) {
        const int nd = n0 + w * 16 + g * 4 + reg;
        float sa = 0.f, sd = 0.f;
#pragma unroll
        for (int ct = 0; ct < 4; ++ct) {
            sa += acc[ct][reg] * asc[ct];
            sd += acc[ct][reg] * adc[ct];
        }
#pragma unroll
        for (int off = 8; off > 0; off >>= 1) {
            sa += __shfl_xor(sa, off);
            sd += __shfl_xor(sd, off);
        }
        if (nd < NN) {
#pragma unroll
            for (int ct = 0; ct < 4; ++ct)
                h2b[(size_t)nd * HID + ct * 16 + cl] = f2bf(acc[ct][reg]);
            if (cl == 0) { as2[nd] = sa; ad2[nd] = sd; }
        }
    }
}

// ================= conv1 aggregate: 2 nodes/wave, precomputed weights =========
// 32 lanes per node, bf16x8 (16B) per lane; weights w1e sequential.
__global__ __launch_bounds__(256) void conv1_agg(const int* __restrict__ rowptr,
                                                 const int* __restrict__ csr_src,
                                                 const float* __restrict__ w1e,
                                                 const unsigned short* __restrict__ h1b,
                                                 const float* __restrict__ b1,
                                                 unsigned short* __restrict__ h1c) {
    const int tid  = threadIdx.x;
    const int wid  = tid >> 6;
    const int l    = tid & 63;
    const int half = l >> 5;
    const int l32  = l & 31;
    const int node = blockIdx.x * 8 + wid * 2 + half;   // NN % 8 == 0
    const int hd   = l32 >> 3;
    const int beg = rowptr[node], end = rowptr[node + 1];

    float acc[8] = {0.f, 0.f, 0.f, 0.f, 0.f, 0.f, 0.f, 0.f};
    float sm = 0.f;
#pragma unroll 2
    for (int i = beg; i < end; ++i) {
        int s = csr_src[i];
        float w = w1e[(size_t)i * 4 + hd];
        bf16x8 hv = *(const bf16x8*)(h1b + (size_t)s * C1 + l32 * 8);
#pragma unroll
        for (int j = 0; j < 8; ++j)
            acc[j] += w * bf2f((unsigned short)hv[j]);
        sm += w;
    }
    const float rden = 1.f / (sm + EPSS);

    const float* bp = b1 + l32 * 8;
    bf16x8 ob;
#pragma unroll
    for (int j = 0; j < 8; ++j) {
        float o = acc[j] * rden + bp[j];
        o = o > 0.f ? o : (__expf(o) - 1.f);
        ob[j] = (short)f2bf(o);
    }
    *(bf16x8*)(h1c + (size_t)node * C1 + l32 * 8) = ob;
}

// ================= conv2 aggregate: 2 nodes/wave, precomputed weights =========
__global__ __launch_bounds__(256) void conv2_agg(const int* __restrict__ rowptr,
                                                 const int* __restrict__ csr_src,
                                                 const float* __restrict__ w2e,
                                                 const unsigned short* __restrict__ h2b,
                                                 const float* __restrict__ b2,
                                                 unsigned short* __restrict__ embb) {
    const int tid  = threadIdx.x;
    const int wid  = tid >> 6;
    const int l    = tid & 63;
    const int half = l >> 5;
    const int l32  = l & 31;
    const int node = blockIdx.x * 8 + wid * 2 + half;
    const int beg = rowptr[node], end = rowptr[node + 1];

    float a0 = 0.f, a1 = 0.f, sm = 0.f;
#pragma unroll 2
    for (int i = beg; i < end; ++i) {
        int s = csr_src[i];
        float w = w2e[i];
        unsigned hv = *(const unsigned*)(h2b + (size_t)s * HID + l32 * 2);
        a0 += w * bf2f((unsigned short)(hv & 0xFFFF));
        a1 += w * bf2f((unsigned short)(hv >> 16));
        sm += w;
    }
    const float rden = 1.f / (sm + EPSS);
    float o0 = a0 * rden + b2[l32 * 2];
    float o1 = a1 * rden + b2[l32 * 2 + 1];
    unsigned outw = (unsigned)f2bf(o0) | ((unsigned)f2bf(o1) << 16);
    *(unsigned*)(embb + (size_t)node * HID + l32 * 2) = outw;
}

// ================= edge MLP: persistent waves, W in registers, NO LDS =========
__global__ __launch_bounds__(256) void edge_mlp_mfma(const int* __restrict__ ei,
                                                     const unsigned short* __restrict__ embb,
                                                     const float* __restrict__ stats,
                                                     const unsigned short* __restrict__ wTh,
                                                     const unsigned short* __restrict__ wTl,
                                                     const float* __restrict__ mb1,
                                                     const float* __restrict__ mW2,
                                                     const float* __restrict__ mb2,
                                                     float* __restrict__ out) {
    const int l  = threadIdx.x & 63;
    const int cl = l & 15;
    const int g  = l >> 4;
    const int g8 = g * 8;

    bf16x8 bH[5][4], bL[5][4];
#pragma unroll
    for (int kk = 0; kk < 5; ++kk)
#pragma unroll
        for (int ct = 0; ct < 4; ++ct) {
            bH[kk][ct] = *(const bf16x8*)(wTh + (ct * 16 + cl) * KP + kk * 32 + g8);
            bL[kk][ct] = *(const bf16x8*)(wTl + (ct * 16 + cl) * KP + kk * 32 + g8);
        }

    float bia[4], w2a[4], w2b[4];
#pragma unroll
    for (int ct = 0; ct < 4; ++ct) {
        bia[ct] = mb1[ct * 16 + cl];
        w2a[ct] = mW2[(ct * 16 + cl) * 2 + 0];
        w2b[ct] = mW2[(ct * 16 + cl) * 2 + 1];
    }
    const float ob0 = mb2[0], ob1 = mb2[1];

    const int wave0  = blockIdx.x * 4 + (threadIdx.x >> 6);
    const int nwaves = gridDim.x * 4;

    for (int t = wave0; t < NE / 16; t += nwaves) {
        const int ge_a = t * 16 + cl;
        const int rn = ei[ge_a];
        const int cn = ei[NE + ge_a];
        const unsigned short* rp = embb + (size_t)rn * HID;
        const unsigned short* cp = embb + (size_t)cn * HID;

        bf16x8 aH[5];
        aH[0] = *(const bf16x8*)(rp + g8);
        aH[1] = *(const bf16x8*)(rp + 32 + g8);
        aH[2] = *(const bf16x8*)(cp + g8);
        aH[3] = *(const bf16x8*)(cp + 32 + g8);
        {
            bf16x8 z = {0, 0, 0, 0, 0, 0, 0, 0};
            if (g == 0) {
                z[0] = (short)f2bf(stats[(size_t)ge_a * 3 + 0]);
                z[1] = (short)f2bf(stats[(size_t)ge_a * 3 + 1]);
                z[2] = (short)f2bf(stats[(size_t)ge_a * 3 + 2]);
            }
            aH[4] = z;
        }

        f32x4 acc[4];
#pragma unroll
        for (int ct = 0; ct < 4; ++ct)
            acc[ct] = (f32x4){bia[ct], bia[ct], bia[ct], bia[ct]};

#pragma unroll
        for (int kk = 0; kk < 5; ++kk) {
#pragma unroll
            for (int ct = 0; ct < 4; ++ct) {
                acc[ct] = __builtin_amdgcn_mfma_f32_16x16x32_bf16(aH[kk], bH[kk][ct], acc[ct], 0, 0, 0);
                acc[ct] = __builtin_amdgcn_mfma_f32_16x16x32_bf16(aH[kk], bL[kk][ct], acc[ct], 0, 0, 0);
            }
        }

#pragma unroll
        for (int reg = 0; reg < 4; ++reg) {
            float p0 = 0.f, p1 = 0.f;
#pragma unroll
            for (int ct = 0; ct < 4; ++ct) {
                float h = fmaxf(acc[ct][reg], 0.f);
                p0 += h * w2a[ct];
                p1 += h * w2b[ct];
            }
#pragma unroll
            for (int off = 8; off > 0; off >>= 1) {
                p0 += __shfl_xor(p0, off);
                p1 += __shfl_xor(p1, off);
            }
            if (cl == 0) {
                const int ge = t * 16 + g * 4 + reg;
                *(float2*)(out + (size_t)ge * 2) = make_float2(p0 + ob0, p1 + ob1);
            }
        }
    }
}

// ================= launcher =================
extern "C" void kernel_launch(void* const* d_in, const int* in_sizes, int n_in,
                              void* d_out, int out_size, void* d_ws, size_t ws_size,
                              hipStream_t stream) {
    const float* x      = (const float*)d_in[0];
    const int*   ei     = (const int*)d_in[1];
    const float* stats  = (const float*)d_in[2];
    const float* W1     = (const float*)d_in[3];
    const float* att_s1 = (const float*)d_in[4];
    const float* att_d1 = (const float*)d_in[5];
    const float* b1     = (const float*)d_in[6];
    const float* W2     = (const float*)d_in[7];
    const float* att_s2 = (const float*)d_in[8];
    const float* att_d2 = (const float*)d_in[9];
    const float* b2     = (const float*)d_in[10];
    const float* mW1    = (const float*)d_in[11];
    const float* mb1    = (const float*)d_in[12];
    const float* mW2    = (const float*)d_in[13];
    const float* mb2    = (const float*)d_in[14];
    float* out = (float*)d_out;
    float* ws  = (float*)d_ws;

    // f32-word-offset layout (no aliasing)
    int*   rowptr  = (int*)ws;                                 // NN+16
    int*   csr_src = rowptr + NN + 16;                         // EP
    int*   csr_dst = csr_src + EP;                             // EP
    float* as1     = (float*)(csr_dst + EP);                   // 4NN
    float* ad1     = as1 + (size_t)4 * NN;                     // 4NN
    unsigned short* h1b = (unsigned short*)(ad1 + (size_t)4 * NN);   // NN*256 bf16
    unsigned short* h1c = h1b + (size_t)256 * NN;              // NN*256 bf16
    unsigned short* h2b = h1c + (size_t)256 * NN;              // NN*64 bf16
    unsigned short* embb = h2b + (size_t)64 * NN;              // NN*64 bf16
    float* as2     = (float*)(embb + (size_t)64 * NN);         // NN
    float* ad2     = as2 + NN;                                 // NN
    unsigned short* wTh = (unsigned short*)(ad2 + NN);         // 64*KP
    unsigned short* wTl = wTh + 64 * KP;
    unsigned short* w1h = wTl + 64 * KP;                       // 256*128
    unsigned short* w1l = w1h + C1 * INC;
    unsigned short* w2h = w1l + C1 * INC;                      // 64*256
    unsigned short* w2l = w2h + HID * C1;
    float* w1e     = (float*)(w2l + HID * C1 + 64);            // 4*EP
    float* w2e     = w1e + (size_t)4 * EP;                     // EP
    int*   counts  = (int*)(w2e + EP + 64);                    // NN
    int*   bsum    = counts + NN + 64;                         // NSB
    int*   cursor  = bsum + NSB + 64;                          // NN

    // ---- CSR build + weight prep ----
    hipMemsetAsync(counts, 0, NN * sizeof(int), stream);
    prep_all<<<(PREP_TOT + EP + 255) / 256, 256, 0, stream>>>(
        mW1, W1, W2, ei, wTh, wTl, w1h, w1l, w2h, w2l, counts);
    scan_partial<<<NSB, SCHUNK, 0, stream>>>(counts, bsum);
    scan_top<<<1, 128, 0, stream>>>(bsum, rowptr);
    scan_final<<<NSB, SCHUNK, 0, stream>>>(counts, bsum, rowptr, cursor);
    csr_fill<<<(EP + 255) / 256, 256, 0, stream>>>(ei, cursor, csr_src, csr_dst);

    // ---- conv1 ----
    gemm1_mfma<<<dim3((NN + 63) / 64, 4), 256, 0, stream>>>(x, w1h, w1l, att_s1, att_d1,
                                                            h1b, as1, ad1);
    edge_w1k<<<(EP + 255) / 256, 256, 0, stream>>>(csr_src, csr_dst, as1, ad1, w1e);
    conv1_agg<<<NN / 8, 256, 0, stream>>>(rowptr, csr_src, w1e, h1b, b1, h1c);

    // ---- conv2 ----
    gemm2_mfma<<<(NN + 63) / 64, 256, 0, stream>>>(h1c, w2h, w2l, att_s2, att_d2,
                                                   h2b, as2, ad2);
    edge_w2k<<<(EP + 255) / 256, 256, 0, stream>>>(csr_src, csr_dst, as2, ad2, w2e);
    conv2_agg<<<NN / 8, 256, 0, stream>>>(rowptr, csr_src, w2e, h2b, b2, embb);

    // ---- edge MLP: persistent, reg-resident W ----
    edge_mlp_mfma<<<512, 256, 0, stream>>>(ei, embb, stats, wTh, wTl,
                                           mb1, mW2, mb2, out);
}

// Round 11
// 310.951 us; speedup vs baseline: 8.9028x; 1.0269x over previous
//
#include <hip/hip_runtime.h>
#include <math.h>

#define NN 50000
#define NE 800000
#define EP (NE + NN)        // edges including self loops
#define INC 128
#define HID 64
#define HEADS 4
#define C1 (HEADS * HID)    // 256
#define NEG 0.2f
#define EPSS 1e-16f

#define SCHUNK 512
#define NSB ((NN + SCHUNK - 1) / SCHUNK)   // 98

#define KP  170             // edge-MLP W1^T storage stride (bf16 elems)
#define KP1 136             // gemm1 W1^T LDS stride
#define KP2 264             // gemm2 W2^T LDS stride
typedef __attribute__((ext_vector_type(8))) short bf16x8;
typedef __attribute__((ext_vector_type(4))) float f32x4;

// ---------- bf16 helpers ----------
__device__ __forceinline__ unsigned short f2bf(float f) {
    unsigned u = __float_as_uint(f);
    unsigned r = (u + 0x7FFFu + ((u >> 16) & 1u)) >> 16;
    return (unsigned short)r;
}
__device__ __forceinline__ float bf2f(unsigned short b) {
    return __uint_as_float(((unsigned)b) << 16);
}

// ================= CSR build (count merged into prep_all) =================
__global__ __launch_bounds__(SCHUNK) void scan_partial(const int* __restrict__ counts,
                                                       int* __restrict__ bsum) {
    __shared__ int lds[SCHUNK];
    int i = blockIdx.x * SCHUNK + threadIdx.x;
    lds[threadIdx.x] = (i < NN) ? counts[i] : 0;
    __syncthreads();
    for (int off = SCHUNK / 2; off > 0; off >>= 1) {
        if (threadIdx.x < off) lds[threadIdx.x] += lds[threadIdx.x + off];
        __syncthreads();
    }
    if (threadIdx.x == 0) bsum[blockIdx.x] = lds[0];
}

__global__ void scan_top(int* __restrict__ bsum, int* __restrict__ rowptr) {
    __shared__ int lds[NSB];
    int t = threadIdx.x;
    if (t < NSB) lds[t] = bsum[t];
    __syncthreads();
    if (t == 0) {
        int acc = 0;
        for (int i = 0; i < NSB; ++i) { int v = lds[i]; lds[i] = acc; acc += v; }
        rowptr[NN] = acc;   // == EP
    }
    __syncthreads();
    if (t < NSB) bsum[t] = lds[t];
}

__global__ __launch_bounds__(SCHUNK) void scan_final(const int* __restrict__ counts,
                                                     const int* __restrict__ bsum,
                                                     int* __restrict__ rowptr,
                                                     int* __restrict__ cursor) {
    __shared__ int lds[SCHUNK];
    int i = blockIdx.x * SCHUNK + threadIdx.x;
    int v = (i < NN) ? counts[i] : 0;
    lds[threadIdx.x] = v;
    __syncthreads();
    for (int off = 1; off < SCHUNK; off <<= 1) {
        int t = (threadIdx.x >= off) ? lds[threadIdx.x - off] : 0;
        __syncthreads();
        lds[threadIdx.x] += t;
        __syncthreads();
    }
    if (i < NN) {
        int excl = lds[threadIdx.x] - v + bsum[blockIdx.x];
        rowptr[i] = excl;
        cursor[i] = excl;
    }
}

__global__ void csr_fill(const int* __restrict__ ei, int* __restrict__ cursor,
                         int* __restrict__ csr_src, int* __restrict__ csr_dst) {
    int e = blockIdx.x * 256 + threadIdx.x;
    if (e >= EP) return;
    int s, d;
    if (e < NE) { s = ei[e]; d = ei[NE + e]; } else { s = d = e - NE; }
    int pos = atomicAdd(&cursor[d], 1);
    csr_src[pos] = s;
    csr_dst[pos] = d;
}

// ================= merged weight prep + edge count =================
#define PREP_N0 (64 * KP)
#define PREP_N1 (C1 * INC)
#define PREP_N2 (HID * C1)
#define PREP_TOT (PREP_N0 + PREP_N1 + PREP_N2)
__global__ void prep_all(const float* __restrict__ mW1, const float* __restrict__ W1,
                         const float* __restrict__ W2, const int* __restrict__ ei,
                         unsigned short* __restrict__ wTh, unsigned short* __restrict__ wTl,
                         unsigned short* __restrict__ w1h, unsigned short* __restrict__ w1l,
                         unsigned short* __restrict__ w2h, unsigned short* __restrict__ w2l,
                         int* __restrict__ counts) {
    int i = blockIdx.x * 256 + threadIdx.x;
    if (i < PREP_N0) {
        int c = i / KP, k = i % KP;
        unsigned short h = 0, l = 0;
        if (k < 131) {
            float f = mW1[k * 64 + c];
            h = f2bf(f);
            l = f2bf(f - bf2f(h));
        }
        wTh[i] = h; wTl[i] = l;
        return;
    }
    i -= PREP_N0;
    if (i < PREP_N1) {
        int c = i >> 7, k = i & 127;
        float f = W1[k * C1 + c];
        unsigned short h = f2bf(f);
        w1h[i] = h; w1l[i] = f2bf(f - bf2f(h));
        return;
    }
    i -= PREP_N1;
    if (i < PREP_N2) {
        int c = i >> 8, k = i & 255;
        float f = W2[k * HID + c];
        unsigned short h = f2bf(f);
        w2h[i] = h; w2l[i] = f2bf(f - bf2f(h));
        return;
    }
    i -= PREP_N2;
    if (i < EP) {
        int d = (i < NE) ? ei[NE + i] : (i - NE);
        atomicAdd(&counts[d], 1);
    }
}

// ================= edge softmax weights (precomputed once per edge) ==========
__global__ void edge_w1k(const int* __restrict__ csr_src, const int* __restrict__ csr_dst,
                         const float* __restrict__ as1, const float* __restrict__ ad1,
                         float* __restrict__ w1e) {
    int i = blockIdx.x * 256 + threadIdx.x;
    if (i >= EP) return;
    int s = csr_src[i], d = csr_dst[i];
    float4 a = *(const float4*)(as1 + s * 4);
    float4 b = *(const float4*)(ad1 + d * 4);
    float4 o;
    float t;
    t = a.x + b.x; t = t > 0.f ? t : NEG * t; o.x = __expf(t);
    t = a.y + b.y; t = t > 0.f ? t : NEG * t; o.y = __expf(t);
    t = a.z + b.z; t = t > 0.f ? t : NEG * t; o.z = __expf(t);
    t = a.w + b.w; t = t > 0.f ? t : NEG * t; o.w = __expf(t);
    *(float4*)(w1e + (size_t)i * 4) = o;
}

__global__ void edge_w2k(const int* __restrict__ csr_src, const int* __restrict__ csr_dst,
                         const float* __restrict__ as2, const float* __restrict__ ad2,
                         float* __restrict__ w2e) {
    int i = blockIdx.x * 256 + threadIdx.x;
    if (i >= EP) return;
    float t = as2[csr_src[i]] + ad2[csr_dst[i]];
    t = t > 0.f ? t : NEG * t;
    w2e[i] = __expf(t);
}

// ================= GEMM1 via split-bf16 MFMA + att1 epilogue =================
__global__ __launch_bounds__(256) void gemm1_mfma(const float* __restrict__ x,
                                                  const unsigned short* __restrict__ w1h,
                                                  const unsigned short* __restrict__ w1l,
                                                  const float* __restrict__ att_s,
                                                  const float* __restrict__ att_d,
                                                  unsigned short* __restrict__ h1b,
                                                  float* __restrict__ as1,
                                                  float* __restrict__ ad1) {
    __shared__ unsigned short wH[64 * KP1];
    __shared__ unsigned short wL[64 * KP1];
    const int tid = threadIdx.x;
    const int n0 = blockIdx.x * 64;
    const int q  = blockIdx.y;

    for (int idx = tid; idx < 64 * 16; idx += 256) {
        int col = idx >> 4, ch = idx & 15;
        *(bf16x8*)(wH + col * KP1 + ch * 8) =
            *(const bf16x8*)(w1h + ((q * 64 + col) << 7) + ch * 8);
        *(bf16x8*)(wL + col * KP1 + ch * 8) =
            *(const bf16x8*)(w1l + ((q * 64 + col) << 7) + ch * 8);
    }

    const int w = tid >> 6, l = tid & 63;
    const int cl = l & 15, g = l >> 4, g8 = g * 8;
    const int na = min(n0 + w * 16 + cl, NN - 1);

    bf16x8 aH[4], aL[4];
#pragma unroll
    for (int kk = 0; kk < 4; ++kk) {
        const float* ap = x + (size_t)na * INC + kk * 32 + g8;
        float4 v0 = *(const float4*)ap;
        float4 v1 = *(const float4*)(ap + 4);
        float vv[8] = {v0.x, v0.y, v0.z, v0.w, v1.x, v1.y, v1.z, v1.w};
#pragma unroll
        for (int j = 0; j < 8; ++j) {
            unsigned short h = f2bf(vv[j]);
            aH[kk][j] = (short)h;
            aL[kk][j] = (short)f2bf(vv[j] - bf2f(h));
        }
    }

    f32x4 acc[4];
#pragma unroll
    for (int ct = 0; ct < 4; ++ct) acc[ct] = (f32x4){0.f, 0.f, 0.f, 0.f};

    __syncthreads();

#pragma unroll
    for (int kk = 0; kk < 4; ++kk) {
        const int ko = kk * 32 + g8;
#pragma unroll
        for (int ct = 0; ct < 4; ++ct) {
            const bf16x8 bH = *(const bf16x8*)(wH + (ct * 16 + cl) * KP1 + ko);
            const bf16x8 bL = *(const bf16x8*)(wL + (ct * 16 + cl) * KP1 + ko);
            acc[ct] = __builtin_amdgcn_mfma_f32_16x16x32_bf16(aH[kk], bH, acc[ct], 0, 0, 0);
            acc[ct] = __builtin_amdgcn_mfma_f32_16x16x32_bf16(aH[kk], bL, acc[ct], 0, 0, 0);
            acc[ct] = __builtin_amdgcn_mfma_f32_16x16x32_bf16(aL[kk], bH, acc[ct], 0, 0, 0);
        }
    }

    float asc[4], adc[4];
#pragma unroll
    for (int ct = 0; ct < 4; ++ct) {
        asc[ct] = att_s[q * 64 + ct * 16 + cl];
        adc[ct] = att_d[q * 64 + ct * 16 + cl];
    }

#pragma unroll
    for (int reg = 0; reg < 4; ++reg) {
        const int nd = n0 + w * 16 + g * 4 + reg;
        float sa = 0.f, sd = 0.f;
#pragma unroll
        for (int ct = 0; ct < 4; ++ct) {
            sa += acc[ct][reg] * asc[ct];
            sd += acc[ct][reg] * adc[ct];
        }
#pragma unroll
        for (int off = 8; off > 0; off >>= 1) {
            sa += __shfl_xor(sa, off);
            sd += __shfl_xor(sd, off);
        }
        if (nd < NN) {
#pragma unroll
            for (int ct = 0; ct < 4; ++ct)
                h1b[(size_t)nd * C1 + q * 64 + ct * 16 + cl] = f2bf(acc[ct][reg]);
            if (cl == 0) { as1[nd * 4 + q] = sa; ad1[nd * 4 + q] = sd; }
        }
    }
}

// ================= GEMM2: bf16-A x split-bf16-W MFMA + att2 epilogue =========
__global__ __launch_bounds__(256) void gemm2_mfma(const unsigned short* __restrict__ h1c,
                                                  const unsigned short* __restrict__ w2h,
                                                  const unsigned short* __restrict__ w2l,
                                                  const float* __restrict__ att_s,
                                                  const float* __restrict__ att_d,
                                                  unsigned short* __restrict__ h2b,
                                                  float* __restrict__ as2,
                                                  float* __restrict__ ad2) {
    __shared__ unsigned short wH[64 * KP2];
    __shared__ unsigned short wL[64 * KP2];
    const int tid = threadIdx.x;
    const int n0 = blockIdx.x * 64;

    for (int idx = tid; idx < 64 * 32; idx += 256) {
        int col = idx >> 5, ch = idx & 31;
        *(bf16x8*)(wH + col * KP2 + ch * 8) =
            *(const bf16x8*)(w2h + ((col) << 8) + ch * 8);
        *(bf16x8*)(wL + col * KP2 + ch * 8) =
            *(const bf16x8*)(w2l + ((col) << 8) + ch * 8);
    }

    const int w = tid >> 6, l = tid & 63;
    const int cl = l & 15, g = l >> 4, g8 = g * 8;
    const int na = min(n0 + w * 16 + cl, NN - 1);

    f32x4 acc[4];
#pragma unroll
    for (int ct = 0; ct < 4; ++ct) acc[ct] = (f32x4){0.f, 0.f, 0.f, 0.f};

    __syncthreads();

#pragma unroll
    for (int kk = 0; kk < 8; ++kk) {
        const bf16x8 aH = *(const bf16x8*)(h1c + (size_t)na * C1 + kk * 32 + g8);
        const int ko = kk * 32 + g8;
#pragma unroll
        for (int ct = 0; ct < 4; ++ct) {
            const bf16x8 bH = *(const bf16x8*)(wH + (ct * 16 + cl) * KP2 + ko);
            const bf16x8 bL = *(const bf16x8*)(wL + (ct * 16 + cl) * KP2 + ko);
            acc[ct] = __builtin_amdgcn_mfma_f32_16x16x32_bf16(aH, bH, acc[ct], 0, 0, 0);
            acc[ct] = __builtin_amdgcn_mfma_f32_16x16x32_bf16(aH, bL, acc[ct], 0, 0, 0);
        }
    }

    float asc[4], adc[4];
#pragma unroll
    for (int ct = 0; ct < 4; ++ct) {
        asc[ct] = att_s[ct * 16 + cl];
        adc[ct] = att_d[ct * 16 + cl];
    }

#pragma unroll
    for (int reg = 0; reg < 4; ++reg) {
        const int nd = n0 + w * 16 + g * 4 + reg;
        float sa = 0.f, sd = 0.f;
#pragma unroll
        for (int ct = 0; ct < 4; ++ct) {
            sa += acc[ct][reg] * asc[ct];
            sd += acc[ct][reg] * adc[ct];
        }
#pragma unroll
        for (int off = 8; off > 0; off >>= 1) {
            sa += __shfl_xor(sa, off);
            sd += __shfl_xor(sd, off);
        }
        if (nd < NN) {
#pragma unroll
            for (int ct = 0; ct < 4; ++ct)
                h2b[(size_t)nd * HID + ct * 16 + cl] = f2bf(acc[ct][reg]);
            if (cl == 0) { as2[nd] = sa; ad2[nd] = sd; }
        }
    }
}

// ================= conv1 aggregate: 2 nodes/wave, precomputed weights =========
__global__ __launch_bounds__(256) void conv1_agg(const int* __restrict__ rowptr,
                                                 const int* __restrict__ csr_src,
                                                 const float* __restrict__ w1e,
                                                 const unsigned short* __restrict__ h1b,
                                                 const float* __restrict__ b1,
                                                 unsigned short* __restrict__ h1c) {
    const int tid  = threadIdx.x;
    const int wid  = tid >> 6;
    const int l    = tid & 63;
    const int half = l >> 5;
    const int l32  = l & 31;
    const int node = blockIdx.x * 8 + wid * 2 + half;   // NN % 8 == 0
    const int hd   = l32 >> 3;
    const int beg = rowptr[node], end = rowptr[node + 1];

    float acc[8] = {0.f, 0.f, 0.f, 0.f, 0.f, 0.f, 0.f, 0.f};
    float sm = 0.f;
#pragma unroll 2
    for (int i = beg; i < end; ++i) {
        int s = csr_src[i];
        float w = w1e[(size_t)i * 4 + hd];
        bf16x8 hv = *(const bf16x8*)(h1b + (size_t)s * C1 + l32 * 8);
#pragma unroll
        for (int j = 0; j < 8; ++j)
            acc[j] += w * bf2f((unsigned short)hv[j]);
        sm += w;
    }
    const float rden = 1.f / (sm + EPSS);

    const float* bp = b1 + l32 * 8;
    bf16x8 ob;
#pragma unroll
    for (int j = 0; j < 8; ++j) {
        float o = acc[j] * rden + bp[j];
        o = o > 0.f ? o : (__expf(o) - 1.f);
        ob[j] = (short)f2bf(o);
    }
    *(bf16x8*)(h1c + (size_t)node * C1 + l32 * 8) = ob;
}

// ================= conv2 aggregate: 2 nodes/wave, precomputed weights =========
__global__ __launch_bounds__(256) void conv2_agg(const int* __restrict__ rowptr,
                                                 const int* __restrict__ csr_src,
                                                 const float* __restrict__ w2e,
                                                 const unsigned short* __restrict__ h2b,
                                                 const float* __restrict__ b2,
                                                 unsigned short* __restrict__ embb) {
    const int tid  = threadIdx.x;
    const int wid  = tid >> 6;
    const int l    = tid & 63;
    const int half = l >> 5;
    const int l32  = l & 31;
    const int node = blockIdx.x * 8 + wid * 2 + half;
    const int beg = rowptr[node], end = rowptr[node + 1];

    float a0 = 0.f, a1 = 0.f, sm = 0.f;
#pragma unroll 2
    for (int i = beg; i < end; ++i) {
        int s = csr_src[i];
        float w = w2e[i];
        unsigned hv = *(const unsigned*)(h2b + (size_t)s * HID + l32 * 2);
        a0 += w * bf2f((unsigned short)(hv & 0xFFFF));
        a1 += w * bf2f((unsigned short)(hv >> 16));
        sm += w;
    }
    const float rden = 1.f / (sm + EPSS);
    float o0 = a0 * rden + b2[l32 * 2];
    float o1 = a1 * rden + b2[l32 * 2 + 1];
    unsigned outw = (unsigned)f2bf(o0) | ((unsigned)f2bf(o1) << 16);
    *(unsigned*)(embb + (size_t)node * HID + l32 * 2) = outw;
}

// ================= edge MLP: persistent, B reg-resident (256-VGPR budget) =====
// K=128 via MFMA (32/tile); stats columns (k=128..130) handled as exact f32
// FMAs in the epilogue. 1-deep software pipeline on the A-gather.
__global__ __launch_bounds__(256, 2) void edge_mlp_mfma(const int* __restrict__ ei,
                                                        const unsigned short* __restrict__ embb,
                                                        const float* __restrict__ stats,
                                                        const unsigned short* __restrict__ wTh,
                                                        const unsigned short* __restrict__ wTl,
                                                        const float* __restrict__ mW1,
                                                        const float* __restrict__ mb1,
                                                        const float* __restrict__ mW2,
                                                        const float* __restrict__ mb2,
                                                        float* __restrict__ out) {
    const int l  = threadIdx.x & 63;
    const int cl = l & 15;
    const int g  = l >> 4;
    const int g8 = g * 8;

    // B fragments (K=0..127) -> registers (block-invariant, lane-determined)
    bf16x8 bH[4][4], bL[4][4];
#pragma unroll
    for (int kk = 0; kk < 4; ++kk)
#pragma unroll
        for (int ct = 0; ct < 4; ++ct) {
            bH[kk][ct] = *(const bf16x8*)(wTh + (ct * 16 + cl) * KP + kk * 32 + g8);
            bL[kk][ct] = *(const bf16x8*)(wTl + (ct * 16 + cl) * KP + kk * 32 + g8);
        }

    // stats rows of W1 (k=128..130), exact f32
    float w1s0[4], w1s1[4], w1s2[4];
    float bia[4], w2a[4], w2b[4];
#pragma unroll
    for (int ct = 0; ct < 4; ++ct) {
        const int col = ct * 16 + cl;
        w1s0[ct] = mW1[128 * 64 + col];
        w1s1[ct] = mW1[129 * 64 + col];
        w1s2[ct] = mW1[130 * 64 + col];
        bia[ct] = mb1[col];
        w2a[ct] = mW2[col * 2 + 0];
        w2b[ct] = mW2[col * 2 + 1];
    }
    const float ob0 = mb2[0], ob1 = mb2[1];

    const int wave0  = blockIdx.x * 4 + (threadIdx.x >> 6);
    const int nwaves = gridDim.x * 4;
    const int NT = NE / 16;

    int t = wave0;
    if (t >= NT) return;

    // prefetch tile t
    bf16x8 a0, a1, a2, a3;
    float st[12];
    {
        const int rn = ei[t * 16 + cl];
        const int cn = ei[NE + t * 16 + cl];
        const unsigned short* rp = embb + (size_t)rn * HID;
        const unsigned short* cp = embb + (size_t)cn * HID;
        a0 = *(const bf16x8*)(rp + g8);
        a1 = *(const bf16x8*)(rp + 32 + g8);
        a2 = *(const bf16x8*)(cp + g8);
        a3 = *(const bf16x8*)(cp + 32 + g8);
#pragma unroll
        for (int r = 0; r < 4; ++r) {
            const size_t e = (size_t)(t * 16 + g * 4 + r) * 3;
            st[r * 3 + 0] = stats[e + 0];
            st[r * 3 + 1] = stats[e + 1];
            st[r * 3 + 2] = stats[e + 2];
        }
    }

    while (t < NT) {
        const int tn = t + nwaves;
        // move current into named regs
        bf16x8 c0 = a0, c1 = a1, c2 = a2, c3 = a3;
        float cst[12];
#pragma unroll
        for (int j = 0; j < 12; ++j) cst[j] = st[j];

        // prefetch next tile (independent of this tile's compute)
        if (tn < NT) {
            const int rn = ei[tn * 16 + cl];
            const int cn = ei[NE + tn * 16 + cl];
            const unsigned short* rp = embb + (size_t)rn * HID;
            const unsigned short* cp = embb + (size_t)cn * HID;
            a0 = *(const bf16x8*)(rp + g8);
            a1 = *(const bf16x8*)(rp + 32 + g8);
            a2 = *(const bf16x8*)(cp + g8);
            a3 = *(const bf16x8*)(cp + 32 + g8);
#pragma unroll
            for (int r = 0; r < 4; ++r) {
                const size_t e = (size_t)(tn * 16 + g * 4 + r) * 3;
                st[r * 3 + 0] = stats[e + 0];
                st[r * 3 + 1] = stats[e + 1];
                st[r * 3 + 2] = stats[e + 2];
            }
        }

        f32x4 acc[4];
#pragma unroll
        for (int ct = 0; ct < 4; ++ct)
            acc[ct] = (f32x4){bia[ct], bia[ct], bia[ct], bia[ct]};

#pragma unroll
        for (int ct = 0; ct < 4; ++ct) {
            acc[ct] = __builtin_amdgcn_mfma_f32_16x16x32_bf16(c0, bH[0][ct], acc[ct], 0, 0, 0);
            acc[ct] = __builtin_amdgcn_mfma_f32_16x16x32_bf16(c0, bL[0][ct], acc[ct], 0, 0, 0);
            acc[ct] = __builtin_amdgcn_mfma_f32_16x16x32_bf16(c1, bH[1][ct], acc[ct], 0, 0, 0);
            acc[ct] = __builtin_amdgcn_mfma_f32_16x16x32_bf16(c1, bL[1][ct], acc[ct], 0, 0, 0);
            acc[ct] = __builtin_amdgcn_mfma_f32_16x16x32_bf16(c2, bH[2][ct], acc[ct], 0, 0, 0);
            acc[ct] = __builtin_amdgcn_mfma_f32_16x16x32_bf16(c2, bL[2][ct], acc[ct], 0, 0, 0);
            acc[ct] = __builtin_amdgcn_mfma_f32_16x16x32_bf16(c3, bH[3][ct], acc[ct], 0, 0, 0);
            acc[ct] = __builtin_amdgcn_mfma_f32_16x16x32_bf16(c3, bL[3][ct], acc[ct], 0, 0, 0);
        }

        // stats contribution (exact f32), then layer 2 + reduce + store
#pragma unroll
        for (int reg = 0; reg < 4; ++reg) {
            float p0 = 0.f, p1 = 0.f;
#pragma unroll
            for (int ct = 0; ct < 4; ++ct) {
                float h = acc[ct][reg]
                        + cst[reg * 3 + 0] * w1s0[ct]
                        + cst[reg * 3 + 1] * w1s1[ct]
                        + cst[reg * 3 + 2] * w1s2[ct];
                h = fmaxf(h, 0.f);
                p0 += h * w2a[ct];
                p1 += h * w2b[ct];
            }
#pragma unroll
            for (int off = 8; off > 0; off >>= 1) {
                p0 += __shfl_xor(p0, off);
                p1 += __shfl_xor(p1, off);
            }
            if (cl == 0) {
                const int ge = t * 16 + g * 4 + reg;
                *(float2*)(out + (size_t)ge * 2) = make_float2(p0 + ob0, p1 + ob1);
            }
        }
        t = tn;
    }
}

// ================= launcher =================
extern "C" void kernel_launch(void* const* d_in, const int* in_sizes, int n_in,
                              void* d_out, int out_size, void* d_ws, size_t ws_size,
                              hipStream_t stream) {
    const float* x      = (const float*)d_in[0];
    const int*   ei     = (const int*)d_in[1];
    const float* stats  = (const float*)d_in[2];
    const float* W1     = (const float*)d_in[3];
    const float* att_s1 = (const float*)d_in[4];
    const float* att_d1 = (const float*)d_in[5];
    const float* b1     = (const float*)d_in[6];
    const float* W2     = (const float*)d_in[7];
    const float* att_s2 = (const float*)d_in[8];
    const float* att_d2 = (const float*)d_in[9];
    const float* b2     = (const float*)d_in[10];
    const float* mW1    = (const float*)d_in[11];
    const float* mb1    = (const float*)d_in[12];
    const float* mW2    = (const float*)d_in[13];
    const float* mb2    = (const float*)d_in[14];
    float* out = (float*)d_out;
    float* ws  = (float*)d_ws;

    // f32-word-offset layout (no aliasing)
    int*   rowptr  = (int*)ws;                                 // NN+16
    int*   csr_src = rowptr + NN + 16;                         // EP
    int*   csr_dst = csr_src + EP;                             // EP
    float* as1     = (float*)(csr_dst + EP);                   // 4NN
    float* ad1     = as1 + (size_t)4 * NN;                     // 4NN
    unsigned short* h1b = (unsigned short*)(ad1 + (size_t)4 * NN);   // NN*256 bf16
    unsigned short* h1c = h1b + (size_t)256 * NN;              // NN*256 bf16
    unsigned short* h2b = h1c + (size_t)256 * NN;              // NN*64 bf16
    unsigned short* embb = h2b + (size_t)64 * NN;              // NN*64 bf16
    float* as2     = (float*)(embb + (size_t)64 * NN);         // NN
    float* ad2     = as2 + NN;                                 // NN
    unsigned short* wTh = (unsigned short*)(ad2 + NN);         // 64*KP
    unsigned short* wTl = wTh + 64 * KP;
    unsigned short* w1h = wTl + 64 * KP;                       // 256*128
    unsigned short* w1l = w1h + C1 * INC;
    unsigned short* w2h = w1l + C1 * INC;                      // 64*256
    unsigned short* w2l = w2h + HID * C1;
    float* w1e     = (float*)(w2l + HID * C1 + 64);            // 4*EP
    float* w2e     = w1e + (size_t)4 * EP;                     // EP
    int*   counts  = (int*)(w2e + EP + 64);                    // NN
    int*   bsum    = counts + NN + 64;                         // NSB
    int*   cursor  = bsum + NSB + 64;                          // NN

    // ---- CSR build + weight prep ----
    hipMemsetAsync(counts, 0, NN * sizeof(int), stream);
    prep_all<<<(PREP_TOT + EP + 255) / 256, 256, 0, stream>>>(
        mW1, W1, W2, ei, wTh, wTl, w1h, w1l, w2h, w2l, counts);
    scan_partial<<<NSB, SCHUNK, 0, stream>>>(counts, bsum);
    scan_top<<<1, 128, 0, stream>>>(bsum, rowptr);
    scan_final<<<NSB, SCHUNK, 0, stream>>>(counts, bsum, rowptr, cursor);
    csr_fill<<<(EP + 255) / 256, 256, 0, stream>>>(ei, cursor, csr_src, csr_dst);

    // ---- conv1 ----
    gemm1_mfma<<<dim3((NN + 63) / 64, 4), 256, 0, stream>>>(x, w1h, w1l, att_s1, att_d1,
                                                            h1b, as1, ad1);
    edge_w1k<<<(EP + 255) / 256, 256, 0, stream>>>(csr_src, csr_dst, as1, ad1, w1e);
    conv1_agg<<<NN / 8, 256, 0, stream>>>(rowptr, csr_src, w1e, h1b, b1, h1c);

    // ---- conv2 ----
    gemm2_mfma<<<(NN + 63) / 64, 256, 0, stream>>>(h1c, w2h, w2l, att_s2, att_d2,
                                                   h2b, as2, ad2);
    edge_w2k<<<(EP + 255) / 256, 256, 0, stream>>>(csr_src, csr_dst, as2, ad2, w2e);
    conv2_agg<<<NN / 8, 256, 0, stream>>>(rowptr, csr_src, w2e, h2b, b2, embb);

    // ---- edge MLP: persistent, reg-resident W ----
    edge_mlp_mfma<<<512, 256, 0, stream>>>(ei, embb, stats, wTh, wTl, mW1,
                                           mb1, mW2, mb2, out);
}